// Round 5
// baseline (1390.172 us; speedup 1.0000x reference)
//
#include <hip/hip_runtime.h>
#include <hip/hip_cooperative_groups.h>
#include <math.h>

namespace cg = cooperative_groups;

#define B_ 32
#define T_ 128
#define H_ 300
#define HG 1200   // 4*H
#define LMAX 10
#define WLCAP 8192
#define ECAP 2048
#define BKT 16
#define NEGV -10000000.0f

__device__ __forceinline__ float sigm(float x){ return 1.f/(1.f+expf(-x)); }

// ---------------- fused weight prep: uh1T (enc+comp), folded proj W, cls_w1 transpose ----------------
// enh = [e, a, e-a, e*a];  enh@W^T = e(W0+W2)^T + a(W1-W2)^T + (e*a)W3^T
__global__ __launch_bounds__(256) void k_prep_all(
    const float* __restrict__ enc_uh, const float* __restrict__ comp_uh,
    const float* __restrict__ pw, const float* __restrict__ cw1,
    float* __restrict__ te, float* __restrict__ tc, float* __restrict__ wp, float* __restrict__ w1t)
{
  int i = blockIdx.x*256 + threadIdx.x;
  if (i < 90000) {                       // uh1 transposes: te/tc[m][k] = uh[1][k][m]
    int m = i / H_, k = i - m*H_;
    te[i] = enc_uh[H_*H_ + (size_t)k*H_ + m];
    tc[i] = comp_uh[H_*H_ + (size_t)k*H_ + m];
  } else if (i < 360000) {               // folded proj weight wp (300 x 900)
    int i2 = i - 90000;
    int n = i2 / 900, k = i2 - n*900;
    const float* r = pw + (size_t)n*HG;
    float v;
    if (k < 300)      v = r[k] + r[600+k];
    else if (k < 600) v = r[k] - r[k+300];
    else              v = r[k+300];
    wp[i2] = v;
  } else if (i < 720000) {               // w1t (1200 x 300): w1t[m][k] = cw1[k][m]
    int i2 = i - 360000;
    int m = i2 / H_, k = i2 - m*H_;
    w1t[i2] = cw1[(size_t)k*HG + m];
  }
}

// ---------------- graph analysis: edges, depths, level worklists (shared by both scans) ----------------
__global__ __launch_bounds__(256) void k_build(const float* __restrict__ lg, const float* __restrict__ rg,
    int* __restrict__ cnt_g, int* __restrict__ coff_g, int* __restrict__ eidx_g, float* __restrict__ ew_g,
    int* __restrict__ hasp_g, int* __restrict__ depth_g, int* __restrict__ maxd_g,
    int* __restrict__ lvlcnt_g, int* __restrict__ wl_g, int* __restrict__ maxl_g)
{
  int chain = blockIdx.x; int s = chain >> 5, b = chain & 31;
  const float* graph = (s ? rg : lg) + (size_t)b*T_*T_;
  int tid = threadIdx.x;
  __shared__ int cnt[T_], coff[T_], depth[T_], hasp[T_];
  __shared__ short eidx[ECAP];
  __shared__ float ew[ECAP];
  __shared__ int etot_s;
  if (tid < T_) hasp[tid] = 0;
  if (tid < T_) {
    int j = tid, c = 0;
    const float* gr = graph + (size_t)j*T_;
    for (int t = 0; t < j; ++t) c += (gr[t] != 0.f) ? 1 : 0;
    cnt[j] = c;
  }
  __syncthreads();
  if (tid == 0) { int a = 0; for (int j = 0; j < T_; ++j) { coff[j] = a; a += cnt[j]; } etot_s = a; }
  __syncthreads();
  if (tid < T_) {
    int j = tid, p = coff[j];
    const float* gr = graph + (size_t)j*T_;
    for (int t = 0; t < j; ++t) {
      float g = gr[t];
      if (g != 0.f && p < ECAP) { eidx[p] = (short)t; ew[p] = g; hasp[t] = 1; ++p; }
    }
  }
  __syncthreads();
  if (tid == 0) {
    int md = 0;
    for (int j = 0; j < T_; ++j) {
      int d = 0, e0 = coff[j], e1 = coff[j] + cnt[j];
      if (e1 > ECAP) e1 = ECAP;
      for (int k = e0; k < e1; ++k) { int dd = depth[eidx[k]] + 1; d = dd > d ? dd : d; }
      depth[j] = d; md = d > md ? d : md;
    }
    maxd_g[chain] = md;
    int mc = md; if (mc > LMAX-1) mc = LMAX-1;
    atomicMax(maxl_g, mc);
  }
  __syncthreads();
  int base = chain * T_;
  if (tid < T_) {
    cnt_g[base+tid] = cnt[tid]; coff_g[base+tid] = coff[tid];
    hasp_g[base+tid] = hasp[tid]; depth_g[base+tid] = depth[tid];
    int L = depth[tid];
    if (L < LMAX) { int p = atomicAdd(&lvlcnt_g[L], 1); wl_g[L*WLCAP + p] = (chain << 8) | tid; }
  }
  int etot = etot_s; if (etot > ECAP) etot = ECAP;
  for (int i = tid; i < etot; i += 256) { eidx_g[chain*ECAP + i] = eidx[i]; ew_g[chain*ECAP + i] = ew[i]; }
}

// ---------------- cooperative tree-LSTM: all levels + tail in ONE kernel ----------------
__global__ __launch_bounds__(1024) void k_scan_coop(
    const float* __restrict__ xg, const float* __restrict__ bhv, const float* __restrict__ uh1T,
    const int* __restrict__ cnt_g, const int* __restrict__ coff_g,
    const int* __restrict__ eidx_g, const float* __restrict__ ew_g,
    const int* __restrict__ hasp_g, const int* __restrict__ depth_g, const int* __restrict__ maxd_g,
    const int* __restrict__ lvlcnt_g, const int* __restrict__ wl_g, const int* __restrict__ maxl_g,
    float* __restrict__ hout, float* __restrict__ chist, float* __restrict__ fh)
{
  cg::grid_group grid = cg::this_grid();
  int tid = threadIdx.x;
  int bid = blockIdx.x;
  __shared__ float h_s[4][H_];
  __shared__ float psum[3][4][H_];
  __shared__ int nodes[4];
  __shared__ int anyp;
  int maxl = maxl_g[0];

  for (int L = 0; L <= maxl; ++L) {
    int count = lvlcnt_g[L];
    int nblk = (count + 3) >> 2;
    for (int blk = bid; blk < nblk; blk += 256) {
      int base = blk * 4;
      int nn = count - base; if (nn > 4) nn = 4;
      if (tid == 0) anyp = 0;
      __syncthreads();
      if (tid < 4) {
        int pk = (tid < nn) ? wl_g[L*WLCAP + base + tid] : -1;
        nodes[tid] = pk;
        if (pk >= 0 && hasp_g[(pk >> 8)*T_ + (pk & 255)]) atomicAdd(&anyp, 1);
      }
      __syncthreads();
      // gates + child accumulation
      for (int w = tid; w < nn*H_; w += 1024) {
        int n = w / H_, e = w - n*H_;
        int pk = nodes[n]; int chain = pk >> 8, j = pk & 255;
        size_t cb = (size_t)chain*T_*H_, xb = (size_t)chain*T_*HG;
        const float* xp = xg + xb + (size_t)j*HG;
        float x0 = xp[e], x1 = xp[H_+e], x2 = xp[2*H_+e], x3 = xp[3*H_+e];
        float iu  = sigm(x0 + bhv[e]) * tanhf(x3 + bhv[3*H_+e]);
        float og  = sigm(x2 + bhv[2*H_+e]);
        float x1b = x1 + bhv[H_+e];
        float acc = iu;
        int c0 = coff_g[chain*T_+j], c1 = c0 + cnt_g[chain*T_+j];
        const int* ei = eidx_g + chain*ECAP;
        const float* ewp = ew_g + chain*ECAP;
        for (int k = c0; k < c1; ++k) {
          int t = ei[k];
          acc += ewp[k] * sigm(x1b + fh[cb + (size_t)t*H_ + e]) * chist[cb + (size_t)t*H_ + e];
        }
        chist[cb + (size_t)j*H_ + e] = acc;
        float hv = og * tanhf(acc);
        hout[cb + (size_t)j*H_ + e] = hv;
        h_s[n][e] = hv;
      }
      __syncthreads();
      if (anyp > 0) {
        if (tid < 3*H_) {
          int g = tid / H_, e = tid - g*H_;
          float a0=0.f, a1=0.f, a2=0.f, a3=0.f;
          const float* up = uh1T + e;
          int m0 = g*100, m1 = m0 + 100;
          #pragma unroll 4
          for (int m = m0; m < m1; ++m) {
            float u = up[(size_t)m*H_];
            a0 = fmaf(u, h_s[0][m], a0);
            a1 = fmaf(u, h_s[1][m], a1);
            a2 = fmaf(u, h_s[2][m], a2);
            a3 = fmaf(u, h_s[3][m], a3);
          }
          psum[g][0][e]=a0; psum[g][1][e]=a1; psum[g][2][e]=a2; psum[g][3][e]=a3;
        }
        __syncthreads();
        for (int w = tid; w < nn*H_; w += 1024) {
          int n = w / H_, e = w - n*H_;
          int pk = nodes[n]; int chain = pk >> 8, j = pk & 255;
          if (hasp_g[chain*T_+j]) {
            size_t cb = (size_t)chain*T_*H_;
            fh[cb + (size_t)j*H_ + e] = psum[0][n][e] + psum[1][n][e] + psum[2][n][e];
          }
        }
      }
      __syncthreads();
    }
    grid.sync();
  }

  // serial tail for rare deep graphs (depth >= LMAX); block-local, one chain per block
  if (bid < 64 && maxd_g[bid] >= LMAX) {
    int chain = bid;
    bool act = tid < H_;
    float bh0=0.f,bh1=0.f,bh2=0.f,bh3=0.f;
    if (act) { bh0=bhv[tid]; bh1=bhv[H_+tid]; bh2=bhv[2*H_+tid]; bh3=bhv[3*H_+tid]; }
    size_t cb = (size_t)chain*T_*H_, xb = (size_t)chain*T_*HG;
    const int* ei = eidx_g + chain*ECAP;
    const float* ewp = ew_g + chain*ECAP;
    for (int j = 0; j < T_; ++j) {
      if (depth_g[chain*T_+j] < LMAX) continue;
      if (act) {
        const float* xp = xg + xb + (size_t)j*HG;
        float x0 = xp[tid], x1 = xp[H_+tid], x2 = xp[2*H_+tid], x3 = xp[3*H_+tid];
        float acc = sigm(x0+bh0) * tanhf(x3+bh3);
        float og  = sigm(x2+bh2);
        float x1b = x1 + bh1;
        int c0 = coff_g[chain*T_+j], c1 = c0 + cnt_g[chain*T_+j];
        for (int k = c0; k < c1; ++k) {
          int t = ei[k];
          acc += ewp[k] * sigm(x1b + fh[cb + (size_t)t*H_ + tid]) * chist[cb + (size_t)t*H_ + tid];
        }
        chist[cb + (size_t)j*H_ + tid] = acc;
        float hv = og * tanhf(acc);
        hout[cb + (size_t)j*H_ + tid] = hv;
        h_s[0][tid] = hv;
      }
      __syncthreads();
      if (hasp_g[chain*T_+j] && act) {
        float a = 0.f;
        const float* up = uh1T + tid;
        #pragma unroll 4
        for (int m = 0; m < H_; ++m) a = fmaf(up[(size_t)m*H_], h_s[0][m], a);
        fh[cb + (size_t)j*H_ + tid] = a;
      }
      __syncthreads();
    }
  }
}

// ---------------- fp32 GEMM, 128x128 tile, 512 threads, double-buffered LDS ----------------
// C[8192,N] = act(A[8192,K] @ W[N,K]^T + bias[N])
// mode 0: A plain (row stride K); mode 1: A = emb[tok[m]] gather (K=300);
// mode 2: A = [H1 | ATT | H1*ATT] segmented over K=900
__global__ __launch_bounds__(512) void k_gemm128(
    const float* __restrict__ A, const float* __restrict__ A2,
    const int* __restrict__ ptok, const int* __restrict__ htok, const float* __restrict__ embr,
    const float* __restrict__ W, const float* __restrict__ bias, float* __restrict__ C,
    int N, int K, int act, int mode)
{
  __shared__ float As[2][BKT][132];
  __shared__ float Ws[2][BKT][132];
  int bn = blockIdx.x * 128;
  int bm = blockIdx.y * 128;
  int tid = threadIdx.x;
  int lr = tid >> 2;        // staging row 0..127
  int kq = (tid & 3) * 4;   // staging k offset 0,4,8,12

  int arow = bm + lr;       // always < 8192
  const float* Ar1; const float* Ar2 = A2;
  if (mode == 1)      { int tok = (arow < 4096) ? ptok[arow] : htok[arow - 4096]; Ar1 = embr + (size_t)tok*H_; }
  else if (mode == 2) { Ar1 = A + (size_t)arow*H_; Ar2 = A2 + (size_t)arow*H_; }
  else                  Ar1 = A + (size_t)arow*K;
  int brow = bn + lr;
  const float* Wr = W + (size_t)brow*K;
  bool bok = brow < N;

  int NT = (K + BKT - 1) / BKT;
  float4 ra, rx, rb;
  int segv = 0;

  auto issue = [&](int t) {
    int gk = t*BKT + kq;
    ra = make_float4(0.f,0.f,0.f,0.f); rb = make_float4(0.f,0.f,0.f,0.f); segv = 0;
    if (gk < K) {
      if (mode == 2) {
        int s = (gk >= 600) ? 2 : ((gk >= 300) ? 1 : 0);
        int kk = gk - s*300; segv = s;
        if (s == 0)      ra = *(const float4*)(Ar1 + kk);
        else if (s == 1) ra = *(const float4*)(Ar2 + kk);
        else { ra = *(const float4*)(Ar1 + kk); rx = *(const float4*)(Ar2 + kk); }
      } else ra = *(const float4*)(Ar1 + gk);
      if (bok) rb = *(const float4*)(Wr + gk);
    }
  };
  auto commit = [&](int buf) {
    float4 va = ra;
    if (mode == 2 && segv == 2) { va.x*=rx.x; va.y*=rx.y; va.z*=rx.z; va.w*=rx.w; }
    As[buf][kq+0][lr]=va.x; As[buf][kq+1][lr]=va.y; As[buf][kq+2][lr]=va.z; As[buf][kq+3][lr]=va.w;
    Ws[buf][kq+0][lr]=rb.x; Ws[buf][kq+1][lr]=rb.y; Ws[buf][kq+2][lr]=rb.z; Ws[buf][kq+3][lr]=rb.w;
  };

  float acc[4][8];
  #pragma unroll
  for (int i=0;i<4;++i)
    #pragma unroll
    for (int j=0;j<8;++j) acc[i][j]=0.f;

  int tx = tid & 15, ty = tid >> 4;

  issue(0); commit(0);
  __syncthreads();
  int cur = 0;
  for (int t = 0; t < NT; ++t) {
    bool more = (t+1 < NT);
    if (more) issue(t+1);
    #pragma unroll
    for (int kk = 0; kk < BKT; ++kk) {
      float a[4], b[8];
      *(float4*)&a[0] = *(const float4*)&As[cur][kk][ty*4];
      *(float4*)&b[0] = *(const float4*)&Ws[cur][kk][tx*8];
      *(float4*)&b[4] = *(const float4*)&Ws[cur][kk][tx*8+4];
      #pragma unroll
      for (int i=0;i<4;++i)
        #pragma unroll
        for (int j=0;j<8;++j) acc[i][j] = fmaf(a[i], b[j], acc[i][j]);
    }
    if (more) commit(cur^1);
    __syncthreads();
    cur ^= 1;
  }
  #pragma unroll
  for (int i=0;i<4;++i) {
    int m = bm + ty*4 + i;
    float* cr = C + (size_t)m*N;
    #pragma unroll
    for (int j=0;j<8;++j) {
      int n = bn + tx*8 + j;
      if (n < N) {
        float v = acc[i][j] + bias[n];
        if (act) v = fmaxf(v, 0.f);
        cr[n] = v;
      }
    }
  }
}

// ---------------- fused attention (one direction per blockIdx.x) ----------------
__global__ __launch_bounds__(256) void k_attention(const float* __restrict__ H,  // (2,B,T,300)
    const int* __restrict__ plen, const int* __restrict__ hlen, float* __restrict__ ATT)
{
  int d = blockIdx.x;
  int b = blockIdx.y;
  int r0 = blockIdx.z * 8;
  int qs = d, ks = 1 - d;
  int klen = (d == 0 ? hlen[b] : plen[b]);
  const float* Q  = H + ((size_t)(qs*B_ + b)*T_) * H_;
  const float* Kp = H + ((size_t)(ks*B_ + b)*T_) * H_;
  __shared__ float qr[8][H_];
  __shared__ float P[8][T_];
  __shared__ float rinv[8];
  int tid = threadIdx.x;

  for (int e = tid; e < 8*H_; e += 256) {
    int r = e / H_, m = e % H_;
    qr[r][m] = Q[(size_t)(r0 + r)*H_ + m];
  }
  __syncthreads();
  #pragma unroll
  for (int rep = 0; rep < 4; ++rep) {
    int e = tid + rep*256;
    int r = e >> 7, q = e & 127;
    float sc;
    if (q >= klen) sc = NEGV;
    else {
      sc = 0.f;
      const float* kp = Kp + (size_t)q*H_;
      #pragma unroll 4
      for (int m = 0; m < H_; ++m) sc = fmaf(qr[r][m], kp[m], sc);
    }
    P[r][q] = sc;
  }
  __syncthreads();
  {
    int g = tid >> 5, l = tid & 31;
    float s0 = P[g][l], s1 = P[g][l+32], s2 = P[g][l+64], s3 = P[g][l+96];
    float m0 = fmaxf(fmaxf(s0,s1), fmaxf(s2,s3));
    for (int o = 16; o > 0; o >>= 1) m0 = fmaxf(m0, __shfl_xor(m0, o, 32));
    float e0 = expf(s0-m0), e1 = expf(s1-m0), e2 = expf(s2-m0), e3 = expf(s3-m0);
    float sum = e0+e1+e2+e3;
    for (int o = 16; o > 0; o >>= 1) sum += __shfl_xor(sum, o, 32);
    P[g][l] = e0; P[g][l+32] = e1; P[g][l+64] = e2; P[g][l+96] = e3;
    if (l == 0) rinv[g] = 1.f / sum;
  }
  __syncthreads();
  float* out = ATT + ((size_t)(d*B_ + b)*T_ + r0) * H_;
  for (int e = tid; e < 8*H_; e += 256) {
    int r = e / H_, h = e % H_;
    float a = 0.f;
    const float* kp = Kp + h;
    #pragma unroll 4
    for (int q = 0; q < T_; ++q) a = fmaf(P[r][q], kp[(size_t)q*H_], a);
    out[(size_t)r*H_ + h] = a * rinv[r];
  }
}

// ---------------- pool stage 1: per (chain, 16-t chunk) partial sum/max ----------------
__global__ __launch_bounds__(320) void k_pool(const float* __restrict__ H,
    const int* __restrict__ plen, const int* __restrict__ hlen,
    float* __restrict__ psum, float* __restrict__ pmax)
{
  int chain = blockIdx.x; int s = chain >> 5, b = chain & 31;
  int c = blockIdx.y; int t0 = c * 16;
  int len = (s == 0 ? plen[b] : hlen[b]);
  int tid = threadIdx.x;
  __shared__ float buf[16*H_];
  const float* hp = H + (size_t)chain*T_*H_ + (size_t)t0*H_;
  for (int i = tid; i < 16*H_; i += 320) buf[i] = hp[i];   // fully coalesced
  __syncthreads();
  if (tid < H_) {
    int tmax = len - t0; if (tmax > 16) tmax = 16;
    float sum = 0.f, mx = NEGV;
    for (int t = 0; t < tmax; ++t) { float x = buf[t*H_ + tid]; sum += x; mx = fmaxf(mx, x); }
    int o = (chain*8 + c)*H_ + tid;
    psum[o] = sum; pmax[o] = mx;
  }
}

// ---------------- pool stage 2 + classifier ----------------
__global__ __launch_bounds__(320) void k_classify(
    const float* __restrict__ psum, const float* __restrict__ pmax,
    const int* __restrict__ plen, const int* __restrict__ hlen,
    const float* __restrict__ w1t, const float* __restrict__ b1,
    const float* __restrict__ w2, const float* __restrict__ b2,
    float* __restrict__ out)
{
  int b = blockIdx.x;
  int tid = threadIdx.x;
  __shared__ float v[HG];
  __shared__ float hid[H_];
  for (int s = 0; s < 2; ++s) {
    int chain = s*B_ + b;
    int len = (s == 0 ? plen[b] : hlen[b]);
    if (tid < H_) {
      float sum = 0.f, mx = NEGV;
      #pragma unroll
      for (int c = 0; c < 8; ++c) {
        int o = (chain*8 + c)*H_ + tid;
        sum += psum[o]; mx = fmaxf(mx, pmax[o]);
      }
      v[s*600 + tid]       = sum / (float)len;
      v[s*600 + 300 + tid] = mx;
    }
  }
  __syncthreads();
  if (tid < H_) {
    float a0 = b1[tid], a1 = 0.f, a2 = 0.f, a3 = 0.f;
    for (int m = 0; m < HG; m += 4) {     // w1t[m][k]: coalesced across tid
      a0 = fmaf(v[m+0], w1t[(size_t)(m+0)*H_ + tid], a0);
      a1 = fmaf(v[m+1], w1t[(size_t)(m+1)*H_ + tid], a1);
      a2 = fmaf(v[m+2], w1t[(size_t)(m+2)*H_ + tid], a2);
      a3 = fmaf(v[m+3], w1t[(size_t)(m+3)*H_ + tid], a3);
    }
    hid[tid] = tanhf(a0 + a1 + a2 + a3);
  }
  __syncthreads();
  if (tid < 3) {
    float a = b2[tid];
    const float* wr = w2 + (size_t)tid*H_;
    for (int n = 0; n < H_; ++n) a = fmaf(hid[n], wr[n], a);
    out[b*3 + tid] = a;
  }
}

// ---------------- launch ----------------
extern "C" void kernel_launch(void* const* d_in, const int* in_sizes, int n_in,
                              void* d_out, int out_size, void* d_ws, size_t ws_size,
                              hipStream_t stream) {
  const int*   prem    = (const int*)d_in[0];
  const int*   plen    = (const int*)d_in[1];
  const int*   hyp     = (const int*)d_in[2];
  const int*   hlen    = (const int*)d_in[3];
  const float* lg      = (const float*)d_in[4];
  const float* rg      = (const float*)d_in[5];
  const float* emb     = (const float*)d_in[6];
  const float* enc_wx  = (const float*)d_in[7];
  const float* enc_bx  = (const float*)d_in[8];
  const float* enc_uh  = (const float*)d_in[9];
  const float* enc_bh  = (const float*)d_in[10];
  const float* comp_wx = (const float*)d_in[11];
  const float* comp_bx = (const float*)d_in[12];
  const float* comp_uh = (const float*)d_in[13];
  const float* comp_bh = (const float*)d_in[14];
  const float* proj_w  = (const float*)d_in[15];
  const float* proj_b  = (const float*)d_in[16];
  const float* cls_w1  = (const float*)d_in[17];
  const float* cls_b1  = (const float*)d_in[18];
  const float* cls_w2  = (const float*)d_in[19];
  const float* cls_b2  = (const float*)d_in[20];
  float* outp = (float*)d_out;

  // workspace layout (floats); ATT aliases CH (disjoint lifetimes)
  const size_t SZ_XG  = (size_t)2*B_*T_*HG;   // 9,830,400
  const size_t SZ_BTH = (size_t)2*B_*T_*H_;   // 2,457,600
  float* XG  = (float*)d_ws;    // enc-xg -> comp-xg
  float* PROJ= XG  + SZ_XG;     // proj output (8192x300)
  float* H1  = PROJ+ SZ_BTH;    // enc h -> comp h
  float* CH  = H1  + SZ_BTH;    // c history (scan-local); reused as ATT between scans
  float* FH  = CH  + SZ_BTH;    // fh = uh1 @ h
  float* UTE = FH  + SZ_BTH;    // uh1T enc (90000)
  float* UTC = UTE + (size_t)H_*H_;
  float* WP  = UTC + (size_t)H_*H_;          // folded proj weight (300x900)
  float* W1T = WP  + (size_t)H_*900;         // cls_w1 transpose (1200x300)
  float* PSUM= W1T + (size_t)HG*H_;          // 64*8*300
  float* PMAX= PSUM+ (size_t)64*8*H_;
  float* EW  = PMAX+ (size_t)64*8*H_;        // 64*2048
  int*   EIDX = (int*)(EW + (size_t)64*ECAP);
  int*   CNT  = EIDX + (size_t)64*ECAP;
  int*   COFF = CNT  + 64*T_;
  int*   DEPTH= COFF + 64*T_;
  int*   HASP = DEPTH+ 64*T_;
  int*   MAXD = HASP + 64*T_;
  int*   LVLCNT = MAXD + 64;                 // LMAX ints
  int*   MAXL = LVLCNT + LMAX;               // 1 int
  int*   WL   = MAXL + 1;                    // LMAX*WLCAP
  float* ATT  = CH;

  hipMemsetAsync(LVLCNT, 0, (LMAX+1)*sizeof(int), stream);
  // 1. weight prep + graph analysis
  k_prep_all<<<(720000 + 255)/256, 256, 0, stream>>>(enc_uh, comp_uh, proj_w, cls_w1, UTE, UTC, WP, W1T);
  k_build<<<64, 256, 0, stream>>>(lg, rg, CNT, COFF, EIDX, EW, HASP, DEPTH, MAXD, LVLCNT, WL, MAXL);
  // 2. enc xg = emb-gather @ enc_wx^T + enc_bx
  k_gemm128<<<dim3(10, 64), 512, 0, stream>>>(nullptr, nullptr, prem, hyp, emb,
      enc_wx, enc_bx, XG, HG, H_, 0, 1);
  // 3. enc tree scan (single cooperative kernel, grid.sync between levels)
  {
    const float* a_xg = XG; const float* a_bh = enc_bh; const float* a_ut = UTE;
    const int* a_cnt = CNT; const int* a_coff = COFF; const int* a_eidx = EIDX;
    const float* a_ew = EW; const int* a_hasp = HASP; const int* a_dep = DEPTH;
    const int* a_maxd = MAXD; const int* a_lvl = LVLCNT; const int* a_wl = WL; const int* a_maxl = MAXL;
    float* a_h = H1; float* a_c = CH; float* a_f = FH;
    void* args[] = { &a_xg, &a_bh, &a_ut, &a_cnt, &a_coff, &a_eidx, &a_ew, &a_hasp, &a_dep,
                     &a_maxd, &a_lvl, &a_wl, &a_maxl, &a_h, &a_c, &a_f };
    hipLaunchCooperativeKernel((const void*)k_scan_coop, dim3(256), dim3(1024), args, 0, stream);
  }
  // 4. attention both directions (CH dead -> ATT)
  k_attention<<<dim3(2, B_, T_/8), 256, 0, stream>>>(H1, plen, hlen, ATT);
  // 5. proj = relu([H1|ATT|H1*ATT] @ WP^T + proj_b)
  k_gemm128<<<dim3(3, 64), 512, 0, stream>>>(H1, ATT, nullptr, nullptr, nullptr,
      WP, proj_b, PROJ, H_, 900, 1, 2);
  // 6. comp xg = proj @ comp_wx^T + comp_bx
  k_gemm128<<<dim3(10, 64), 512, 0, stream>>>(PROJ, nullptr, nullptr, nullptr, nullptr,
      comp_wx, comp_bx, XG, HG, H_, 0, 0);
  // 7. comp tree scan (ATT dead -> CH again)
  {
    const float* a_xg = XG; const float* a_bh = comp_bh; const float* a_ut = UTC;
    const int* a_cnt = CNT; const int* a_coff = COFF; const int* a_eidx = EIDX;
    const float* a_ew = EW; const int* a_hasp = HASP; const int* a_dep = DEPTH;
    const int* a_maxd = MAXD; const int* a_lvl = LVLCNT; const int* a_wl = WL; const int* a_maxl = MAXL;
    float* a_h = H1; float* a_c = CH; float* a_f = FH;
    void* args[] = { &a_xg, &a_bh, &a_ut, &a_cnt, &a_coff, &a_eidx, &a_ew, &a_hasp, &a_dep,
                     &a_maxd, &a_lvl, &a_wl, &a_maxl, &a_h, &a_c, &a_f };
    hipLaunchCooperativeKernel((const void*)k_scan_coop, dim3(256), dim3(1024), args, 0, stream);
  }
  // 8. pool (2-stage) + classifier
  k_pool<<<dim3(64, 8), 320, 0, stream>>>(H1, plen, hlen, PSUM, PMAX);
  k_classify<<<B_, 320, 0, stream>>>(PSUM, PMAX, plen, hlen, W1T, cls_b1, cls_w2, cls_b2, outp);
}

// Round 6
// 1086.870 us; speedup vs baseline: 1.2791x; 1.2791x over previous
//
#include <hip/hip_runtime.h>
#include <math.h>

#define B_ 32
#define T_ 128
#define H_ 300
#define HG 1200   // 4*H
#define LMAX 10
#define WLCAP 8192
#define ECAP 2048
#define BKT 16
#define NEGV -10000000.0f

__device__ __forceinline__ float sigm(float x){ return 1.f/(1.f+expf(-x)); }

// ---------------- fused weight prep ----------------
__global__ __launch_bounds__(256) void k_prep_all(
    const float* __restrict__ enc_uh, const float* __restrict__ comp_uh,
    const float* __restrict__ pw, const float* __restrict__ cw1,
    float* __restrict__ te, float* __restrict__ tc, float* __restrict__ wp, float* __restrict__ w1t)
{
  int i = blockIdx.x*256 + threadIdx.x;
  if (i < 90000) {                       // uh1 transposes: te/tc[m][k] = uh[1][k][m]
    int m = i / H_, k = i - m*H_;
    te[i] = enc_uh[H_*H_ + (size_t)k*H_ + m];
    tc[i] = comp_uh[H_*H_ + (size_t)k*H_ + m];
  } else if (i < 360000) {               // folded proj weight wp (300 x 900)
    int i2 = i - 90000;
    int n = i2 / 900, k = i2 - n*900;
    const float* r = pw + (size_t)n*HG;
    float v;
    if (k < 300)      v = r[k] + r[600+k];
    else if (k < 600) v = r[k] - r[k+300];
    else              v = r[k+300];
    wp[i2] = v;
  } else if (i < 720000) {               // w1t (1200 x 300): w1t[m][k] = cw1[k][m]
    int i2 = i - 360000;
    int m = i2 / H_, k = i2 - m*H_;
    w1t[i2] = cw1[(size_t)k*HG + m];
  }
}

// ---------------- graph analysis ----------------
__global__ __launch_bounds__(256) void k_build(const float* __restrict__ lg, const float* __restrict__ rg,
    int* __restrict__ cnt_g, int* __restrict__ coff_g, int* __restrict__ eidx_g, float* __restrict__ ew_g,
    int* __restrict__ hasp_g, int* __restrict__ depth_g, int* __restrict__ maxd_g,
    int* __restrict__ lvlcnt_g, int* __restrict__ wl_g)
{
  int chain = blockIdx.x; int s = chain >> 5, b = chain & 31;
  const float* graph = (s ? rg : lg) + (size_t)b*T_*T_;
  int tid = threadIdx.x;
  __shared__ int cnt[T_], coff[T_], depth[T_], hasp[T_];
  __shared__ short eidx[ECAP];
  __shared__ float ew[ECAP];
  __shared__ int etot_s;
  if (tid < T_) hasp[tid] = 0;
  if (tid < T_) {
    int j = tid, c = 0;
    const float* gr = graph + (size_t)j*T_;
    for (int t = 0; t < j; ++t) c += (gr[t] != 0.f) ? 1 : 0;
    cnt[j] = c;
  }
  __syncthreads();
  if (tid == 0) { int a = 0; for (int j = 0; j < T_; ++j) { coff[j] = a; a += cnt[j]; } etot_s = a; }
  __syncthreads();
  if (tid < T_) {
    int j = tid, p = coff[j];
    const float* gr = graph + (size_t)j*T_;
    for (int t = 0; t < j; ++t) {
      float g = gr[t];
      if (g != 0.f && p < ECAP) { eidx[p] = (short)t; ew[p] = g; hasp[t] = 1; ++p; }
    }
  }
  __syncthreads();
  if (tid == 0) {
    int md = 0;
    for (int j = 0; j < T_; ++j) {
      int d = 0, e0 = coff[j], e1 = coff[j] + cnt[j];
      if (e1 > ECAP) e1 = ECAP;
      for (int k = e0; k < e1; ++k) { int dd = depth[eidx[k]] + 1; d = dd > d ? dd : d; }
      depth[j] = d; md = d > md ? d : md;
    }
    maxd_g[chain] = md;
  }
  __syncthreads();
  int base = chain * T_;
  if (tid < T_) {
    cnt_g[base+tid] = cnt[tid]; coff_g[base+tid] = coff[tid];
    hasp_g[base+tid] = hasp[tid]; depth_g[base+tid] = depth[tid];
    int L = depth[tid];
    if (L < LMAX) { int p = atomicAdd(&lvlcnt_g[L], 1); wl_g[L*WLCAP + p] = (chain << 8) | tid; }
  }
  int etot = etot_s; if (etot > ECAP) etot = ECAP;
  for (int i = tid; i < etot; i += 256) { eidx_g[chain*ECAP + i] = eidx[i]; ew_g[chain*ECAP + i] = ew[i]; }
}

// ---------------- gate precompute, in-place over XG ----------------
// slot0 <- i*u ; slot1 <- x1+bh1 ; slot2 <- o   (slot3 left stale)
__global__ __launch_bounds__(256) void k_gates(float* __restrict__ xg, const float* __restrict__ bhv)
{
  int i = blockIdx.x*256 + threadIdx.x;          // over 2*B*T*300
  if (i >= 2*B_*T_*H_) return;
  int bt = i / H_, e = i - bt*H_;
  float* xp = xg + (size_t)bt*HG;
  float x0 = xp[e], x1 = xp[H_+e], x2 = xp[2*H_+e], x3 = xp[3*H_+e];
  xp[e]       = sigm(x0 + bhv[e]) * tanhf(x3 + bhv[3*H_+e]);
  xp[H_+e]    = x1 + bhv[H_+e];
  xp[2*H_+e]  = sigm(x2 + bhv[2*H_+e]);
}

// ---------------- per-level tree-LSTM (round-4 proven structure, gates precomputed) ----------------
__global__ __launch_bounds__(1024) void k_level(
    const float* __restrict__ xg, const float* __restrict__ uh1T,
    const int* __restrict__ cnt_g, const int* __restrict__ coff_g,
    const int* __restrict__ eidx_g, const float* __restrict__ ew_g,
    const int* __restrict__ hasp_g, const int* __restrict__ lvlcnt_g, const int* __restrict__ wl_g,
    int L, float* __restrict__ hout, float* __restrict__ chist, float* __restrict__ fh)
{
  int count = lvlcnt_g[L];
  int nblk = (count + 3) >> 2;
  int tid = threadIdx.x;
  __shared__ float h_s[4][H_];
  __shared__ float psum[3][4][H_];
  __shared__ int nodes[4];
  __shared__ int anyp;
  for (int blk = blockIdx.x; blk < nblk; blk += gridDim.x) {
    int base = blk * 4;
    int nn = count - base; if (nn > 4) nn = 4;
    if (tid == 0) anyp = 0;
    __syncthreads();
    if (tid < 4) {
      int pk = (tid < nn) ? wl_g[L*WLCAP + base + tid] : -1;
      nodes[tid] = pk;
      if (pk >= 0 && hasp_g[(pk >> 8)*T_ + (pk & 255)]) atomicAdd(&anyp, 1);
    }
    __syncthreads();
    for (int w = tid; w < nn*H_; w += 1024) {
      int n = w / H_, e = w - n*H_;
      int pk = nodes[n]; int chain = pk >> 8, j = pk & 255;
      size_t cb = (size_t)chain*T_*H_, xb = (size_t)chain*T_*HG;
      const float* xp = xg + xb + (size_t)j*HG;
      float iu = xp[e], x1b = xp[H_+e], og = xp[2*H_+e];
      float acc = iu;
      int c0 = coff_g[chain*T_+j], c1 = c0 + cnt_g[chain*T_+j];
      const int* ei = eidx_g + chain*ECAP;
      const float* ewp = ew_g + chain*ECAP;
      for (int k = c0; k < c1; ++k) {
        int t = ei[k];
        acc += ewp[k] * sigm(x1b + fh[cb + (size_t)t*H_ + e]) * chist[cb + (size_t)t*H_ + e];
      }
      chist[cb + (size_t)j*H_ + e] = acc;
      float hv = og * tanhf(acc);
      hout[cb + (size_t)j*H_ + e] = hv;
      h_s[n][e] = hv;
    }
    __syncthreads();
    if (anyp > 0) {
      if (tid < 3*H_) {
        int g = tid / H_, e = tid - g*H_;
        float a0=0.f, a1=0.f, a2=0.f, a3=0.f;
        const float* up = uh1T + e;
        int m0 = g*100, m1 = m0 + 100;
        #pragma unroll 4
        for (int m = m0; m < m1; ++m) {
          float u = up[(size_t)m*H_];
          a0 = fmaf(u, h_s[0][m], a0);
          a1 = fmaf(u, h_s[1][m], a1);
          a2 = fmaf(u, h_s[2][m], a2);
          a3 = fmaf(u, h_s[3][m], a3);
        }
        psum[g][0][e]=a0; psum[g][1][e]=a1; psum[g][2][e]=a2; psum[g][3][e]=a3;
      }
      __syncthreads();
      for (int w = tid; w < nn*H_; w += 1024) {
        int n = w / H_, e = w - n*H_;
        int pk = nodes[n]; int chain = pk >> 8, j = pk & 255;
        if (hasp_g[chain*T_+j]) {
          size_t cb = (size_t)chain*T_*H_;
          fh[cb + (size_t)j*H_ + e] = psum[0][n][e] + psum[1][n][e] + psum[2][n][e];
        }
      }
    }
    __syncthreads();
  }
}

// ---------------- serial tail for rare deep graphs ----------------
__global__ __launch_bounds__(320) void k_tail(const float* __restrict__ xg,
    const float* __restrict__ uh1T, const int* __restrict__ cnt_g, const int* __restrict__ coff_g,
    const int* __restrict__ eidx_g, const float* __restrict__ ew_g, const int* __restrict__ hasp_g,
    const int* __restrict__ depth_g, const int* __restrict__ maxd_g,
    float* __restrict__ hout, float* __restrict__ chist, float* __restrict__ fh)
{
  int chain = blockIdx.x;
  if (maxd_g[chain] < LMAX) return;
  int tid = threadIdx.x;
  bool act = tid < H_;
  __shared__ float h_lds[H_];
  size_t cb = (size_t)chain*T_*H_, xb = (size_t)chain*T_*HG;
  const int* ei = eidx_g + chain*ECAP;
  const float* ewp = ew_g + chain*ECAP;
  for (int j = 0; j < T_; ++j) {
    if (depth_g[chain*T_+j] < LMAX) continue;
    if (act) {
      const float* xp = xg + xb + (size_t)j*HG;
      float iu = xp[tid], x1b = xp[H_+tid], og = xp[2*H_+tid];
      float acc = iu;
      int c0 = coff_g[chain*T_+j], c1 = c0 + cnt_g[chain*T_+j];
      for (int k = c0; k < c1; ++k) {
        int t = ei[k];
        acc += ewp[k] * sigm(x1b + fh[cb + (size_t)t*H_ + tid]) * chist[cb + (size_t)t*H_ + tid];
      }
      chist[cb + (size_t)j*H_ + tid] = acc;
      float hv = og * tanhf(acc);
      hout[cb + (size_t)j*H_ + tid] = hv;
      h_lds[tid] = hv;
    }
    __syncthreads();
    if (hasp_g[chain*T_+j] && act) {
      float a = 0.f;
      const float* up = uh1T + tid;
      #pragma unroll 4
      for (int m = 0; m < H_; ++m) a = fmaf(up[(size_t)m*H_], h_lds[m], a);
      fh[cb + (size_t)j*H_ + tid] = a;
    }
    __syncthreads();
  }
}

// ---------------- fp32 GEMM v3: BMx128 tile, 8x8 acc, double-buffered, split-B fragments ----------------
// C[8192,N] = act(A[8192,K] @ W[N,K]^T + bias[N])
// mode 0: A plain; mode 1: A = emb[tok[m]]; mode 2: A = [H1|ATT|H1*ATT] over K=900
template<int BM, int TH>
__global__ __launch_bounds__(TH) void k_gemm(
    const float* __restrict__ A, const float* __restrict__ A2,
    const int* __restrict__ ptok, const int* __restrict__ htok, const float* __restrict__ embr,
    const float* __restrict__ W, const float* __restrict__ bias, float* __restrict__ C,
    int N, int K, int act, int mode)
{
  constexpr int NA4 = BM*4/TH;     // A float4s per thread (=2)
  constexpr int NB4 = 512/TH;      // B float4s per thread (2 or 4)
  constexpr int LDA = BM + 4;
  __shared__ float As[2][BKT][LDA];
  __shared__ float Ws[2][BKT][132];
  int bn = blockIdx.x * 128;
  int bm = blockIdx.y * BM;
  int tid = threadIdx.x;
  int tx = tid & 15, ty = tid >> 4;

  const float* ArA[NA4]; const float* ArB[NA4];
  int rA[NA4], kqA[NA4];
  #pragma unroll
  for (int i = 0; i < NA4; ++i) {
    int f = tid + i*TH; rA[i] = f >> 2; kqA[i] = (f & 3) << 2;
    int arow = bm + rA[i];
    if (mode == 1)      { int tok = (arow < 4096) ? ptok[arow] : htok[arow-4096]; ArA[i] = embr + (size_t)tok*H_; ArB[i] = nullptr; }
    else if (mode == 2) { ArA[i] = A + (size_t)arow*H_; ArB[i] = A2 + (size_t)arow*H_; }
    else                { ArA[i] = A + (size_t)arow*K;  ArB[i] = nullptr; }
  }
  int rB[NB4], kqB[NB4]; const float* Wr[NB4]; bool bok[NB4];
  #pragma unroll
  for (int i = 0; i < NB4; ++i) {
    int f = tid + i*TH; rB[i] = f >> 2; kqB[i] = (f & 3) << 2;
    int brow = bn + rB[i];
    bok[i] = brow < N;
    Wr[i] = W + (size_t)brow*K;
  }

  float4 ra[NA4], rx[NA4], rb[NB4];
  int seg[NA4];

  auto issue = [&](int t) {
    #pragma unroll
    for (int i = 0; i < NA4; ++i) {
      int gk = t*BKT + kqA[i];
      ra[i] = make_float4(0.f,0.f,0.f,0.f); seg[i] = 0;
      if (gk < K) {
        if (mode == 2) {
          int s = (gk >= 600) ? 2 : ((gk >= 300) ? 1 : 0);
          int kk = gk - s*300; seg[i] = s;
          if (s == 0)      ra[i] = *(const float4*)(ArA[i] + kk);
          else if (s == 1) ra[i] = *(const float4*)(ArB[i] + kk);
          else { ra[i] = *(const float4*)(ArA[i] + kk); rx[i] = *(const float4*)(ArB[i] + kk); }
        } else ra[i] = *(const float4*)(ArA[i] + gk);
      }
    }
    #pragma unroll
    for (int i = 0; i < NB4; ++i) {
      int gk = t*BKT + kqB[i];
      rb[i] = make_float4(0.f,0.f,0.f,0.f);
      if (bok[i] && gk < K) rb[i] = *(const float4*)(Wr[i] + gk);
    }
  };
  auto commit = [&](int buf) {
    #pragma unroll
    for (int i = 0; i < NA4; ++i) {
      float4 va = ra[i];
      if (mode == 2 && seg[i] == 2) { va.x*=rx[i].x; va.y*=rx[i].y; va.z*=rx[i].z; va.w*=rx[i].w; }
      As[buf][kqA[i]+0][rA[i]]=va.x; As[buf][kqA[i]+1][rA[i]]=va.y;
      As[buf][kqA[i]+2][rA[i]]=va.z; As[buf][kqA[i]+3][rA[i]]=va.w;
    }
    #pragma unroll
    for (int i = 0; i < NB4; ++i) {
      Ws[buf][kqB[i]+0][rB[i]]=rb[i].x; Ws[buf][kqB[i]+1][rB[i]]=rb[i].y;
      Ws[buf][kqB[i]+2][rB[i]]=rb[i].z; Ws[buf][kqB[i]+3][rB[i]]=rb[i].w;
    }
  };

  float acc[8][8];
  #pragma unroll
  for (int i=0;i<8;++i)
    #pragma unroll
    for (int j=0;j<8;++j) acc[i][j]=0.f;

  int NT = (K + BKT - 1) / BKT;
  issue(0); commit(0);
  __syncthreads();
  int cur = 0;
  for (int t = 0; t < NT; ++t) {
    bool more = (t+1 < NT);
    if (more) issue(t+1);
    #pragma unroll
    for (int kk = 0; kk < BKT; ++kk) {
      float a[8], b[8];
      *(float4*)&a[0] = *(const float4*)&As[cur][kk][ty*8];
      *(float4*)&a[4] = *(const float4*)&As[cur][kk][ty*8+4];
      *(float4*)&b[0] = *(const float4*)&Ws[cur][kk][tx*4];        // cols bn+tx*4..+3
      *(float4*)&b[4] = *(const float4*)&Ws[cur][kk][64 + tx*4];   // cols bn+64+tx*4..+3
      #pragma unroll
      for (int i=0;i<8;++i)
        #pragma unroll
        for (int j=0;j<8;++j) acc[i][j] = fmaf(a[i], b[j], acc[i][j]);
    }
    if (more) commit(cur^1);
    __syncthreads();
    cur ^= 1;
  }
  #pragma unroll
  for (int i=0;i<8;++i) {
    int m = bm + ty*8 + i;
    float* cr = C + (size_t)m*N;
    #pragma unroll
    for (int j=0;j<8;++j) {
      int n = bn + ((j<4) ? (tx*4 + j) : (64 + tx*4 + (j-4)));
      if (n < N) {
        float v = acc[i][j] + bias[n];
        if (act) v = fmaxf(v, 0.f);
        cr[n] = v;
      }
    }
  }
}

// ---------------- fused attention (unchanged) ----------------
__global__ __launch_bounds__(256) void k_attention(const float* __restrict__ H,
    const int* __restrict__ plen, const int* __restrict__ hlen, float* __restrict__ ATT)
{
  int d = blockIdx.x;
  int b = blockIdx.y;
  int r0 = blockIdx.z * 8;
  int qs = d, ks = 1 - d;
  int klen = (d == 0 ? hlen[b] : plen[b]);
  const float* Q  = H + ((size_t)(qs*B_ + b)*T_) * H_;
  const float* Kp = H + ((size_t)(ks*B_ + b)*T_) * H_;
  __shared__ float qr[8][H_];
  __shared__ float P[8][T_];
  __shared__ float rinv[8];
  int tid = threadIdx.x;

  for (int e = tid; e < 8*H_; e += 256) {
    int r = e / H_, m = e % H_;
    qr[r][m] = Q[(size_t)(r0 + r)*H_ + m];
  }
  __syncthreads();
  #pragma unroll
  for (int rep = 0; rep < 4; ++rep) {
    int e = tid + rep*256;
    int r = e >> 7, q = e & 127;
    float sc;
    if (q >= klen) sc = NEGV;
    else {
      sc = 0.f;
      const float* kp = Kp + (size_t)q*H_;
      #pragma unroll 4
      for (int m = 0; m < H_; ++m) sc = fmaf(qr[r][m], kp[m], sc);
    }
    P[r][q] = sc;
  }
  __syncthreads();
  {
    int g = tid >> 5, l = tid & 31;
    float s0 = P[g][l], s1 = P[g][l+32], s2 = P[g][l+64], s3 = P[g][l+96];
    float m0 = fmaxf(fmaxf(s0,s1), fmaxf(s2,s3));
    for (int o = 16; o > 0; o >>= 1) m0 = fmaxf(m0, __shfl_xor(m0, o, 32));
    float e0 = expf(s0-m0), e1 = expf(s1-m0), e2 = expf(s2-m0), e3 = expf(s3-m0);
    float sum = e0+e1+e2+e3;
    for (int o = 16; o > 0; o >>= 1) sum += __shfl_xor(sum, o, 32);
    P[g][l] = e0; P[g][l+32] = e1; P[g][l+64] = e2; P[g][l+96] = e3;
    if (l == 0) rinv[g] = 1.f / sum;
  }
  __syncthreads();
  float* out = ATT + ((size_t)(d*B_ + b)*T_ + r0) * H_;
  for (int e = tid; e < 8*H_; e += 256) {
    int r = e / H_, h = e % H_;
    float a = 0.f;
    const float* kp = Kp + h;
    #pragma unroll 4
    for (int q = 0; q < T_; ++q) a = fmaf(P[r][q], kp[(size_t)q*H_], a);
    out[(size_t)r*H_ + h] = a * rinv[r];
  }
}

// ---------------- pool stage 1 ----------------
__global__ __launch_bounds__(320) void k_pool(const float* __restrict__ H,
    const int* __restrict__ plen, const int* __restrict__ hlen,
    float* __restrict__ psum, float* __restrict__ pmax)
{
  int chain = blockIdx.x; int s = chain >> 5, b = chain & 31;
  int c = blockIdx.y; int t0 = c * 16;
  int len = (s == 0 ? plen[b] : hlen[b]);
  int tid = threadIdx.x;
  __shared__ float buf[16*H_];
  const float* hp = H + (size_t)chain*T_*H_ + (size_t)t0*H_;
  for (int i = tid; i < 16*H_; i += 320) buf[i] = hp[i];
  __syncthreads();
  if (tid < H_) {
    int tmax = len - t0; if (tmax > 16) tmax = 16;
    float sum = 0.f, mx = NEGV;
    for (int t = 0; t < tmax; ++t) { float x = buf[t*H_ + tid]; sum += x; mx = fmaxf(mx, x); }
    int o = (chain*8 + c)*H_ + tid;
    psum[o] = sum; pmax[o] = mx;
  }
}

// ---------------- pool stage 2 + classifier ----------------
__global__ __launch_bounds__(320) void k_classify(
    const float* __restrict__ psum, const float* __restrict__ pmax,
    const int* __restrict__ plen, const int* __restrict__ hlen,
    const float* __restrict__ w1t, const float* __restrict__ b1,
    const float* __restrict__ w2, const float* __restrict__ b2,
    float* __restrict__ out)
{
  int b = blockIdx.x;
  int tid = threadIdx.x;
  __shared__ float v[HG];
  __shared__ float hid[H_];
  for (int s = 0; s < 2; ++s) {
    int chain = s*B_ + b;
    int len = (s == 0 ? plen[b] : hlen[b]);
    if (tid < H_) {
      float sum = 0.f, mx = NEGV;
      #pragma unroll
      for (int c = 0; c < 8; ++c) {
        int o = (chain*8 + c)*H_ + tid;
        sum += psum[o]; mx = fmaxf(mx, pmax[o]);
      }
      v[s*600 + tid]       = sum / (float)len;
      v[s*600 + 300 + tid] = mx;
    }
  }
  __syncthreads();
  if (tid < H_) {
    float a0 = b1[tid], a1 = 0.f, a2 = 0.f, a3 = 0.f;
    for (int m = 0; m < HG; m += 4) {
      a0 = fmaf(v[m+0], w1t[(size_t)(m+0)*H_ + tid], a0);
      a1 = fmaf(v[m+1], w1t[(size_t)(m+1)*H_ + tid], a1);
      a2 = fmaf(v[m+2], w1t[(size_t)(m+2)*H_ + tid], a2);
      a3 = fmaf(v[m+3], w1t[(size_t)(m+3)*H_ + tid], a3);
    }
    hid[tid] = tanhf(a0 + a1 + a2 + a3);
  }
  __syncthreads();
  if (tid < 3) {
    float a = b2[tid];
    const float* wr = w2 + (size_t)tid*H_;
    for (int n = 0; n < H_; ++n) a = fmaf(hid[n], wr[n], a);
    out[b*3 + tid] = a;
  }
}

// ---------------- launch ----------------
extern "C" void kernel_launch(void* const* d_in, const int* in_sizes, int n_in,
                              void* d_out, int out_size, void* d_ws, size_t ws_size,
                              hipStream_t stream) {
  const int*   prem    = (const int*)d_in[0];
  const int*   plen    = (const int*)d_in[1];
  const int*   hyp     = (const int*)d_in[2];
  const int*   hlen    = (const int*)d_in[3];
  const float* lg      = (const float*)d_in[4];
  const float* rg      = (const float*)d_in[5];
  const float* emb     = (const float*)d_in[6];
  const float* enc_wx  = (const float*)d_in[7];
  const float* enc_bx  = (const float*)d_in[8];
  const float* enc_uh  = (const float*)d_in[9];
  const float* enc_bh  = (const float*)d_in[10];
  const float* comp_wx = (const float*)d_in[11];
  const float* comp_bx = (const float*)d_in[12];
  const float* comp_uh = (const float*)d_in[13];
  const float* comp_bh = (const float*)d_in[14];
  const float* proj_w  = (const float*)d_in[15];
  const float* proj_b  = (const float*)d_in[16];
  const float* cls_w1  = (const float*)d_in[17];
  const float* cls_b1  = (const float*)d_in[18];
  const float* cls_w2  = (const float*)d_in[19];
  const float* cls_b2  = (const float*)d_in[20];
  float* outp = (float*)d_out;

  const size_t SZ_XG  = (size_t)2*B_*T_*HG;
  const size_t SZ_BTH = (size_t)2*B_*T_*H_;
  float* XG  = (float*)d_ws;    // enc-xg -> comp-xg
  float* PROJ= XG  + SZ_XG;
  float* H1  = PROJ+ SZ_BTH;
  float* CH  = H1  + SZ_BTH;    // c history; reused as ATT between scans
  float* FH  = CH  + SZ_BTH;
  float* UTE = FH  + SZ_BTH;
  float* UTC = UTE + (size_t)H_*H_;
  float* WP  = UTC + (size_t)H_*H_;
  float* W1T = WP  + (size_t)H_*900;
  float* PSUM= W1T + (size_t)HG*H_;
  float* PMAX= PSUM+ (size_t)64*8*H_;
  float* EW  = PMAX+ (size_t)64*8*H_;
  int*   EIDX = (int*)(EW + (size_t)64*ECAP);
  int*   CNT  = EIDX + (size_t)64*ECAP;
  int*   COFF = CNT  + 64*T_;
  int*   DEPTH= COFF + 64*T_;
  int*   HASP = DEPTH+ 64*T_;
  int*   MAXD = HASP + 64*T_;
  int*   LVLCNT = MAXD + 64;
  int*   WL   = LVLCNT + LMAX;
  float* ATT  = CH;

  hipMemsetAsync(LVLCNT, 0, LMAX*sizeof(int), stream);
  // 1. weight prep + graph analysis
  k_prep_all<<<(720000 + 255)/256, 256, 0, stream>>>(enc_uh, comp_uh, proj_w, cls_w1, UTE, UTC, WP, W1T);
  k_build<<<64, 256, 0, stream>>>(lg, rg, CNT, COFF, EIDX, EW, HASP, DEPTH, MAXD, LVLCNT, WL);
  // 2. enc xg = emb-gather @ enc_wx^T + enc_bx, then gate precompute in place
  k_gemm<128,256><<<dim3(10, 64), 256, 0, stream>>>(nullptr, nullptr, prem, hyp, emb,
      enc_wx, enc_bx, XG, HG, H_, 0, 1);
  k_gates<<<(2*B_*T_*H_ + 255)/256, 256, 0, stream>>>(XG, enc_bh);
  // 3. enc tree scan (per-level launches)
  for (int L = 0; L < LMAX; ++L)
    k_level<<<640, 1024, 0, stream>>>(XG, UTE, CNT, COFF, EIDX, EW, HASP, LVLCNT, WL, L, H1, CH, FH);
  k_tail<<<64, 320, 0, stream>>>(XG, UTE, CNT, COFF, EIDX, EW, HASP, DEPTH, MAXD, H1, CH, FH);
  // 4. attention (CH dead -> ATT)
  k_attention<<<dim3(2, B_, T_/8), 256, 0, stream>>>(H1, plen, hlen, ATT);
  // 5. proj = relu([H1|ATT|H1*ATT] @ WP^T + proj_b)
  k_gemm<64,128><<<dim3(3, 128), 128, 0, stream>>>(H1, ATT, nullptr, nullptr, nullptr,
      WP, proj_b, PROJ, H_, 900, 1, 2);
  // 6. comp xg = proj @ comp_wx^T + comp_bx, then gates
  k_gemm<128,256><<<dim3(10, 64), 256, 0, stream>>>(PROJ, nullptr, nullptr, nullptr, nullptr,
      comp_wx, comp_bx, XG, HG, H_, 0, 0);
  k_gates<<<(2*B_*T_*H_ + 255)/256, 256, 0, stream>>>(XG, comp_bh);
  // 7. comp tree scan
  for (int L = 0; L < LMAX; ++L)
    k_level<<<640, 1024, 0, stream>>>(XG, UTC, CNT, COFF, EIDX, EW, HASP, LVLCNT, WL, L, H1, CH, FH);
  k_tail<<<64, 320, 0, stream>>>(XG, UTC, CNT, COFF, EIDX, EW, HASP, DEPTH, MAXD, H1, CH, FH);
  // 8. pool + classifier
  k_pool<<<dim3(64, 8), 320, 0, stream>>>(H1, plen, hlen, PSUM, PMAX);
  k_classify<<<B_, 320, 0, stream>>>(PSUM, PMAX, plen, hlen, W1T, cls_b1, cls_w2, cls_b2, outp);
}

// Round 7
// 794.725 us; speedup vs baseline: 1.7492x; 1.3676x over previous
//
#include <hip/hip_runtime.h>
#include <math.h>

#define B_ 32
#define T_ 128
#define H_ 300
#define HG 1200   // 4*H
#define LMAX 10
#define WLCAP 8192
#define ECAP 2048
#define NEGV -10000000.0f

typedef __attribute__((ext_vector_type(8))) short bf16x8;
typedef __attribute__((ext_vector_type(4))) float f32x4;

__device__ __forceinline__ float sigm(float x){ return 1.f/(1.f+expf(-x)); }

__device__ __forceinline__ unsigned short f2bf(float x){
  union { float f; unsigned int u; } c; c.f = x;
  unsigned int u = c.u;
  return (unsigned short)((u + 0x7fffu + ((u >> 16) & 1u)) >> 16);
}
__device__ __forceinline__ float bf2f(unsigned short h){
  union { unsigned int u; float f; } c; c.u = ((unsigned int)h) << 16;
  return c.f;
}

// ---------------- fused weight prep ----------------
__global__ __launch_bounds__(256) void k_prep_all(
    const float* __restrict__ enc_uh, const float* __restrict__ comp_uh,
    const float* __restrict__ pw, const float* __restrict__ cw1,
    float* __restrict__ te, float* __restrict__ tc, float* __restrict__ wp, float* __restrict__ w1t)
{
  int i = blockIdx.x*256 + threadIdx.x;
  if (i < 90000) {                       // uh1 transposes: te/tc[m][k] = uh[1][k][m]
    int m = i / H_, k = i - m*H_;
    te[i] = enc_uh[H_*H_ + (size_t)k*H_ + m];
    tc[i] = comp_uh[H_*H_ + (size_t)k*H_ + m];
  } else if (i < 360000) {               // folded proj weight wp (300 x 900)
    int i2 = i - 90000;
    int n = i2 / 900, k = i2 - n*900;
    const float* r = pw + (size_t)n*HG;
    float v;
    if (k < 300)      v = r[k] + r[600+k];
    else if (k < 600) v = r[k] - r[k+300];
    else              v = r[k+300];
    wp[i2] = v;
  } else if (i < 720000) {               // w1t (1200 x 300): w1t[m][k] = cw1[k][m]
    int i2 = i - 360000;
    int m = i2 / H_, k = i2 - m*H_;
    w1t[i2] = cw1[(size_t)k*HG + m];
  }
}

// ---------------- graph analysis ----------------
__global__ __launch_bounds__(256) void k_build(const float* __restrict__ lg, const float* __restrict__ rg,
    int* __restrict__ cnt_g, int* __restrict__ coff_g, int* __restrict__ eidx_g, float* __restrict__ ew_g,
    int* __restrict__ hasp_g, int* __restrict__ depth_g, int* __restrict__ maxd_g,
    int* __restrict__ lvlcnt_g, int* __restrict__ wl_g)
{
  int chain = blockIdx.x; int s = chain >> 5, b = chain & 31;
  const float* graph = (s ? rg : lg) + (size_t)b*T_*T_;
  int tid = threadIdx.x;
  __shared__ int cnt[T_], coff[T_], depth[T_], hasp[T_];
  __shared__ short eidx[ECAP];
  __shared__ float ew[ECAP];
  __shared__ int etot_s;
  if (tid < T_) hasp[tid] = 0;
  if (tid < T_) {
    int j = tid, c = 0;
    const float* gr = graph + (size_t)j*T_;
    for (int t = 0; t < j; ++t) c += (gr[t] != 0.f) ? 1 : 0;
    cnt[j] = c;
  }
  __syncthreads();
  if (tid == 0) { int a = 0; for (int j = 0; j < T_; ++j) { coff[j] = a; a += cnt[j]; } etot_s = a; }
  __syncthreads();
  if (tid < T_) {
    int j = tid, p = coff[j];
    const float* gr = graph + (size_t)j*T_;
    for (int t = 0; t < j; ++t) {
      float g = gr[t];
      if (g != 0.f && p < ECAP) { eidx[p] = (short)t; ew[p] = g; hasp[t] = 1; ++p; }
    }
  }
  __syncthreads();
  if (tid == 0) {
    int md = 0;
    for (int j = 0; j < T_; ++j) {
      int d = 0, e0 = coff[j], e1 = coff[j] + cnt[j];
      if (e1 > ECAP) e1 = ECAP;
      for (int k = e0; k < e1; ++k) { int dd = depth[eidx[k]] + 1; d = dd > d ? dd : d; }
      depth[j] = d; md = d > md ? d : md;
    }
    maxd_g[chain] = md;
  }
  __syncthreads();
  int base = chain * T_;
  if (tid < T_) {
    cnt_g[base+tid] = cnt[tid]; coff_g[base+tid] = coff[tid];
    hasp_g[base+tid] = hasp[tid]; depth_g[base+tid] = depth[tid];
    int L = depth[tid];
    if (L < LMAX) { int p = atomicAdd(&lvlcnt_g[L], 1); wl_g[L*WLCAP + p] = (chain << 8) | tid; }
  }
  int etot = etot_s; if (etot > ECAP) etot = ECAP;
  for (int i = tid; i < etot; i += 256) { eidx_g[chain*ECAP + i] = eidx[i]; ew_g[chain*ECAP + i] = ew[i]; }
}

// ---------------- gate precompute, in-place over XG ----------------
__global__ __launch_bounds__(256) void k_gates(float* __restrict__ xg, const float* __restrict__ bhv)
{
  int i = blockIdx.x*256 + threadIdx.x;
  if (i >= 2*B_*T_*H_) return;
  int bt = i / H_, e = i - bt*H_;
  float* xp = xg + (size_t)bt*HG;
  float x0 = xp[e], x1 = xp[H_+e], x2 = xp[2*H_+e], x3 = xp[3*H_+e];
  xp[e]       = sigm(x0 + bhv[e]) * tanhf(x3 + bhv[3*H_+e]);
  xp[H_+e]    = x1 + bhv[H_+e];
  xp[2*H_+e]  = sigm(x2 + bhv[2*H_+e]);
}

// ---------------- per-level tree-LSTM ----------------
__global__ __launch_bounds__(1024) void k_level(
    const float* __restrict__ xg, const float* __restrict__ uh1T,
    const int* __restrict__ cnt_g, const int* __restrict__ coff_g,
    const int* __restrict__ eidx_g, const float* __restrict__ ew_g,
    const int* __restrict__ hasp_g, const int* __restrict__ lvlcnt_g, const int* __restrict__ wl_g,
    int L, float* __restrict__ hout, float* __restrict__ chist, float* __restrict__ fh)
{
  int count = lvlcnt_g[L];
  int nblk = (count + 3) >> 2;
  int tid = threadIdx.x;
  __shared__ float h_s[4][H_];
  __shared__ float psum[3][4][H_];
  __shared__ int nodes[4];
  __shared__ int anyp;
  for (int blk = blockIdx.x; blk < nblk; blk += gridDim.x) {
    int base = blk * 4;
    int nn = count - base; if (nn > 4) nn = 4;
    if (tid == 0) anyp = 0;
    __syncthreads();
    if (tid < 4) {
      int pk = (tid < nn) ? wl_g[L*WLCAP + base + tid] : -1;
      nodes[tid] = pk;
      if (pk >= 0 && hasp_g[(pk >> 8)*T_ + (pk & 255)]) atomicAdd(&anyp, 1);
    }
    __syncthreads();
    for (int w = tid; w < nn*H_; w += 1024) {
      int n = w / H_, e = w - n*H_;
      int pk = nodes[n]; int chain = pk >> 8, j = pk & 255;
      size_t cb = (size_t)chain*T_*H_, xb = (size_t)chain*T_*HG;
      const float* xp = xg + xb + (size_t)j*HG;
      float iu = xp[e], x1b = xp[H_+e], og = xp[2*H_+e];
      float acc = iu;
      int c0 = coff_g[chain*T_+j], c1 = c0 + cnt_g[chain*T_+j];
      const int* ei = eidx_g + chain*ECAP;
      const float* ewp = ew_g + chain*ECAP;
      for (int k = c0; k < c1; ++k) {
        int t = ei[k];
        acc += ewp[k] * sigm(x1b + fh[cb + (size_t)t*H_ + e]) * chist[cb + (size_t)t*H_ + e];
      }
      chist[cb + (size_t)j*H_ + e] = acc;
      float hv = og * tanhf(acc);
      hout[cb + (size_t)j*H_ + e] = hv;
      h_s[n][e] = hv;
    }
    __syncthreads();
    if (anyp > 0) {
      if (tid < 3*H_) {
        int g = tid / H_, e = tid - g*H_;
        float a0=0.f, a1=0.f, a2=0.f, a3=0.f;
        const float* up = uh1T + e;
        int m0 = g*100, m1 = m0 + 100;
        #pragma unroll 4
        for (int m = m0; m < m1; ++m) {
          float u = up[(size_t)m*H_];
          a0 = fmaf(u, h_s[0][m], a0);
          a1 = fmaf(u, h_s[1][m], a1);
          a2 = fmaf(u, h_s[2][m], a2);
          a3 = fmaf(u, h_s[3][m], a3);
        }
        psum[g][0][e]=a0; psum[g][1][e]=a1; psum[g][2][e]=a2; psum[g][3][e]=a3;
      }
      __syncthreads();
      for (int w = tid; w < nn*H_; w += 1024) {
        int n = w / H_, e = w - n*H_;
        int pk = nodes[n]; int chain = pk >> 8, j = pk & 255;
        if (hasp_g[chain*T_+j]) {
          size_t cb = (size_t)chain*T_*H_;
          fh[cb + (size_t)j*H_ + e] = psum[0][n][e] + psum[1][n][e] + psum[2][n][e];
        }
      }
    }
    __syncthreads();
  }
}

// ---------------- serial tail for rare deep graphs ----------------
__global__ __launch_bounds__(320) void k_tail(const float* __restrict__ xg,
    const float* __restrict__ uh1T, const int* __restrict__ cnt_g, const int* __restrict__ coff_g,
    const int* __restrict__ eidx_g, const float* __restrict__ ew_g, const int* __restrict__ hasp_g,
    const int* __restrict__ depth_g, const int* __restrict__ maxd_g,
    float* __restrict__ hout, float* __restrict__ chist, float* __restrict__ fh)
{
  int chain = blockIdx.x;
  if (maxd_g[chain] < LMAX) return;
  int tid = threadIdx.x;
  bool act = tid < H_;
  __shared__ float h_lds[H_];
  size_t cb = (size_t)chain*T_*H_, xb = (size_t)chain*T_*HG;
  const int* ei = eidx_g + chain*ECAP;
  const float* ewp = ew_g + chain*ECAP;
  for (int j = 0; j < T_; ++j) {
    if (depth_g[chain*T_+j] < LMAX) continue;
    if (act) {
      const float* xp = xg + xb + (size_t)j*HG;
      float iu = xp[tid], x1b = xp[H_+tid], og = xp[2*H_+tid];
      float acc = iu;
      int c0 = coff_g[chain*T_+j], c1 = c0 + cnt_g[chain*T_+j];
      for (int k = c0; k < c1; ++k) {
        int t = ei[k];
        acc += ewp[k] * sigm(x1b + fh[cb + (size_t)t*H_ + tid]) * chist[cb + (size_t)t*H_ + tid];
      }
      chist[cb + (size_t)j*H_ + tid] = acc;
      float hv = og * tanhf(acc);
      hout[cb + (size_t)j*H_ + tid] = hv;
      h_lds[tid] = hv;
    }
    __syncthreads();
    if (hasp_g[chain*T_+j] && act) {
      float a = 0.f;
      const float* up = uh1T + tid;
      #pragma unroll 4
      for (int m = 0; m < H_; ++m) a = fmaf(up[(size_t)m*H_], h_lds[m], a);
      fh[cb + (size_t)j*H_ + tid] = a;
    }
    __syncthreads();
  }
}

// ---------------- split-bf16 MFMA GEMM: C[8192,N] = act(A[8192,K] @ W[N,K]^T + bias) ----------------
// a*b ~= ah*bh + ah*bl + al*bh (fp32-quality). 128x128 tile, 4 waves, each 64x64.
// MODE 0: A plain; MODE 1: A=emb[tok]; MODE 2: A=[H1|ATT|H1*ATT] over K=900.
#define LDT 40   // padded LDS row stride in bf16 (16B-aligned frags, 2-way-free banks)
template<int MODE>
__global__ __launch_bounds__(256) void k_gemm_mfma(
    const float* __restrict__ A, const float* __restrict__ A2,
    const int* __restrict__ ptok, const int* __restrict__ htok, const float* __restrict__ embr,
    const float* __restrict__ W, const float* __restrict__ bias, float* __restrict__ C,
    int N, int K, int act)
{
  __shared__ unsigned short lds[4][128*LDT];   // Ah, Al, Wh, Wl  (40 KB)
  int tid = threadIdx.x;
  int bn = blockIdx.x * 128, bm = blockIdx.y * 128;
  int lane = tid & 63, wave = tid >> 6;
  int wr = (wave >> 1) * 64, wc = (wave & 1) * 64;   // wave sub-tile origin
  int lrow = lane & 15, koff = (lane >> 4) * 8;

  // staging: thread t -> row t>>1, k-quads (t&1)*16 + {0,4,8,12}
  int srow = tid >> 1;
  int kq0 = (tid & 1) * 16;
  const float* Ap; const float* Ap2 = nullptr;
  if (MODE == 1) { int ar = bm + srow; int tok = (ar < 4096) ? ptok[ar] : htok[ar-4096]; Ap = embr + (size_t)tok*H_; }
  else if (MODE == 2) { Ap = A + (size_t)(bm+srow)*H_; Ap2 = A2 + (size_t)(bm+srow)*H_; }
  else Ap = A + (size_t)(bm+srow)*K;
  int wrow = bn + srow;
  const float* Wp = (wrow < N) ? W + (size_t)wrow*K : nullptr;

  float4 ga[4], gw[4], gx[4];
  int sg[4];
  auto issue = [&](int t){
    int kb = t * 32;
    #pragma unroll
    for (int i = 0; i < 4; ++i) {
      int gk = kb + kq0 + i*4;
      ga[i] = make_float4(0.f,0.f,0.f,0.f); gw[i] = make_float4(0.f,0.f,0.f,0.f);
      if (MODE == 2) sg[i] = 0;
      if (gk < K) {                       // K%4==0 so full float4 is in-range
        if (MODE == 2) {
          int s = gk / 300, kk = gk - s*300; sg[i] = s;
          if (s == 0)      ga[i] = *(const float4*)(Ap + kk);
          else if (s == 1) ga[i] = *(const float4*)(Ap2 + kk);
          else { ga[i] = *(const float4*)(Ap + kk); gx[i] = *(const float4*)(Ap2 + kk); }
        } else ga[i] = *(const float4*)(Ap + gk);
        if (Wp) gw[i] = *(const float4*)(Wp + gk);
      }
    }
  };
  auto commit = [&](){
    #pragma unroll
    for (int i = 0; i < 4; ++i) {
      float4 v = ga[i];
      if (MODE == 2 && sg[i] == 2) { v.x*=gx[i].x; v.y*=gx[i].y; v.z*=gx[i].z; v.w*=gx[i].w; }
      ushort4 h, l;
      h.x=f2bf(v.x); h.y=f2bf(v.y); h.z=f2bf(v.z); h.w=f2bf(v.w);
      l.x=f2bf(v.x-bf2f(h.x)); l.y=f2bf(v.y-bf2f(h.y)); l.z=f2bf(v.z-bf2f(h.z)); l.w=f2bf(v.w-bf2f(h.w));
      int off = srow*LDT + kq0 + i*4;
      *(ushort4*)&lds[0][off] = h;
      *(ushort4*)&lds[1][off] = l;
      float4 w = gw[i];
      h.x=f2bf(w.x); h.y=f2bf(w.y); h.z=f2bf(w.z); h.w=f2bf(w.w);
      l.x=f2bf(w.x-bf2f(h.x)); l.y=f2bf(w.y-bf2f(h.y)); l.z=f2bf(w.z-bf2f(h.z)); l.w=f2bf(w.w-bf2f(h.w));
      *(ushort4*)&lds[2][off] = h;
      *(ushort4*)&lds[3][off] = l;
    }
  };

  f32x4 acc[4][4];
  #pragma unroll
  for (int m = 0; m < 4; ++m)
    #pragma unroll
    for (int n = 0; n < 4; ++n) acc[m][n] = (f32x4){0.f,0.f,0.f,0.f};

  int NT = (K + 31) / 32;
  issue(0); commit();
  __syncthreads();
  for (int t = 0; t < NT; ++t) {
    bool more = (t+1 < NT);
    // fragment reads (A: row=lane&15 +16m, k=koff..+7 ; B(=W): col=lane&15 +16n)
    bf16x8 ah[4], al[4], bh[4], bl[4];
    #pragma unroll
    for (int m = 0; m < 4; ++m) {
      int o = (wr + m*16 + lrow)*LDT + koff;
      ah[m] = *(const bf16x8*)&lds[0][o];
      al[m] = *(const bf16x8*)&lds[1][o];
    }
    #pragma unroll
    for (int n = 0; n < 4; ++n) {
      int o = (wc + n*16 + lrow)*LDT + koff;
      bh[n] = *(const bf16x8*)&lds[2][o];
      bl[n] = *(const bf16x8*)&lds[3][o];
    }
    if (more) issue(t+1);
    __syncthreads();            // all waves' frag reads done before overwrite
    if (more) commit();
    #pragma unroll
    for (int m = 0; m < 4; ++m)
      #pragma unroll
      for (int n = 0; n < 4; ++n) {
        acc[m][n] = __builtin_amdgcn_mfma_f32_16x16x32_bf16(ah[m], bh[n], acc[m][n], 0,0,0);
        acc[m][n] = __builtin_amdgcn_mfma_f32_16x16x32_bf16(ah[m], bl[n], acc[m][n], 0,0,0);
        acc[m][n] = __builtin_amdgcn_mfma_f32_16x16x32_bf16(al[m], bh[n], acc[m][n], 0,0,0);
      }
    __syncthreads();            // commit visible before next frag reads
  }
  // epilogue: D row=(lane>>4)*4+r, col=lane&15  [m89-verified]
  #pragma unroll
  for (int m = 0; m < 4; ++m) {
    int row0 = bm + wr + m*16 + (lane >> 4)*4;
    #pragma unroll
    for (int n = 0; n < 4; ++n) {
      int col = bn + wc + n*16 + (lane & 15);
      if (col < N) {
        float bv = bias[col];
        #pragma unroll
        for (int r = 0; r < 4; ++r) {
          float v = acc[m][n][r] + bv;
          if (act) v = fmaxf(v, 0.f);
          C[(size_t)(row0 + r)*N + col] = v;
        }
      }
    }
  }
}

// ---------------- fused attention ----------------
__global__ __launch_bounds__(256) void k_attention(const float* __restrict__ H,
    const int* __restrict__ plen, const int* __restrict__ hlen, float* __restrict__ ATT)
{
  int d = blockIdx.x;
  int b = blockIdx.y;
  int r0 = blockIdx.z * 8;
  int qs = d, ks = 1 - d;
  int klen = (d == 0 ? hlen[b] : plen[b]);
  const float* Q  = H + ((size_t)(qs*B_ + b)*T_) * H_;
  const float* Kp = H + ((size_t)(ks*B_ + b)*T_) * H_;
  __shared__ float qr[8][H_];
  __shared__ float P[8][T_];
  __shared__ float rinv[8];
  int tid = threadIdx.x;

  for (int e = tid; e < 8*H_; e += 256) {
    int r = e / H_, m = e % H_;
    qr[r][m] = Q[(size_t)(r0 + r)*H_ + m];
  }
  __syncthreads();
  #pragma unroll
  for (int rep = 0; rep < 4; ++rep) {
    int e = tid + rep*256;
    int r = e >> 7, q = e & 127;
    float sc;
    if (q >= klen) sc = NEGV;
    else {
      sc = 0.f;
      const float* kp = Kp + (size_t)q*H_;
      #pragma unroll 4
      for (int m = 0; m < H_; ++m) sc = fmaf(qr[r][m], kp[m], sc);
    }
    P[r][q] = sc;
  }
  __syncthreads();
  {
    int g = tid >> 5, l = tid & 31;
    float s0 = P[g][l], s1 = P[g][l+32], s2 = P[g][l+64], s3 = P[g][l+96];
    float m0 = fmaxf(fmaxf(s0,s1), fmaxf(s2,s3));
    for (int o = 16; o > 0; o >>= 1) m0 = fmaxf(m0, __shfl_xor(m0, o, 32));
    float e0 = expf(s0-m0), e1 = expf(s1-m0), e2 = expf(s2-m0), e3 = expf(s3-m0);
    float sum = e0+e1+e2+e3;
    for (int o = 16; o > 0; o >>= 1) sum += __shfl_xor(sum, o, 32);
    P[g][l] = e0; P[g][l+32] = e1; P[g][l+64] = e2; P[g][l+96] = e3;
    if (l == 0) rinv[g] = 1.f / sum;
  }
  __syncthreads();
  float* out = ATT + ((size_t)(d*B_ + b)*T_ + r0) * H_;
  for (int e = tid; e < 8*H_; e += 256) {
    int r = e / H_, h = e % H_;
    float a = 0.f;
    const float* kp = Kp + h;
    #pragma unroll 4
    for (int q = 0; q < T_; ++q) a = fmaf(P[r][q], kp[(size_t)q*H_], a);
    out[(size_t)r*H_ + h] = a * rinv[r];
  }
}

// ---------------- pool stage 1 ----------------
__global__ __launch_bounds__(320) void k_pool(const float* __restrict__ H,
    const int* __restrict__ plen, const int* __restrict__ hlen,
    float* __restrict__ psum, float* __restrict__ pmax)
{
  int chain = blockIdx.x; int s = chain >> 5, b = chain & 31;
  int c = blockIdx.y; int t0 = c * 16;
  int len = (s == 0 ? plen[b] : hlen[b]);
  int tid = threadIdx.x;
  __shared__ float buf[16*H_];
  const float* hp = H + (size_t)chain*T_*H_ + (size_t)t0*H_;
  for (int i = tid; i < 16*H_; i += 320) buf[i] = hp[i];
  __syncthreads();
  if (tid < H_) {
    int tmax = len - t0; if (tmax > 16) tmax = 16;
    float sum = 0.f, mx = NEGV;
    for (int t = 0; t < tmax; ++t) { float x = buf[t*H_ + tid]; sum += x; mx = fmaxf(mx, x); }
    int o = (chain*8 + c)*H_ + tid;
    psum[o] = sum; pmax[o] = mx;
  }
}

// ---------------- pool stage 2 + classifier ----------------
__global__ __launch_bounds__(320) void k_classify(
    const float* __restrict__ psum, const float* __restrict__ pmax,
    const int* __restrict__ plen, const int* __restrict__ hlen,
    const float* __restrict__ w1t, const float* __restrict__ b1,
    const float* __restrict__ w2, const float* __restrict__ b2,
    float* __restrict__ out)
{
  int b = blockIdx.x;
  int tid = threadIdx.x;
  __shared__ float v[HG];
  __shared__ float hid[H_];
  for (int s = 0; s < 2; ++s) {
    int chain = s*B_ + b;
    int len = (s == 0 ? plen[b] : hlen[b]);
    if (tid < H_) {
      float sum = 0.f, mx = NEGV;
      #pragma unroll
      for (int c = 0; c < 8; ++c) {
        int o = (chain*8 + c)*H_ + tid;
        sum += psum[o]; mx = fmaxf(mx, pmax[o]);
      }
      v[s*600 + tid]       = sum / (float)len;
      v[s*600 + 300 + tid] = mx;
    }
  }
  __syncthreads();
  if (tid < H_) {
    float a0 = b1[tid], a1 = 0.f, a2 = 0.f, a3 = 0.f;
    for (int m = 0; m < HG; m += 4) {
      a0 = fmaf(v[m+0], w1t[(size_t)(m+0)*H_ + tid], a0);
      a1 = fmaf(v[m+1], w1t[(size_t)(m+1)*H_ + tid], a1);
      a2 = fmaf(v[m+2], w1t[(size_t)(m+2)*H_ + tid], a2);
      a3 = fmaf(v[m+3], w1t[(size_t)(m+3)*H_ + tid], a3);
    }
    hid[tid] = tanhf(a0 + a1 + a2 + a3);
  }
  __syncthreads();
  if (tid < 3) {
    float a = b2[tid];
    const float* wr = w2 + (size_t)tid*H_;
    for (int n = 0; n < H_; ++n) a = fmaf(hid[n], wr[n], a);
    out[b*3 + tid] = a;
  }
}

// ---------------- launch ----------------
extern "C" void kernel_launch(void* const* d_in, const int* in_sizes, int n_in,
                              void* d_out, int out_size, void* d_ws, size_t ws_size,
                              hipStream_t stream) {
  const int*   prem    = (const int*)d_in[0];
  const int*   plen    = (const int*)d_in[1];
  const int*   hyp     = (const int*)d_in[2];
  const int*   hlen    = (const int*)d_in[3];
  const float* lg      = (const float*)d_in[4];
  const float* rg      = (const float*)d_in[5];
  const float* emb     = (const float*)d_in[6];
  const float* enc_wx  = (const float*)d_in[7];
  const float* enc_bx  = (const float*)d_in[8];
  const float* enc_uh  = (const float*)d_in[9];
  const float* enc_bh  = (const float*)d_in[10];
  const float* comp_wx = (const float*)d_in[11];
  const float* comp_bx = (const float*)d_in[12];
  const float* comp_uh = (const float*)d_in[13];
  const float* comp_bh = (const float*)d_in[14];
  const float* proj_w  = (const float*)d_in[15];
  const float* proj_b  = (const float*)d_in[16];
  const float* cls_w1  = (const float*)d_in[17];
  const float* cls_b1  = (const float*)d_in[18];
  const float* cls_w2  = (const float*)d_in[19];
  const float* cls_b2  = (const float*)d_in[20];
  float* outp = (float*)d_out;

  const size_t SZ_XG  = (size_t)2*B_*T_*HG;
  const size_t SZ_BTH = (size_t)2*B_*T_*H_;
  float* XG  = (float*)d_ws;    // enc-xg -> comp-xg
  float* PROJ= XG  + SZ_XG;
  float* H1  = PROJ+ SZ_BTH;
  float* CH  = H1  + SZ_BTH;    // c history; reused as ATT between scans
  float* FH  = CH  + SZ_BTH;
  float* UTE = FH  + SZ_BTH;
  float* UTC = UTE + (size_t)H_*H_;
  float* WP  = UTC + (size_t)H_*H_;
  float* W1T = WP  + (size_t)H_*900;
  float* PSUM= W1T + (size_t)HG*H_;
  float* PMAX= PSUM+ (size_t)64*8*H_;
  float* EW  = PMAX+ (size_t)64*8*H_;
  int*   EIDX = (int*)(EW + (size_t)64*ECAP);
  int*   CNT  = EIDX + (size_t)64*ECAP;
  int*   COFF = CNT  + 64*T_;
  int*   DEPTH= COFF + 64*T_;
  int*   HASP = DEPTH+ 64*T_;
  int*   MAXD = HASP + 64*T_;
  int*   LVLCNT = MAXD + 64;
  int*   WL   = LVLCNT + LMAX;
  float* ATT  = CH;

  hipMemsetAsync(LVLCNT, 0, LMAX*sizeof(int), stream);
  // 1. weight prep + graph analysis
  k_prep_all<<<(720000 + 255)/256, 256, 0, stream>>>(enc_uh, comp_uh, proj_w, cls_w1, UTE, UTC, WP, W1T);
  k_build<<<64, 256, 0, stream>>>(lg, rg, CNT, COFF, EIDX, EW, HASP, DEPTH, MAXD, LVLCNT, WL);
  // 2. enc xg = emb-gather @ enc_wx^T + enc_bx (split-bf16 MFMA), then gates
  k_gemm_mfma<1><<<dim3(10, 64), 256, 0, stream>>>(nullptr, nullptr, prem, hyp, emb,
      enc_wx, enc_bx, XG, HG, H_, 0);
  k_gates<<<(2*B_*T_*H_ + 255)/256, 256, 0, stream>>>(XG, enc_bh);
  // 3. enc tree scan (per-level launches)
  for (int L = 0; L < LMAX; ++L)
    k_level<<<640, 1024, 0, stream>>>(XG, UTE, CNT, COFF, EIDX, EW, HASP, LVLCNT, WL, L, H1, CH, FH);
  k_tail<<<64, 320, 0, stream>>>(XG, UTE, CNT, COFF, EIDX, EW, HASP, DEPTH, MAXD, H1, CH, FH);
  // 4. attention (CH dead -> ATT)
  k_attention<<<dim3(2, B_, T_/8), 256, 0, stream>>>(H1, plen, hlen, ATT);
  // 5. proj = relu([H1|ATT|H1*ATT] @ WP^T + proj_b)
  k_gemm_mfma<2><<<dim3(3, 64), 256, 0, stream>>>(H1, ATT, nullptr, nullptr, nullptr,
      WP, proj_b, PROJ, H_, 900, 1);
  // 6. comp xg = proj @ comp_wx^T + comp_bx, then gates
  k_gemm_mfma<0><<<dim3(10, 64), 256, 0, stream>>>(PROJ, nullptr, nullptr, nullptr, nullptr,
      comp_wx, comp_bx, XG, HG, H_, 0);
  k_gates<<<(2*B_*T_*H_ + 255)/256, 256, 0, stream>>>(XG, comp_bh);
  // 7. comp tree scan
  for (int L = 0; L < LMAX; ++L)
    k_level<<<640, 1024, 0, stream>>>(XG, UTC, CNT, COFF, EIDX, EW, HASP, LVLCNT, WL, L, H1, CH, FH);
  k_tail<<<64, 320, 0, stream>>>(XG, UTC, CNT, COFF, EIDX, EW, HASP, DEPTH, MAXD, H1, CH, FH);
  // 8. pool + classifier
  k_pool<<<dim3(64, 8), 320, 0, stream>>>(H1, plen, hlen, PSUM, PMAX);
  k_classify<<<B_, 320, 0, stream>>>(PSUM, PMAX, plen, hlen, W1T, cls_b1, cls_w2, cls_b2, outp);
}

// Round 8
// 717.295 us; speedup vs baseline: 1.9381x; 1.1079x over previous
//
#include <hip/hip_runtime.h>
#include <math.h>

#define B_ 32
#define T_ 128
#define H_ 300
#define HG 1200   // 4*H
#define LMAX 10
#define WLCAP 8192
#define ECAP 2048
#define NEGV -10000000.0f

typedef __attribute__((ext_vector_type(8))) short bf16x8;
typedef __attribute__((ext_vector_type(4))) float f32x4;
typedef unsigned short ushort_t;

__device__ __forceinline__ float sigm(float x){ return 1.f/(1.f+expf(-x)); }

__device__ __forceinline__ unsigned short f2bf(float x){
  union { float f; unsigned int u; } c; c.f = x;
  unsigned int u = c.u;
  return (unsigned short)((u + 0x7fffu + ((u >> 16) & 1u)) >> 16);
}
__device__ __forceinline__ float bf2f(unsigned short h){
  union { unsigned int u; float f; } c; c.u = ((unsigned int)h) << 16;
  return c.f;
}

// ---------------- fused weight prep ----------------
__global__ __launch_bounds__(256) void k_prep_all(
    const float* __restrict__ enc_uh, const float* __restrict__ comp_uh,
    const float* __restrict__ pw, const float* __restrict__ cw1,
    float* __restrict__ te, float* __restrict__ tc, float* __restrict__ wp, float* __restrict__ w1t)
{
  int i = blockIdx.x*256 + threadIdx.x;
  if (i < 90000) {                       // uh1 transposes: te/tc[m][k] = uh[1][k][m]
    int m = i / H_, k = i - m*H_;
    te[i] = enc_uh[H_*H_ + (size_t)k*H_ + m];
    tc[i] = comp_uh[H_*H_ + (size_t)k*H_ + m];
  } else if (i < 360000) {               // folded proj weight wp (300 x 900)
    int i2 = i - 90000;
    int n = i2 / 900, k = i2 - n*900;
    const float* r = pw + (size_t)n*HG;
    float v;
    if (k < 300)      v = r[k] + r[600+k];
    else if (k < 600) v = r[k] - r[k+300];
    else              v = r[k+300];
    wp[i2] = v;
  } else if (i < 720000) {               // w1t (1200 x 300): w1t[m][k] = cw1[k][m]
    int i2 = i - 360000;
    int m = i2 / H_, k = i2 - m*H_;
    w1t[i2] = cw1[(size_t)k*HG + m];
  }
}

// ---------------- graph analysis ----------------
__global__ __launch_bounds__(256) void k_build(const float* __restrict__ lg, const float* __restrict__ rg,
    int* __restrict__ cnt_g, int* __restrict__ coff_g, int* __restrict__ eidx_g, float* __restrict__ ew_g,
    int* __restrict__ hasp_g, int* __restrict__ depth_g, int* __restrict__ maxd_g,
    int* __restrict__ lvlcnt_g, int* __restrict__ wl_g)
{
  int chain = blockIdx.x; int s = chain >> 5, b = chain & 31;
  const float* graph = (s ? rg : lg) + (size_t)b*T_*T_;
  int tid = threadIdx.x;
  __shared__ int cnt[T_], coff[T_], depth[T_], hasp[T_];
  __shared__ short eidx[ECAP];
  __shared__ float ew[ECAP];
  __shared__ int etot_s;
  if (tid < T_) hasp[tid] = 0;
  if (tid < T_) {
    int j = tid, c = 0;
    const float* gr = graph + (size_t)j*T_;
    for (int t = 0; t < j; ++t) c += (gr[t] != 0.f) ? 1 : 0;
    cnt[j] = c;
  }
  __syncthreads();
  if (tid == 0) { int a = 0; for (int j = 0; j < T_; ++j) { coff[j] = a; a += cnt[j]; } etot_s = a; }
  __syncthreads();
  if (tid < T_) {
    int j = tid, p = coff[j];
    const float* gr = graph + (size_t)j*T_;
    for (int t = 0; t < j; ++t) {
      float g = gr[t];
      if (g != 0.f && p < ECAP) { eidx[p] = (short)t; ew[p] = g; hasp[t] = 1; ++p; }
    }
  }
  __syncthreads();
  if (tid == 0) {
    int md = 0;
    for (int j = 0; j < T_; ++j) {
      int d = 0, e0 = coff[j], e1 = coff[j] + cnt[j];
      if (e1 > ECAP) e1 = ECAP;
      for (int k = e0; k < e1; ++k) { int dd = depth[eidx[k]] + 1; d = dd > d ? dd : d; }
      depth[j] = d; md = d > md ? d : md;
    }
    maxd_g[chain] = md;
  }
  __syncthreads();
  int base = chain * T_;
  if (tid < T_) {
    cnt_g[base+tid] = cnt[tid]; coff_g[base+tid] = coff[tid];
    hasp_g[base+tid] = hasp[tid]; depth_g[base+tid] = depth[tid];
    int L = depth[tid];
    if (L < LMAX) { int p = atomicAdd(&lvlcnt_g[L], 1); wl_g[L*WLCAP + p] = (chain << 8) | tid; }
  }
  int etot = etot_s; if (etot > ECAP) etot = ECAP;
  for (int i = tid; i < etot; i += 256) { eidx_g[chain*ECAP + i] = eidx[i]; ew_g[chain*ECAP + i] = ew[i]; }
}

// ---------------- gate precompute, in-place over XG ----------------
__global__ __launch_bounds__(256) void k_gates(float* __restrict__ xg, const float* __restrict__ bhv)
{
  int i = blockIdx.x*256 + threadIdx.x;
  if (i >= 2*B_*T_*H_) return;
  int bt = i / H_, e = i - bt*H_;
  float* xp = xg + (size_t)bt*HG;
  float x0 = xp[e], x1 = xp[H_+e], x2 = xp[2*H_+e], x3 = xp[3*H_+e];
  xp[e]       = sigm(x0 + bhv[e]) * tanhf(x3 + bhv[3*H_+e]);
  xp[H_+e]    = x1 + bhv[H_+e];
  xp[2*H_+e]  = sigm(x2 + bhv[2*H_+e]);
}

// ---------------- per-level tree-LSTM ----------------
__global__ __launch_bounds__(1024) void k_level(
    const float* __restrict__ xg, const float* __restrict__ uh1T,
    const int* __restrict__ cnt_g, const int* __restrict__ coff_g,
    const int* __restrict__ eidx_g, const float* __restrict__ ew_g,
    const int* __restrict__ hasp_g, const int* __restrict__ lvlcnt_g, const int* __restrict__ wl_g,
    int L, float* __restrict__ hout, float* __restrict__ chist, float* __restrict__ fh)
{
  int count = lvlcnt_g[L];
  int nblk = (count + 3) >> 2;
  int tid = threadIdx.x;
  __shared__ float h_s[4][H_];
  __shared__ float psum[3][4][H_];
  __shared__ int nodes[4];
  __shared__ int anyp;
  for (int blk = blockIdx.x; blk < nblk; blk += gridDim.x) {
    int base = blk * 4;
    int nn = count - base; if (nn > 4) nn = 4;
    if (tid == 0) anyp = 0;
    __syncthreads();
    if (tid < 4) {
      int pk = (tid < nn) ? wl_g[L*WLCAP + base + tid] : -1;
      nodes[tid] = pk;
      if (pk >= 0 && hasp_g[(pk >> 8)*T_ + (pk & 255)]) atomicAdd(&anyp, 1);
    }
    __syncthreads();
    for (int w = tid; w < nn*H_; w += 1024) {
      int n = w / H_, e = w - n*H_;
      int pk = nodes[n]; int chain = pk >> 8, j = pk & 255;
      size_t cb = (size_t)chain*T_*H_, xb = (size_t)chain*T_*HG;
      const float* xp = xg + xb + (size_t)j*HG;
      float iu = xp[e], x1b = xp[H_+e], og = xp[2*H_+e];
      float acc = iu;
      int c0 = coff_g[chain*T_+j], c1 = c0 + cnt_g[chain*T_+j];
      const int* ei = eidx_g + chain*ECAP;
      const float* ewp = ew_g + chain*ECAP;
      for (int k = c0; k < c1; ++k) {
        int t = ei[k];
        acc += ewp[k] * sigm(x1b + fh[cb + (size_t)t*H_ + e]) * chist[cb + (size_t)t*H_ + e];
      }
      chist[cb + (size_t)j*H_ + e] = acc;
      float hv = og * tanhf(acc);
      hout[cb + (size_t)j*H_ + e] = hv;
      h_s[n][e] = hv;
    }
    __syncthreads();
    if (anyp > 0) {
      if (tid < 3*H_) {
        int g = tid / H_, e = tid - g*H_;
        float a0=0.f, a1=0.f, a2=0.f, a3=0.f;
        const float* up = uh1T + e;
        int m0 = g*100, m1 = m0 + 100;
        #pragma unroll 4
        for (int m = m0; m < m1; ++m) {
          float u = up[(size_t)m*H_];
          a0 = fmaf(u, h_s[0][m], a0);
          a1 = fmaf(u, h_s[1][m], a1);
          a2 = fmaf(u, h_s[2][m], a2);
          a3 = fmaf(u, h_s[3][m], a3);
        }
        psum[g][0][e]=a0; psum[g][1][e]=a1; psum[g][2][e]=a2; psum[g][3][e]=a3;
      }
      __syncthreads();
      for (int w = tid; w < nn*H_; w += 1024) {
        int n = w / H_, e = w - n*H_;
        int pk = nodes[n]; int chain = pk >> 8, j = pk & 255;
        if (hasp_g[chain*T_+j]) {
          size_t cb = (size_t)chain*T_*H_;
          fh[cb + (size_t)j*H_ + e] = psum[0][n][e] + psum[1][n][e] + psum[2][n][e];
        }
      }
    }
    __syncthreads();
  }
}

// ---------------- serial tail for rare deep graphs ----------------
__global__ __launch_bounds__(320) void k_tail(const float* __restrict__ xg,
    const float* __restrict__ uh1T, const int* __restrict__ cnt_g, const int* __restrict__ coff_g,
    const int* __restrict__ eidx_g, const float* __restrict__ ew_g, const int* __restrict__ hasp_g,
    const int* __restrict__ depth_g, const int* __restrict__ maxd_g,
    float* __restrict__ hout, float* __restrict__ chist, float* __restrict__ fh)
{
  int chain = blockIdx.x;
  if (maxd_g[chain] < LMAX) return;
  int tid = threadIdx.x;
  bool act = tid < H_;
  __shared__ float h_lds[H_];
  size_t cb = (size_t)chain*T_*H_, xb = (size_t)chain*T_*HG;
  const int* ei = eidx_g + chain*ECAP;
  const float* ewp = ew_g + chain*ECAP;
  for (int j = 0; j < T_; ++j) {
    if (depth_g[chain*T_+j] < LMAX) continue;
    if (act) {
      const float* xp = xg + xb + (size_t)j*HG;
      float iu = xp[tid], x1b = xp[H_+tid], og = xp[2*H_+tid];
      float acc = iu;
      int c0 = coff_g[chain*T_+j], c1 = c0 + cnt_g[chain*T_+j];
      for (int k = c0; k < c1; ++k) {
        int t = ei[k];
        acc += ewp[k] * sigm(x1b + fh[cb + (size_t)t*H_ + tid]) * chist[cb + (size_t)t*H_ + tid];
      }
      chist[cb + (size_t)j*H_ + tid] = acc;
      float hv = og * tanhf(acc);
      hout[cb + (size_t)j*H_ + tid] = hv;
      h_lds[tid] = hv;
    }
    __syncthreads();
    if (hasp_g[chain*T_+j] && act) {
      float a = 0.f;
      const float* up = uh1T + tid;
      #pragma unroll 4
      for (int m = 0; m < H_; ++m) a = fmaf(up[(size_t)m*H_], h_lds[m], a);
      fh[cb + (size_t)j*H_ + tid] = a;
    }
    __syncthreads();
  }
}

// ---------------- split-bf16 MFMA GEMM (round-7 proven) ----------------
#define LDT 40
template<int MODE>
__global__ __launch_bounds__(256) void k_gemm_mfma(
    const float* __restrict__ A, const float* __restrict__ A2,
    const int* __restrict__ ptok, const int* __restrict__ htok, const float* __restrict__ embr,
    const float* __restrict__ W, const float* __restrict__ bias, float* __restrict__ C,
    int N, int K, int act)
{
  __shared__ unsigned short lds[4][128*LDT];   // Ah, Al, Wh, Wl  (40 KB)
  int tid = threadIdx.x;
  int bn = blockIdx.x * 128, bm = blockIdx.y * 128;
  int lane = tid & 63, wave = tid >> 6;
  int wr = (wave >> 1) * 64, wc = (wave & 1) * 64;
  int lrow = lane & 15, koff = (lane >> 4) * 8;

  int srow = tid >> 1;
  int kq0 = (tid & 1) * 16;
  const float* Ap; const float* Ap2 = nullptr;
  if (MODE == 1) { int ar = bm + srow; int tok = (ar < 4096) ? ptok[ar] : htok[ar-4096]; Ap = embr + (size_t)tok*H_; }
  else if (MODE == 2) { Ap = A + (size_t)(bm+srow)*H_; Ap2 = A2 + (size_t)(bm+srow)*H_; }
  else Ap = A + (size_t)(bm+srow)*K;
  int wrow = bn + srow;
  const float* Wp = (wrow < N) ? W + (size_t)wrow*K : nullptr;

  float4 ga[4], gw[4], gx[4];
  int sg[4];
  auto issue = [&](int t){
    int kb = t * 32;
    #pragma unroll
    for (int i = 0; i < 4; ++i) {
      int gk = kb + kq0 + i*4;
      ga[i] = make_float4(0.f,0.f,0.f,0.f); gw[i] = make_float4(0.f,0.f,0.f,0.f);
      if (MODE == 2) sg[i] = 0;
      if (gk < K) {
        if (MODE == 2) {
          int s = gk / 300, kk = gk - s*300; sg[i] = s;
          if (s == 0)      ga[i] = *(const float4*)(Ap + kk);
          else if (s == 1) ga[i] = *(const float4*)(Ap2 + kk);
          else { ga[i] = *(const float4*)(Ap + kk); gx[i] = *(const float4*)(Ap2 + kk); }
        } else ga[i] = *(const float4*)(Ap + gk);
        if (Wp) gw[i] = *(const float4*)(Wp + gk);
      }
    }
  };
  auto commit = [&](){
    #pragma unroll
    for (int i = 0; i < 4; ++i) {
      float4 v = ga[i];
      if (MODE == 2 && sg[i] == 2) { v.x*=gx[i].x; v.y*=gx[i].y; v.z*=gx[i].z; v.w*=gx[i].w; }
      ushort4 h, l;
      h.x=f2bf(v.x); h.y=f2bf(v.y); h.z=f2bf(v.z); h.w=f2bf(v.w);
      l.x=f2bf(v.x-bf2f(h.x)); l.y=f2bf(v.y-bf2f(h.y)); l.z=f2bf(v.z-bf2f(h.z)); l.w=f2bf(v.w-bf2f(h.w));
      int off = srow*LDT + kq0 + i*4;
      *(ushort4*)&lds[0][off] = h;
      *(ushort4*)&lds[1][off] = l;
      float4 w = gw[i];
      h.x=f2bf(w.x); h.y=f2bf(w.y); h.z=f2bf(w.z); h.w=f2bf(w.w);
      l.x=f2bf(w.x-bf2f(h.x)); l.y=f2bf(w.y-bf2f(h.y)); l.z=f2bf(w.z-bf2f(h.z)); l.w=f2bf(w.w-bf2f(h.w));
      *(ushort4*)&lds[2][off] = h;
      *(ushort4*)&lds[3][off] = l;
    }
  };

  f32x4 acc[4][4];
  #pragma unroll
  for (int m = 0; m < 4; ++m)
    #pragma unroll
    for (int n = 0; n < 4; ++n) acc[m][n] = (f32x4){0.f,0.f,0.f,0.f};

  int NT = (K + 31) / 32;
  issue(0); commit();
  __syncthreads();
  for (int t = 0; t < NT; ++t) {
    bool more = (t+1 < NT);
    bf16x8 ah[4], al[4], bh[4], bl[4];
    #pragma unroll
    for (int m = 0; m < 4; ++m) {
      int o = (wr + m*16 + lrow)*LDT + koff;
      ah[m] = *(const bf16x8*)&lds[0][o];
      al[m] = *(const bf16x8*)&lds[1][o];
    }
    #pragma unroll
    for (int n = 0; n < 4; ++n) {
      int o = (wc + n*16 + lrow)*LDT + koff;
      bh[n] = *(const bf16x8*)&lds[2][o];
      bl[n] = *(const bf16x8*)&lds[3][o];
    }
    if (more) issue(t+1);
    __syncthreads();
    if (more) commit();
    #pragma unroll
    for (int m = 0; m < 4; ++m)
      #pragma unroll
      for (int n = 0; n < 4; ++n) {
        acc[m][n] = __builtin_amdgcn_mfma_f32_16x16x32_bf16(ah[m], bh[n], acc[m][n], 0,0,0);
        acc[m][n] = __builtin_amdgcn_mfma_f32_16x16x32_bf16(ah[m], bl[n], acc[m][n], 0,0,0);
        acc[m][n] = __builtin_amdgcn_mfma_f32_16x16x32_bf16(al[m], bh[n], acc[m][n], 0,0,0);
      }
    __syncthreads();
  }
  #pragma unroll
  for (int m = 0; m < 4; ++m) {
    int row0 = bm + wr + m*16 + (lane >> 4)*4;
    #pragma unroll
    for (int n = 0; n < 4; ++n) {
      int col = bn + wc + n*16 + (lane & 15);
      if (col < N) {
        float bv = bias[col];
        #pragma unroll
        for (int r = 0; r < 4; ++r) {
          float v = acc[m][n][r] + bv;
          if (act) v = fmaxf(v, 0.f);
          C[(size_t)(row0 + r)*N + col] = v;
        }
      }
    }
  }
}

// ---------------- fused MFMA attention: one block per (d, b, q-half) ----------------
// Phase1 SIM=Q@K^T (split-bf16), Phase2 masked softmax -> P hi/lo, Phase3 ATT=P@K.
__global__ __launch_bounds__(256) void k_attn_mfma(
    const float* __restrict__ Hm, const int* __restrict__ plen, const int* __restrict__ hlen,
    float* __restrict__ ATT)
{
  __shared__ float regA_f[12800];            // 51200 B: phase1 stage / SIM / Kt (aliased)
  __shared__ ushort_t pbuf[2*64*136];        // 34816 B: P hi/lo  [comp][row][136]
  ushort_t* regA = (ushort_t*)regA_f;

  int tid = threadIdx.x;
  int lane = tid & 63, wave = tid >> 6;
  int lrow = lane & 15, koff = (lane >> 4) * 8;
  int d = blockIdx.x, b = blockIdx.y, q0 = blockIdx.z * 64;
  const float* Q  = Hm + ((size_t)(d*B_ + b)*T_ + q0) * H_;
  const float* Kp = Hm + ((size_t)((1-d)*B_ + b)*T_) * H_;
  float* outp = ATT + ((size_t)(d*B_ + b)*T_ + q0) * H_;
  int klen = (d == 0) ? hlen[b] : plen[b];

  // ---- phase 1: SIM(64x128) = Q @ K^T, contraction feat 300 (10 chunks of 32) ----
  ushort_t* sQh = regA;            // [64][40]
  ushort_t* sQl = regA + 2560;
  ushort_t* sKh = regA + 5120;     // [128][40]
  ushort_t* sKl = regA + 10240;
  int qrow = tid >> 2, qk0 = (tid & 3) * 8;
  int krow = tid >> 1, kk0 = (tid & 1) * 16;
  const float* Qr = Q + (size_t)qrow*H_;
  const float* Kr = Kp + (size_t)krow*H_;

  float4 gq[2], gk4[4];
  auto issue1 = [&](int t){
    int kb = t*32;
    #pragma unroll
    for (int i = 0; i < 2; ++i) {
      int g = kb + qk0 + i*4;
      gq[i] = make_float4(0.f,0.f,0.f,0.f);
      if (g < H_) gq[i] = *(const float4*)(Qr + g);
    }
    #pragma unroll
    for (int i = 0; i < 4; ++i) {
      int g = kb + kk0 + i*4;
      gk4[i] = make_float4(0.f,0.f,0.f,0.f);
      if (g < H_) gk4[i] = *(const float4*)(Kr + g);
    }
  };
  auto commit1 = [&](){
    #pragma unroll
    for (int i = 0; i < 2; ++i) {
      float4 v = gq[i]; ushort4 h, l;
      h.x=f2bf(v.x); h.y=f2bf(v.y); h.z=f2bf(v.z); h.w=f2bf(v.w);
      l.x=f2bf(v.x-bf2f(h.x)); l.y=f2bf(v.y-bf2f(h.y)); l.z=f2bf(v.z-bf2f(h.z)); l.w=f2bf(v.w-bf2f(h.w));
      int o = qrow*40 + qk0 + i*4;
      *(ushort4*)&sQh[o] = h; *(ushort4*)&sQl[o] = l;
    }
    #pragma unroll
    for (int i = 0; i < 4; ++i) {
      float4 v = gk4[i]; ushort4 h, l;
      h.x=f2bf(v.x); h.y=f2bf(v.y); h.z=f2bf(v.z); h.w=f2bf(v.w);
      l.x=f2bf(v.x-bf2f(h.x)); l.y=f2bf(v.y-bf2f(h.y)); l.z=f2bf(v.z-bf2f(h.z)); l.w=f2bf(v.w-bf2f(h.w));
      int o = krow*40 + kk0 + i*4;
      *(ushort4*)&sKh[o] = h; *(ushort4*)&sKl[o] = l;
    }
  };

  f32x4 acc1[4][2];
  #pragma unroll
  for (int m = 0; m < 4; ++m)
    #pragma unroll
    for (int n = 0; n < 2; ++n) acc1[m][n] = (f32x4){0.f,0.f,0.f,0.f};
  int wc = wave * 32;            // key strip per wave

  issue1(0); commit1();
  __syncthreads();
  for (int t = 0; t < 10; ++t) {
    bool more = (t < 9);
    bf16x8 ah[4], al[4], bh[2], bl[2];
    #pragma unroll
    for (int m = 0; m < 4; ++m) {
      int o = (m*16 + lrow)*40 + koff;
      ah[m] = *(const bf16x8*)&sQh[o];
      al[m] = *(const bf16x8*)&sQl[o];
    }
    #pragma unroll
    for (int n = 0; n < 2; ++n) {
      int o = (wc + n*16 + lrow)*40 + koff;
      bh[n] = *(const bf16x8*)&sKh[o];
      bl[n] = *(const bf16x8*)&sKl[o];
    }
    if (more) issue1(t+1);
    __syncthreads();
    if (more) commit1();
    #pragma unroll
    for (int m = 0; m < 4; ++m)
      #pragma unroll
      for (int n = 0; n < 2; ++n) {
        acc1[m][n] = __builtin_amdgcn_mfma_f32_16x16x32_bf16(ah[m], bh[n], acc1[m][n], 0,0,0);
        acc1[m][n] = __builtin_amdgcn_mfma_f32_16x16x32_bf16(ah[m], bl[n], acc1[m][n], 0,0,0);
        acc1[m][n] = __builtin_amdgcn_mfma_f32_16x16x32_bf16(al[m], bh[n], acc1[m][n], 0,0,0);
      }
    __syncthreads();
  }
  // ---- SIM -> LDS (f32 [64][132], aliases dead staging) ----
  float* sim = regA_f;
  #pragma unroll
  for (int m = 0; m < 4; ++m)
    #pragma unroll
    for (int n = 0; n < 2; ++n)
      #pragma unroll
      for (int r = 0; r < 4; ++r)
        sim[(m*16 + (lane>>4)*4 + r)*132 + wc + n*16 + lrow] = acc1[m][n][r];
  __syncthreads();

  // ---- phase 2: masked row-softmax; P = hi/lo bf16 into pbuf ----
  {
    int row = tid >> 2, qtr = (tid & 3) * 32;
    const float* sr = sim + row*132;
    float mx = NEGV;
    for (int c = 0; c < 32; ++c) { int cg = qtr + c; float s = (cg < klen) ? sr[cg] : NEGV; mx = fmaxf(mx, s); }
    mx = fmaxf(mx, __shfl_xor(mx, 1));
    mx = fmaxf(mx, __shfl_xor(mx, 2));
    float sum = 0.f;
    for (int c = 0; c < 32; ++c) { int cg = qtr + c; if (cg < klen) sum += expf(sr[cg] - mx); }
    sum += __shfl_xor(sum, 1);
    sum += __shfl_xor(sum, 2);
    float rinv = 1.f / sum;
    for (int c = 0; c < 32; ++c) {
      int cg = qtr + c;
      float p = (cg < klen) ? expf(sr[cg] - mx) * rinv : 0.f;
      ushort_t h = f2bf(p);
      pbuf[row*136 + cg] = h;
      pbuf[64*136 + row*136 + cg] = f2bf(p - bf2f(h));
    }
  }
  __syncthreads();

  // ---- phase 3: ATT(64x300) = P(64x128) @ K(128x300); Kt staged transposed ----
  ushort_t* kth = regA;            // [320][40]
  ushort_t* ktl = regA + 12800;
  int wr2 = (wave & 1) * 32;       // row strip
  int wcf = (wave >> 1) * 160;     // feat strip
  f32x4 acc3[2][10];
  #pragma unroll
  for (int m = 0; m < 2; ++m)
    #pragma unroll
    for (int n = 0; n < 10; ++n) acc3[m][n] = (f32x4){0.f,0.f,0.f,0.f};
  int skey = tid >> 3, sf4 = tid & 7;

  for (int kc = 0; kc < 4; ++kc) {
    __syncthreads();               // previous Kt reads (or softmax sim reads) done
    const float* kr = Kp + (size_t)(kc*32 + skey)*H_;
    for (int f4 = sf4; f4 < 75; f4 += 8) {
      float4 v = *(const float4*)(kr + f4*4);
      float vv[4] = {v.x, v.y, v.z, v.w};
      #pragma unroll
      for (int i = 0; i < 4; ++i) {
        int feat = f4*4 + i;
        ushort_t h = f2bf(vv[i]);
        kth[feat*40 + skey] = h;
        ktl[feat*40 + skey] = f2bf(vv[i] - bf2f(h));
      }
    }
    __syncthreads();
    bf16x8 ph[2], pl[2], kh[10], kl[10];
    #pragma unroll
    for (int m = 0; m < 2; ++m) {
      int o = (wr2 + m*16 + lrow)*136 + kc*32 + koff;
      ph[m] = *(const bf16x8*)&pbuf[o];
      pl[m] = *(const bf16x8*)&pbuf[64*136 + o];
    }
    #pragma unroll
    for (int n = 0; n < 10; ++n) {
      int o = (wcf + n*16 + lrow)*40 + koff;
      kh[n] = *(const bf16x8*)&kth[o];
      kl[n] = *(const bf16x8*)&ktl[o];
    }
    #pragma unroll
    for (int m = 0; m < 2; ++m)
      #pragma unroll
      for (int n = 0; n < 10; ++n) {
        acc3[m][n] = __builtin_amdgcn_mfma_f32_16x16x32_bf16(ph[m], kh[n], acc3[m][n], 0,0,0);
        acc3[m][n] = __builtin_amdgcn_mfma_f32_16x16x32_bf16(ph[m], kl[n], acc3[m][n], 0,0,0);
        acc3[m][n] = __builtin_amdgcn_mfma_f32_16x16x32_bf16(pl[m], kh[n], acc3[m][n], 0,0,0);
      }
  }
  #pragma unroll
  for (int m = 0; m < 2; ++m) {
    int row0 = wr2 + m*16 + (lane >> 4)*4;
    #pragma unroll
    for (int n = 0; n < 10; ++n) {
      int col = wcf + n*16 + lrow;
      if (col < H_) {
        #pragma unroll
        for (int r = 0; r < 4; ++r)
          outp[(size_t)(row0 + r)*H_ + col] = acc3[m][n][r];
      }
    }
  }
}

// ---------------- pool stage 1 ----------------
__global__ __launch_bounds__(320) void k_pool(const float* __restrict__ H,
    const int* __restrict__ plen, const int* __restrict__ hlen,
    float* __restrict__ psum, float* __restrict__ pmax)
{
  int chain = blockIdx.x; int s = chain >> 5, b = chain & 31;
  int c = blockIdx.y; int t0 = c * 16;
  int len = (s == 0 ? plen[b] : hlen[b]);
  int tid = threadIdx.x;
  __shared__ float buf[16*H_];
  const float* hp = H + (size_t)chain*T_*H_ + (size_t)t0*H_;
  for (int i = tid; i < 16*H_; i += 320) buf[i] = hp[i];
  __syncthreads();
  if (tid < H_) {
    int tmax = len - t0; if (tmax > 16) tmax = 16;
    float sum = 0.f, mx = NEGV;
    for (int t = 0; t < tmax; ++t) { float x = buf[t*H_ + tid]; sum += x; mx = fmaxf(mx, x); }
    int o = (chain*8 + c)*H_ + tid;
    psum[o] = sum; pmax[o] = mx;
  }
}

// ---------------- pool stage 2 + classifier ----------------
__global__ __launch_bounds__(320) void k_classify(
    const float* __restrict__ psum, const float* __restrict__ pmax,
    const int* __restrict__ plen, const int* __restrict__ hlen,
    const float* __restrict__ w1t, const float* __restrict__ b1,
    const float* __restrict__ w2, const float* __restrict__ b2,
    float* __restrict__ out)
{
  int b = blockIdx.x;
  int tid = threadIdx.x;
  __shared__ float v[HG];
  __shared__ float hid[H_];
  for (int s = 0; s < 2; ++s) {
    int chain = s*B_ + b;
    int len = (s == 0 ? plen[b] : hlen[b]);
    if (tid < H_) {
      float sum = 0.f, mx = NEGV;
      #pragma unroll
      for (int c = 0; c < 8; ++c) {
        int o = (chain*8 + c)*H_ + tid;
        sum += psum[o]; mx = fmaxf(mx, pmax[o]);
      }
      v[s*600 + tid]       = sum / (float)len;
      v[s*600 + 300 + tid] = mx;
    }
  }
  __syncthreads();
  if (tid < H_) {
    float a0 = b1[tid], a1 = 0.f, a2 = 0.f, a3 = 0.f;
    for (int m = 0; m < HG; m += 4) {
      a0 = fmaf(v[m+0], w1t[(size_t)(m+0)*H_ + tid], a0);
      a1 = fmaf(v[m+1], w1t[(size_t)(m+1)*H_ + tid], a1);
      a2 = fmaf(v[m+2], w1t[(size_t)(m+2)*H_ + tid], a2);
      a3 = fmaf(v[m+3], w1t[(size_t)(m+3)*H_ + tid], a3);
    }
    hid[tid] = tanhf(a0 + a1 + a2 + a3);
  }
  __syncthreads();
  if (tid < 3) {
    float a = b2[tid];
    const float* wr = w2 + (size_t)tid*H_;
    for (int n = 0; n < H_; ++n) a = fmaf(hid[n], wr[n], a);
    out[b*3 + tid] = a;
  }
}

// ---------------- launch ----------------
extern "C" void kernel_launch(void* const* d_in, const int* in_sizes, int n_in,
                              void* d_out, int out_size, void* d_ws, size_t ws_size,
                              hipStream_t stream) {
  const int*   prem    = (const int*)d_in[0];
  const int*   plen    = (const int*)d_in[1];
  const int*   hyp     = (const int*)d_in[2];
  const int*   hlen    = (const int*)d_in[3];
  const float* lg      = (const float*)d_in[4];
  const float* rg      = (const float*)d_in[5];
  const float* emb     = (const float*)d_in[6];
  const float* enc_wx  = (const float*)d_in[7];
  const float* enc_bx  = (const float*)d_in[8];
  const float* enc_uh  = (const float*)d_in[9];
  const float* enc_bh  = (const float*)d_in[10];
  const float* comp_wx = (const float*)d_in[11];
  const float* comp_bx = (const float*)d_in[12];
  const float* comp_uh = (const float*)d_in[13];
  const float* comp_bh = (const float*)d_in[14];
  const float* proj_w  = (const float*)d_in[15];
  const float* proj_b  = (const float*)d_in[16];
  const float* cls_w1  = (const float*)d_in[17];
  const float* cls_b1  = (const float*)d_in[18];
  const float* cls_w2  = (const float*)d_in[19];
  const float* cls_b2  = (const float*)d_in[20];
  float* outp = (float*)d_out;

  const size_t SZ_XG  = (size_t)2*B_*T_*HG;
  const size_t SZ_BTH = (size_t)2*B_*T_*H_;
  float* XG  = (float*)d_ws;    // enc-xg -> comp-xg
  float* PROJ= XG  + SZ_XG;
  float* H1  = PROJ+ SZ_BTH;
  float* CH  = H1  + SZ_BTH;    // c history; reused as ATT between scans
  float* FH  = CH  + SZ_BTH;
  float* UTE = FH  + SZ_BTH;
  float* UTC = UTE + (size_t)H_*H_;
  float* WP  = UTC + (size_t)H_*H_;
  float* W1T = WP  + (size_t)H_*900;
  float* PSUM= W1T + (size_t)HG*H_;
  float* PMAX= PSUM+ (size_t)64*8*H_;
  float* EW  = PMAX+ (size_t)64*8*H_;
  int*   EIDX = (int*)(EW + (size_t)64*ECAP);
  int*   CNT  = EIDX + (size_t)64*ECAP;
  int*   COFF = CNT  + 64*T_;
  int*   DEPTH= COFF + 64*T_;
  int*   HASP = DEPTH+ 64*T_;
  int*   MAXD = HASP + 64*T_;
  int*   LVLCNT = MAXD + 64;
  int*   WL   = LVLCNT + LMAX;
  float* ATT  = CH;

  hipMemsetAsync(LVLCNT, 0, LMAX*sizeof(int), stream);
  // 1. weight prep + graph analysis
  k_prep_all<<<(720000 + 255)/256, 256, 0, stream>>>(enc_uh, comp_uh, proj_w, cls_w1, UTE, UTC, WP, W1T);
  k_build<<<64, 256, 0, stream>>>(lg, rg, CNT, COFF, EIDX, EW, HASP, DEPTH, MAXD, LVLCNT, WL);
  // 2. enc xg = emb-gather @ enc_wx^T + enc_bx (split-bf16 MFMA), then gates
  k_gemm_mfma<1><<<dim3(10, 64), 256, 0, stream>>>(nullptr, nullptr, prem, hyp, emb,
      enc_wx, enc_bx, XG, HG, H_, 0);
  k_gates<<<(2*B_*T_*H_ + 255)/256, 256, 0, stream>>>(XG, enc_bh);
  // 3. enc tree scan (per-level launches)
  for (int L = 0; L < LMAX; ++L)
    k_level<<<640, 1024, 0, stream>>>(XG, UTE, CNT, COFF, EIDX, EW, HASP, LVLCNT, WL, L, H1, CH, FH);
  k_tail<<<64, 320, 0, stream>>>(XG, UTE, CNT, COFF, EIDX, EW, HASP, DEPTH, MAXD, H1, CH, FH);
  // 4. attention via MFMA (CH dead -> ATT)
  k_attn_mfma<<<dim3(2, B_, 2), 256, 0, stream>>>(H1, plen, hlen, ATT);
  // 5. proj = relu([H1|ATT|H1*ATT] @ WP^T + proj_b)
  k_gemm_mfma<2><<<dim3(3, 64), 256, 0, stream>>>(H1, ATT, nullptr, nullptr, nullptr,
      WP, proj_b, PROJ, H_, 900, 1);
  // 6. comp xg = proj @ comp_wx^T + comp_bx, then gates
  k_gemm_mfma<0><<<dim3(10, 64), 256, 0, stream>>>(PROJ, nullptr, nullptr, nullptr, nullptr,
      comp_wx, comp_bx, XG, HG, H_, 0);
  k_gates<<<(2*B_*T_*H_ + 255)/256, 256, 0, stream>>>(XG, comp_bh);
  // 7. comp tree scan
  for (int L = 0; L < LMAX; ++L)
    k_level<<<640, 1024, 0, stream>>>(XG, UTC, CNT, COFF, EIDX, EW, HASP, LVLCNT, WL, L, H1, CH, FH);
  k_tail<<<64, 320, 0, stream>>>(XG, UTC, CNT, COFF, EIDX, EW, HASP, DEPTH, MAXD, H1, CH, FH);
  // 8. pool + classifier
  k_pool<<<dim3(64, 8), 320, 0, stream>>>(H1, plen, hlen, PSUM, PMAX);
  k_classify<<<B_, 320, 0, stream>>>(PSUM, PMAX, plen, hlen, W1T, cls_b1, cls_w2, cls_b2, outp);
}

// Round 9
// 596.960 us; speedup vs baseline: 2.3288x; 1.2016x over previous
//
#include <hip/hip_runtime.h>
#include <math.h>

#define B_ 32
#define T_ 128
#define H_ 300
#define HG 1200   // 4*H
#define LMAX 10
#define WLCAP 8192
#define ECAP 2048
#define NEGV -10000000.0f

typedef __attribute__((ext_vector_type(8))) short bf16x8;
typedef __attribute__((ext_vector_type(4))) float f32x4;
typedef unsigned short ushort_t;

__device__ __forceinline__ float sigm(float x){ return 1.f/(1.f+expf(-x)); }

__device__ __forceinline__ unsigned short f2bf(float x){
  union { float f; unsigned int u; } c; c.f = x;
  unsigned int u = c.u;
  return (unsigned short)((u + 0x7fffu + ((u >> 16) & 1u)) >> 16);
}
__device__ __forceinline__ float bf2f(unsigned short h){
  union { unsigned int u; float f; } c; c.u = ((unsigned int)h) << 16;
  return c.f;
}

// ---------------- fused weight prep: fp32 transposes + bf16 hi/lo padded weights ----------------
__global__ __launch_bounds__(256) void k_prep_all(
    const float* __restrict__ enc_uh, const float* __restrict__ comp_uh,
    const float* __restrict__ enc_wx, const float* __restrict__ comp_wx,
    const float* __restrict__ pw, const float* __restrict__ cw1,
    float* __restrict__ te, float* __restrict__ tc, float* __restrict__ w1t,
    ushort_t* __restrict__ WencH, ushort_t* __restrict__ WencL,
    ushort_t* __restrict__ WcompH, ushort_t* __restrict__ WcompL,
    ushort_t* __restrict__ WPH, ushort_t* __restrict__ WPL)
{
  int i = blockIdx.x*256 + threadIdx.x;
  if (i < 90000) {                       // uh1 transposes: te/tc[m][k] = uh[1][k][m]
    int m = i / H_, k = i - m*H_;
    te[i] = enc_uh[H_*H_ + (size_t)k*H_ + m];
    tc[i] = comp_uh[H_*H_ + (size_t)k*H_ + m];
  } else if (i < 450000) {               // w1t (1200 x 300): w1t[m][k] = cw1[k][m]
    int i2 = i - 90000;
    int m = i2 / H_, k = i2 - m*H_;
    w1t[i2] = cw1[(size_t)k*HG + m];
  } else if (i < 834000) {               // Wenc hi/lo [1200][320], zero-padded
    int i2 = i - 450000;
    int n = i2 / 320, k = i2 - n*320;
    float v = (k < 300) ? enc_wx[(size_t)n*300 + k] : 0.f;
    ushort_t h = f2bf(v);
    WencH[i2] = h; WencL[i2] = f2bf(v - bf2f(h));
  } else if (i < 1218000) {              // Wcomp hi/lo [1200][320]
    int i2 = i - 834000;
    int n = i2 / 320, k = i2 - n*320;
    float v = (k < 300) ? comp_wx[(size_t)n*300 + k] : 0.f;
    ushort_t h = f2bf(v);
    WcompH[i2] = h; WcompL[i2] = f2bf(v - bf2f(h));
  } else if (i < 1496400) {              // folded proj W hi/lo [300][928]
    int i2 = i - 1218000;
    int n = i2 / 928, k = i2 - n*928;
    const float* r = pw + (size_t)n*HG;
    float v = 0.f;
    if (k < 300)      v = r[k] + r[600+k];
    else if (k < 600) v = r[k] - r[k+300];
    else if (k < 900) v = r[k+300];
    ushort_t h = f2bf(v);
    WPH[i2] = h; WPL[i2] = f2bf(v - bf2f(h));
  }
}

// ---------------- embedding gather + bf16 split: [8192][320] hi/lo ----------------
__global__ __launch_bounds__(256) void k_embed_split(const int* __restrict__ prem, const int* __restrict__ hyp,
    const float* __restrict__ emb, ushort_t* __restrict__ EH, ushort_t* __restrict__ EL)
{
  int i = blockIdx.x*256 + threadIdx.x;      // over 8192*320
  int bt = i / 320, k = i - bt*320;
  int side = bt >> 12, bt2 = bt & 4095;
  float v = 0.f;
  if (k < 300) {
    int tok = (side == 0 ? prem : hyp)[bt2];
    v = emb[(size_t)tok*H_ + k];
  }
  ushort_t h = f2bf(v);
  EH[i] = h; EL[i] = f2bf(v - bf2f(h));
}

// ---------------- enhance + bf16 split: A=[H1|ATT|H1*ATT] -> [8192][928] hi/lo ----------------
__global__ __launch_bounds__(256) void k_enh_split(const float* __restrict__ H1, const float* __restrict__ ATT,
    ushort_t* __restrict__ AH, ushort_t* __restrict__ AL)
{
  int i = blockIdx.x*256 + threadIdx.x;      // over 8192*928
  int r = i / 928, k = i - r*928;
  float v = 0.f;
  if (k < 300)      v = H1[(size_t)r*H_ + k];
  else if (k < 600) v = ATT[(size_t)r*H_ + k - 300];
  else if (k < 900) { int kk = k - 600; v = H1[(size_t)r*H_ + kk] * ATT[(size_t)r*H_ + kk]; }
  ushort_t h = f2bf(v);
  AH[i] = h; AL[i] = f2bf(v - bf2f(h));
}

// ---------------- graph analysis ----------------
__global__ __launch_bounds__(256) void k_build(const float* __restrict__ lg, const float* __restrict__ rg,
    int* __restrict__ cnt_g, int* __restrict__ coff_g, int* __restrict__ eidx_g, float* __restrict__ ew_g,
    int* __restrict__ hasp_g, int* __restrict__ depth_g, int* __restrict__ maxd_g,
    int* __restrict__ lvlcnt_g, int* __restrict__ wl_g)
{
  int chain = blockIdx.x; int s = chain >> 5, b = chain & 31;
  const float* graph = (s ? rg : lg) + (size_t)b*T_*T_;
  int tid = threadIdx.x;
  __shared__ int cnt[T_], coff[T_], depth[T_], hasp[T_];
  __shared__ short eidx[ECAP];
  __shared__ float ew[ECAP];
  __shared__ int etot_s;
  if (tid < T_) hasp[tid] = 0;
  if (tid < T_) {
    int j = tid, c = 0;
    const float* gr = graph + (size_t)j*T_;
    for (int t = 0; t < j; ++t) c += (gr[t] != 0.f) ? 1 : 0;
    cnt[j] = c;
  }
  __syncthreads();
  if (tid == 0) { int a = 0; for (int j = 0; j < T_; ++j) { coff[j] = a; a += cnt[j]; } etot_s = a; }
  __syncthreads();
  if (tid < T_) {
    int j = tid, p = coff[j];
    const float* gr = graph + (size_t)j*T_;
    for (int t = 0; t < j; ++t) {
      float g = gr[t];
      if (g != 0.f && p < ECAP) { eidx[p] = (short)t; ew[p] = g; hasp[t] = 1; ++p; }
    }
  }
  __syncthreads();
  if (tid == 0) {
    int md = 0;
    for (int j = 0; j < T_; ++j) {
      int d = 0, e0 = coff[j], e1 = coff[j] + cnt[j];
      if (e1 > ECAP) e1 = ECAP;
      for (int k = e0; k < e1; ++k) { int dd = depth[eidx[k]] + 1; d = dd > d ? dd : d; }
      depth[j] = d; md = d > md ? d : md;
    }
    maxd_g[chain] = md;
  }
  __syncthreads();
  int base = chain * T_;
  if (tid < T_) {
    cnt_g[base+tid] = cnt[tid]; coff_g[base+tid] = coff[tid];
    hasp_g[base+tid] = hasp[tid]; depth_g[base+tid] = depth[tid];
    int L = depth[tid];
    if (L < LMAX) { int p = atomicAdd(&lvlcnt_g[L], 1); wl_g[L*WLCAP + p] = (chain << 8) | tid; }
  }
  int etot = etot_s; if (etot > ECAP) etot = ECAP;
  for (int i = tid; i < etot; i += 256) { eidx_g[chain*ECAP + i] = eidx[i]; ew_g[chain*ECAP + i] = ew[i]; }
}

// ---------------- gate precompute, in-place over XG ----------------
__global__ __launch_bounds__(256) void k_gates(float* __restrict__ xg, const float* __restrict__ bhv)
{
  int i = blockIdx.x*256 + threadIdx.x;
  if (i >= 2*B_*T_*H_) return;
  int bt = i / H_, e = i - bt*H_;
  float* xp = xg + (size_t)bt*HG;
  float x0 = xp[e], x1 = xp[H_+e], x2 = xp[2*H_+e], x3 = xp[3*H_+e];
  xp[e]       = sigm(x0 + bhv[e]) * tanhf(x3 + bhv[3*H_+e]);
  xp[H_+e]    = x1 + bhv[H_+e];
  xp[2*H_+e]  = sigm(x2 + bhv[2*H_+e]);
}

// ---------------- per-level tree-LSTM ----------------
__global__ __launch_bounds__(1024) void k_level(
    const float* __restrict__ xg, const float* __restrict__ uh1T,
    const int* __restrict__ cnt_g, const int* __restrict__ coff_g,
    const int* __restrict__ eidx_g, const float* __restrict__ ew_g,
    const int* __restrict__ hasp_g, const int* __restrict__ lvlcnt_g, const int* __restrict__ wl_g,
    int L, float* __restrict__ hout, float* __restrict__ chist, float* __restrict__ fh)
{
  int count = lvlcnt_g[L];
  int nblk = (count + 3) >> 2;
  int tid = threadIdx.x;
  __shared__ float h_s[4][H_];
  __shared__ float psum[3][4][H_];
  __shared__ int nodes[4];
  __shared__ int anyp;
  for (int blk = blockIdx.x; blk < nblk; blk += gridDim.x) {
    int base = blk * 4;
    int nn = count - base; if (nn > 4) nn = 4;
    if (tid == 0) anyp = 0;
    __syncthreads();
    if (tid < 4) {
      int pk = (tid < nn) ? wl_g[L*WLCAP + base + tid] : -1;
      nodes[tid] = pk;
      if (pk >= 0 && hasp_g[(pk >> 8)*T_ + (pk & 255)]) atomicAdd(&anyp, 1);
    }
    __syncthreads();
    for (int w = tid; w < nn*H_; w += 1024) {
      int n = w / H_, e = w - n*H_;
      int pk = nodes[n]; int chain = pk >> 8, j = pk & 255;
      size_t cb = (size_t)chain*T_*H_, xb = (size_t)chain*T_*HG;
      const float* xp = xg + xb + (size_t)j*HG;
      float iu = xp[e], x1b = xp[H_+e], og = xp[2*H_+e];
      float acc = iu;
      int c0 = coff_g[chain*T_+j], c1 = c0 + cnt_g[chain*T_+j];
      const int* ei = eidx_g + chain*ECAP;
      const float* ewp = ew_g + chain*ECAP;
      for (int k = c0; k < c1; ++k) {
        int t = ei[k];
        acc += ewp[k] * sigm(x1b + fh[cb + (size_t)t*H_ + e]) * chist[cb + (size_t)t*H_ + e];
      }
      chist[cb + (size_t)j*H_ + e] = acc;
      float hv = og * tanhf(acc);
      hout[cb + (size_t)j*H_ + e] = hv;
      h_s[n][e] = hv;
    }
    __syncthreads();
    if (anyp > 0) {
      if (tid < 3*H_) {
        int g = tid / H_, e = tid - g*H_;
        float a0=0.f, a1=0.f, a2=0.f, a3=0.f;
        const float* up = uh1T + e;
        int m0 = g*100, m1 = m0 + 100;
        #pragma unroll 4
        for (int m = m0; m < m1; ++m) {
          float u = up[(size_t)m*H_];
          a0 = fmaf(u, h_s[0][m], a0);
          a1 = fmaf(u, h_s[1][m], a1);
          a2 = fmaf(u, h_s[2][m], a2);
          a3 = fmaf(u, h_s[3][m], a3);
        }
        psum[g][0][e]=a0; psum[g][1][e]=a1; psum[g][2][e]=a2; psum[g][3][e]=a3;
      }
      __syncthreads();
      for (int w = tid; w < nn*H_; w += 1024) {
        int n = w / H_, e = w - n*H_;
        int pk = nodes[n]; int chain = pk >> 8, j = pk & 255;
        if (hasp_g[chain*T_+j]) {
          size_t cb = (size_t)chain*T_*H_;
          fh[cb + (size_t)j*H_ + e] = psum[0][n][e] + psum[1][n][e] + psum[2][n][e];
        }
      }
    }
    __syncthreads();
  }
}

// ---------------- serial tail for rare deep graphs ----------------
__global__ __launch_bounds__(320) void k_tail(const float* __restrict__ xg,
    const float* __restrict__ uh1T, const int* __restrict__ cnt_g, const int* __restrict__ coff_g,
    const int* __restrict__ eidx_g, const float* __restrict__ ew_g, const int* __restrict__ hasp_g,
    const int* __restrict__ depth_g, const int* __restrict__ maxd_g,
    float* __restrict__ hout, float* __restrict__ chist, float* __restrict__ fh)
{
  int chain = blockIdx.x;
  if (maxd_g[chain] < LMAX) return;
  int tid = threadIdx.x;
  bool act = tid < H_;
  __shared__ float h_lds[H_];
  size_t cb = (size_t)chain*T_*H_, xb = (size_t)chain*T_*HG;
  const int* ei = eidx_g + chain*ECAP;
  const float* ewp = ew_g + chain*ECAP;
  for (int j = 0; j < T_; ++j) {
    if (depth_g[chain*T_+j] < LMAX) continue;
    if (act) {
      const float* xp = xg + xb + (size_t)j*HG;
      float iu = xp[tid], x1b = xp[H_+tid], og = xp[2*H_+tid];
      float acc = iu;
      int c0 = coff_g[chain*T_+j], c1 = c0 + cnt_g[chain*T_+j];
      for (int k = c0; k < c1; ++k) {
        int t = ei[k];
        acc += ewp[k] * sigm(x1b + fh[cb + (size_t)t*H_ + tid]) * chist[cb + (size_t)t*H_ + tid];
      }
      chist[cb + (size_t)j*H_ + tid] = acc;
      float hv = og * tanhf(acc);
      hout[cb + (size_t)j*H_ + tid] = hv;
      h_lds[tid] = hv;
    }
    __syncthreads();
    if (hasp_g[chain*T_+j] && act) {
      float a = 0.f;
      const float* up = uh1T + tid;
      #pragma unroll 4
      for (int m = 0; m < H_; ++m) a = fmaf(up[(size_t)m*H_], h_lds[m], a);
      fh[cb + (size_t)j*H_ + tid] = a;
    }
    __syncthreads();
  }
}

// ---------------- split-bf16 MFMA GEMM v2: pre-split operands, latency-overlapped, swizzled LDS ----
// C[8192,N] = act(A @ W^T + bias), A/W given as bf16 hi/lo with padded K (multiple of 32).
// OUTBF=0: fp32 C (stride N). OUTBF=1: bf16 hi/lo C (stride CS, zero-padded cols).
template<int OUTBF>
__global__ __launch_bounds__(256) void k_gemm_bf(
    const ushort_t* __restrict__ Ah, const ushort_t* __restrict__ Al, int AS,
    const ushort_t* __restrict__ Wh, const ushort_t* __restrict__ Wl, int WS,
    const float* __restrict__ bias, float* __restrict__ C,
    ushort_t* __restrict__ Ch, ushort_t* __restrict__ Cl, int CS,
    int N, int NT, int act)
{
  __shared__ ushort_t sAh[128*32], sAl[128*32], sWh[128*32], sWl[128*32];  // 32 KB
  int tid = threadIdx.x;
  int bn = blockIdx.x * 128, bm = blockIdx.y * 128;
  int lane = tid & 63, wave = tid >> 6;
  int wr = (wave >> 1) * 64, wc = (wave & 1) * 64;
  int lrow = lane & 15, q = lane >> 4;

  // staging: thread -> row tid>>1, element half [0,16) or [16,32) of the 32-wide K chunk
  int srow = tid >> 1, half = tid & 1;
  int ssw = (srow >> 1) & 3;
  int sg0 = ((2*half) ^ ssw) * 8, sg1 = ((2*half+1) ^ ssw) * 8;   // swizzled granule offsets (ushorts)
  int sbase = srow * 32;
  const ushort_t* pAh = Ah + (size_t)(bm + srow)*AS + half*16;
  const ushort_t* pAl = Al + (size_t)(bm + srow)*AS + half*16;
  int wrow = bn + srow;
  int wsafe = (wrow < N) ? wrow : 0;
  const ushort_t* pWh = Wh + (size_t)wsafe*WS + half*16;
  const ushort_t* pWl = Wl + (size_t)wsafe*WS + half*16;

  bf16x8 rA0, rA1, rAl0, rAl1, rW0, rW1, rWl0, rWl1;
  auto issue = [&](int t){
    int kb = t * 32;
    rA0  = *(const bf16x8*)(pAh + kb); rA1  = *(const bf16x8*)(pAh + kb + 8);
    rAl0 = *(const bf16x8*)(pAl + kb); rAl1 = *(const bf16x8*)(pAl + kb + 8);
    rW0  = *(const bf16x8*)(pWh + kb); rW1  = *(const bf16x8*)(pWh + kb + 8);
    rWl0 = *(const bf16x8*)(pWl + kb); rWl1 = *(const bf16x8*)(pWl + kb + 8);
  };
  auto commit = [&](){
    *(bf16x8*)&sAh[sbase + sg0] = rA0; *(bf16x8*)&sAh[sbase + sg1] = rA1;
    *(bf16x8*)&sAl[sbase + sg0] = rAl0; *(bf16x8*)&sAl[sbase + sg1] = rAl1;
    *(bf16x8*)&sWh[sbase + sg0] = rW0; *(bf16x8*)&sWh[sbase + sg1] = rW1;
    *(bf16x8*)&sWl[sbase + sg0] = rWl0; *(bf16x8*)&sWl[sbase + sg1] = rWl1;
  };

  f32x4 acc[4][4];
  #pragma unroll
  for (int m = 0; m < 4; ++m)
    #pragma unroll
    for (int n = 0; n < 4; ++n) acc[m][n] = (f32x4){0.f,0.f,0.f,0.f};

  issue(0); commit();
  __syncthreads();
  for (int t = 0; t < NT; ++t) {
    bool more = (t+1 < NT);
    if (more) issue(t+1);               // global loads fly under ds_reads + MFMA
    bf16x8 ah[4], al[4], bh[4], bl[4];
    #pragma unroll
    for (int m = 0; m < 4; ++m) {
      int R = wr + m*16 + lrow;
      int o = R*32 + ((q ^ ((R>>1)&3)) * 8);
      ah[m] = *(const bf16x8*)&sAh[o];
      al[m] = *(const bf16x8*)&sAl[o];
    }
    #pragma unroll
    for (int n = 0; n < 4; ++n) {
      int R = wc + n*16 + lrow;
      int o = R*32 + ((q ^ ((R>>1)&3)) * 8);
      bh[n] = *(const bf16x8*)&sWh[o];
      bl[n] = *(const bf16x8*)&sWl[o];
    }
    #pragma unroll
    for (int m = 0; m < 4; ++m)
      #pragma unroll
      for (int n = 0; n < 4; ++n) {
        acc[m][n] = __builtin_amdgcn_mfma_f32_16x16x32_bf16(ah[m], bh[n], acc[m][n], 0,0,0);
        acc[m][n] = __builtin_amdgcn_mfma_f32_16x16x32_bf16(ah[m], bl[n], acc[m][n], 0,0,0);
        acc[m][n] = __builtin_amdgcn_mfma_f32_16x16x32_bf16(al[m], bh[n], acc[m][n], 0,0,0);
      }
    __syncthreads();                    // frag reads done; loads drained (covered by MFMA)
    if (more) commit();
    __syncthreads();
  }
  // epilogue: D row=(lane>>4)*4+r, col=lane&15  [m89-verified]
  #pragma unroll
  for (int m = 0; m < 4; ++m) {
    int row0 = bm + wr + m*16 + (lane >> 4)*4;
    #pragma unroll
    for (int n = 0; n < 4; ++n) {
      int col = bn + wc + n*16 + lrow;
      if (OUTBF) {
        if (col < CS) {
          float bv = (col < N) ? bias[col] : 0.f;
          #pragma unroll
          for (int r = 0; r < 4; ++r) {
            float v = 0.f;
            if (col < N) { v = acc[m][n][r] + bv; if (act) v = fmaxf(v, 0.f); }
            ushort_t h = f2bf(v);
            Ch[(size_t)(row0 + r)*CS + col] = h;
            Cl[(size_t)(row0 + r)*CS + col] = f2bf(v - bf2f(h));
          }
        }
      } else {
        if (col < N) {
          float bv = bias[col];
          #pragma unroll
          for (int r = 0; r < 4; ++r) {
            float v = acc[m][n][r] + bv;
            if (act) v = fmaxf(v, 0.f);
            C[(size_t)(row0 + r)*N + col] = v;
          }
        }
      }
    }
  }
}

// ---------------- fused MFMA attention (round-8 proven) ----------------
__global__ __launch_bounds__(256) void k_attn_mfma(
    const float* __restrict__ Hm, const int* __restrict__ plen, const int* __restrict__ hlen,
    float* __restrict__ ATT)
{
  __shared__ float regA_f[12800];
  __shared__ ushort_t pbuf[2*64*136];
  ushort_t* regA = (ushort_t*)regA_f;

  int tid = threadIdx.x;
  int lane = tid & 63, wave = tid >> 6;
  int lrow = lane & 15, koff = (lane >> 4) * 8;
  int d = blockIdx.x, b = blockIdx.y, q0 = blockIdx.z * 64;
  const float* Q  = Hm + ((size_t)(d*B_ + b)*T_ + q0) * H_;
  const float* Kp = Hm + ((size_t)((1-d)*B_ + b)*T_) * H_;
  float* outp = ATT + ((size_t)(d*B_ + b)*T_ + q0) * H_;
  int klen = (d == 0) ? hlen[b] : plen[b];

  ushort_t* sQh = regA;
  ushort_t* sQl = regA + 2560;
  ushort_t* sKh = regA + 5120;
  ushort_t* sKl = regA + 10240;
  int qrow = tid >> 2, qk0 = (tid & 3) * 8;
  int krow = tid >> 1, kk0 = (tid & 1) * 16;
  const float* Qr = Q + (size_t)qrow*H_;
  const float* Kr = Kp + (size_t)krow*H_;

  float4 gq[2], gk4[4];
  auto issue1 = [&](int t){
    int kb = t*32;
    #pragma unroll
    for (int i = 0; i < 2; ++i) {
      int g = kb + qk0 + i*4;
      gq[i] = make_float4(0.f,0.f,0.f,0.f);
      if (g < H_) gq[i] = *(const float4*)(Qr + g);
    }
    #pragma unroll
    for (int i = 0; i < 4; ++i) {
      int g = kb + kk0 + i*4;
      gk4[i] = make_float4(0.f,0.f,0.f,0.f);
      if (g < H_) gk4[i] = *(const float4*)(Kr + g);
    }
  };
  auto commit1 = [&](){
    #pragma unroll
    for (int i = 0; i < 2; ++i) {
      float4 v = gq[i]; ushort4 h, l;
      h.x=f2bf(v.x); h.y=f2bf(v.y); h.z=f2bf(v.z); h.w=f2bf(v.w);
      l.x=f2bf(v.x-bf2f(h.x)); l.y=f2bf(v.y-bf2f(h.y)); l.z=f2bf(v.z-bf2f(h.z)); l.w=f2bf(v.w-bf2f(h.w));
      int o = qrow*40 + qk0 + i*4;
      *(ushort4*)&sQh[o] = h; *(ushort4*)&sQl[o] = l;
    }
    #pragma unroll
    for (int i = 0; i < 4; ++i) {
      float4 v = gk4[i]; ushort4 h, l;
      h.x=f2bf(v.x); h.y=f2bf(v.y); h.z=f2bf(v.z); h.w=f2bf(v.w);
      l.x=f2bf(v.x-bf2f(h.x)); l.y=f2bf(v.y-bf2f(h.y)); l.z=f2bf(v.z-bf2f(h.z)); l.w=f2bf(v.w-bf2f(h.w));
      int o = krow*40 + kk0 + i*4;
      *(ushort4*)&sKh[o] = h; *(ushort4*)&sKl[o] = l;
    }
  };

  f32x4 acc1[4][2];
  #pragma unroll
  for (int m = 0; m < 4; ++m)
    #pragma unroll
    for (int n = 0; n < 2; ++n) acc1[m][n] = (f32x4){0.f,0.f,0.f,0.f};
  int wc = wave * 32;

  issue1(0); commit1();
  __syncthreads();
  for (int t = 0; t < 10; ++t) {
    bool more = (t < 9);
    bf16x8 ah[4], al[4], bh[2], bl[2];
    #pragma unroll
    for (int m = 0; m < 4; ++m) {
      int o = (m*16 + lrow)*40 + koff;
      ah[m] = *(const bf16x8*)&sQh[o];
      al[m] = *(const bf16x8*)&sQl[o];
    }
    #pragma unroll
    for (int n = 0; n < 2; ++n) {
      int o = (wc + n*16 + lrow)*40 + koff;
      bh[n] = *(const bf16x8*)&sKh[o];
      bl[n] = *(const bf16x8*)&sKl[o];
    }
    if (more) issue1(t+1);
    __syncthreads();
    if (more) commit1();
    #pragma unroll
    for (int m = 0; m < 4; ++m)
      #pragma unroll
      for (int n = 0; n < 2; ++n) {
        acc1[m][n] = __builtin_amdgcn_mfma_f32_16x16x32_bf16(ah[m], bh[n], acc1[m][n], 0,0,0);
        acc1[m][n] = __builtin_amdgcn_mfma_f32_16x16x32_bf16(ah[m], bl[n], acc1[m][n], 0,0,0);
        acc1[m][n] = __builtin_amdgcn_mfma_f32_16x16x32_bf16(al[m], bh[n], acc1[m][n], 0,0,0);
      }
    __syncthreads();
  }
  float* sim = regA_f;
  #pragma unroll
  for (int m = 0; m < 4; ++m)
    #pragma unroll
    for (int n = 0; n < 2; ++n)
      #pragma unroll
      for (int r = 0; r < 4; ++r)
        sim[(m*16 + (lane>>4)*4 + r)*132 + wc + n*16 + lrow] = acc1[m][n][r];
  __syncthreads();

  {
    int row = tid >> 2, qtr = (tid & 3) * 32;
    const float* sr = sim + row*132;
    float mx = NEGV;
    for (int c = 0; c < 32; ++c) { int cg = qtr + c; float s = (cg < klen) ? sr[cg] : NEGV; mx = fmaxf(mx, s); }
    mx = fmaxf(mx, __shfl_xor(mx, 1));
    mx = fmaxf(mx, __shfl_xor(mx, 2));
    float sum = 0.f;
    for (int c = 0; c < 32; ++c) { int cg = qtr + c; if (cg < klen) sum += expf(sr[cg] - mx); }
    sum += __shfl_xor(sum, 1);
    sum += __shfl_xor(sum, 2);
    float rinv = 1.f / sum;
    for (int c = 0; c < 32; ++c) {
      int cg = qtr + c;
      float p = (cg < klen) ? expf(sr[cg] - mx) * rinv : 0.f;
      ushort_t h = f2bf(p);
      pbuf[row*136 + cg] = h;
      pbuf[64*136 + row*136 + cg] = f2bf(p - bf2f(h));
    }
  }
  __syncthreads();

  ushort_t* kth = regA;
  ushort_t* ktl = regA + 12800;
  int wr2 = (wave & 1) * 32;
  int wcf = (wave >> 1) * 160;
  f32x4 acc3[2][10];
  #pragma unroll
  for (int m = 0; m < 2; ++m)
    #pragma unroll
    for (int n = 0; n < 10; ++n) acc3[m][n] = (f32x4){0.f,0.f,0.f,0.f};
  int skey = tid >> 3, sf4 = tid & 7;

  for (int kc = 0; kc < 4; ++kc) {
    __syncthreads();
    const float* kr = Kp + (size_t)(kc*32 + skey)*H_;
    for (int f4 = sf4; f4 < 75; f4 += 8) {
      float4 v = *(const float4*)(kr + f4*4);
      float vv[4] = {v.x, v.y, v.z, v.w};
      #pragma unroll
      for (int i = 0; i < 4; ++i) {
        int feat = f4*4 + i;
        ushort_t h = f2bf(vv[i]);
        kth[feat*40 + skey] = h;
        ktl[feat*40 + skey] = f2bf(vv[i] - bf2f(h));
      }
    }
    __syncthreads();
    bf16x8 ph[2], pl[2], kh[10], kl[10];
    #pragma unroll
    for (int m = 0; m < 2; ++m) {
      int o = (wr2 + m*16 + lrow)*136 + kc*32 + koff;
      ph[m] = *(const bf16x8*)&pbuf[o];
      pl[m] = *(const bf16x8*)&pbuf[64*136 + o];
    }
    #pragma unroll
    for (int n = 0; n < 10; ++n) {
      int o = (wcf + n*16 + lrow)*40 + koff;
      kh[n] = *(const bf16x8*)&kth[o];
      kl[n] = *(const bf16x8*)&ktl[o];
    }
    #pragma unroll
    for (int m = 0; m < 2; ++m)
      #pragma unroll
      for (int n = 0; n < 10; ++n) {
        acc3[m][n] = __builtin_amdgcn_mfma_f32_16x16x32_bf16(ph[m], kh[n], acc3[m][n], 0,0,0);
        acc3[m][n] = __builtin_amdgcn_mfma_f32_16x16x32_bf16(ph[m], kl[n], acc3[m][n], 0,0,0);
        acc3[m][n] = __builtin_amdgcn_mfma_f32_16x16x32_bf16(pl[m], kh[n], acc3[m][n], 0,0,0);
      }
  }
  #pragma unroll
  for (int m = 0; m < 2; ++m) {
    int row0 = wr2 + m*16 + (lane >> 4)*4;
    #pragma unroll
    for (int n = 0; n < 10; ++n) {
      int col = wcf + n*16 + lrow;
      if (col < H_) {
        #pragma unroll
        for (int r = 0; r < 4; ++r)
          outp[(size_t)(row0 + r)*H_ + col] = acc3[m][n][r];
      }
    }
  }
}

// ---------------- pool stage 1 ----------------
__global__ __launch_bounds__(320) void k_pool(const float* __restrict__ H,
    const int* __restrict__ plen, const int* __restrict__ hlen,
    float* __restrict__ psum, float* __restrict__ pmax)
{
  int chain = blockIdx.x; int s = chain >> 5, b = chain & 31;
  int c = blockIdx.y; int t0 = c * 16;
  int len = (s == 0 ? plen[b] : hlen[b]);
  int tid = threadIdx.x;
  __shared__ float buf[16*H_];
  const float* hp = H + (size_t)chain*T_*H_ + (size_t)t0*H_;
  for (int i = tid; i < 16*H_; i += 320) buf[i] = hp[i];
  __syncthreads();
  if (tid < H_) {
    int tmax = len - t0; if (tmax > 16) tmax = 16;
    float sum = 0.f, mx = NEGV;
    for (int t = 0; t < tmax; ++t) { float x = buf[t*H_ + tid]; sum += x; mx = fmaxf(mx, x); }
    int o = (chain*8 + c)*H_ + tid;
    psum[o] = sum; pmax[o] = mx;
  }
}

// ---------------- pool stage 2 + classifier ----------------
__global__ __launch_bounds__(320) void k_classify(
    const float* __restrict__ psum, const float* __restrict__ pmax,
    const int* __restrict__ plen, const int* __restrict__ hlen,
    const float* __restrict__ w1t, const float* __restrict__ b1,
    const float* __restrict__ w2, const float* __restrict__ b2,
    float* __restrict__ out)
{
  int b = blockIdx.x;
  int tid = threadIdx.x;
  __shared__ float v[HG];
  __shared__ float hid[H_];
  for (int s = 0; s < 2; ++s) {
    int chain = s*B_ + b;
    int len = (s == 0 ? plen[b] : hlen[b]);
    if (tid < H_) {
      float sum = 0.f, mx = NEGV;
      #pragma unroll
      for (int c = 0; c < 8; ++c) {
        int o = (chain*8 + c)*H_ + tid;
        sum += psum[o]; mx = fmaxf(mx, pmax[o]);
      }
      v[s*600 + tid]       = sum / (float)len;
      v[s*600 + 300 + tid] = mx;
    }
  }
  __syncthreads();
  if (tid < H_) {
    float a0 = b1[tid], a1 = 0.f, a2 = 0.f, a3 = 0.f;
    for (int m = 0; m < HG; m += 4) {
      a0 = fmaf(v[m+0], w1t[(size_t)(m+0)*H_ + tid], a0);
      a1 = fmaf(v[m+1], w1t[(size_t)(m+1)*H_ + tid], a1);
      a2 = fmaf(v[m+2], w1t[(size_t)(m+2)*H_ + tid], a2);
      a3 = fmaf(v[m+3], w1t[(size_t)(m+3)*H_ + tid], a3);
    }
    hid[tid] = tanhf(a0 + a1 + a2 + a3);
  }
  __syncthreads();
  if (tid < 3) {
    float a = b2[tid];
    const float* wr = w2 + (size_t)tid*H_;
    for (int n = 0; n < H_; ++n) a = fmaf(hid[n], wr[n], a);
    out[b*3 + tid] = a;
  }
}

// ---------------- launch ----------------
extern "C" void kernel_launch(void* const* d_in, const int* in_sizes, int n_in,
                              void* d_out, int out_size, void* d_ws, size_t ws_size,
                              hipStream_t stream) {
  const int*   prem    = (const int*)d_in[0];
  const int*   plen    = (const int*)d_in[1];
  const int*   hyp     = (const int*)d_in[2];
  const int*   hlen    = (const int*)d_in[3];
  const float* lg      = (const float*)d_in[4];
  const float* rg      = (const float*)d_in[5];
  const float* emb     = (const float*)d_in[6];
  const float* enc_wx  = (const float*)d_in[7];
  const float* enc_bx  = (const float*)d_in[8];
  const float* enc_uh  = (const float*)d_in[9];
  const float* enc_bh  = (const float*)d_in[10];
  const float* comp_wx = (const float*)d_in[11];
  const float* comp_bx = (const float*)d_in[12];
  const float* comp_uh = (const float*)d_in[13];
  const float* comp_bh = (const float*)d_in[14];
  const float* proj_w  = (const float*)d_in[15];
  const float* proj_b  = (const float*)d_in[16];
  const float* cls_w1  = (const float*)d_in[17];
  const float* cls_b1  = (const float*)d_in[18];
  const float* cls_w2  = (const float*)d_in[19];
  const float* cls_b2  = (const float*)d_in[20];
  float* outp = (float*)d_out;

  // workspace layout (floats); ENH bf16 aliases XG; PROJ bf16 aliases EH/EL
  float* XG  = (float*)d_ws;                       // 9,830,400 f  (enc/comp xg fp32; ENH hi/lo bf16)
  ushort_t* EH = (ushort_t*)(XG + 9830400);        // [8192][320] hi   (also PROJ hi)
  ushort_t* EL = EH + 2621440;                     // [8192][320] lo   (also PROJ lo)
  float* H1  = XG + 9830400 + 2621440;             // 2,457,600
  float* CH  = H1 + 2457600;                       // 2,457,600 (ATT alias)
  float* FH  = CH + 2457600;                       // 2,457,600
  float* UTE = FH + 2457600;                       // 90,000
  float* UTC = UTE + 90000;                        // 90,000
  float* W1T = UTC + 90000;                        // 360,000
  ushort_t* WencH  = (ushort_t*)(W1T + 360000);    // 384,000 each
  ushort_t* WencL  = WencH + 384000;
  ushort_t* WcompH = WencL + 384000;
  ushort_t* WcompL = WcompH + 384000;
  ushort_t* WPH    = WcompL + 384000;              // 278,400 each
  ushort_t* WPL    = WPH + 278400;
  float* PSUM = W1T + 360000 + 1046400;            // 153,600
  float* PMAX = PSUM + 153600;                     // 153,600
  float* EW   = PMAX + 153600;                     // 131,072
  int* EIDX   = (int*)(EW + 64*ECAP);              // 131,072
  int* CNT    = EIDX + 64*ECAP;
  int* COFF   = CNT + 64*T_;
  int* DEPTH  = COFF + 64*T_;
  int* HASP   = DEPTH + 64*T_;
  int* MAXD   = HASP + 64*T_;
  int* LVLCNT = MAXD + 64;
  int* WL     = LVLCNT + LMAX;
  float* ATT  = CH;
  ushort_t* ENH_H = (ushort_t*)XG;                 // [8192][928] hi (after enc scan, XG dead)
  ushort_t* ENH_L = ENH_H + 7602176;

  hipMemsetAsync(LVLCNT, 0, LMAX*sizeof(int), stream);
  // 1. weight prep + graph analysis + embedding split
  k_prep_all<<<(1496400 + 255)/256, 256, 0, stream>>>(enc_uh, comp_uh, enc_wx, comp_wx, proj_w, cls_w1,
      UTE, UTC, W1T, WencH, WencL, WcompH, WcompL, WPH, WPL);
  k_build<<<64, 256, 0, stream>>>(lg, rg, CNT, COFF, EIDX, EW, HASP, DEPTH, MAXD, LVLCNT, WL);
  k_embed_split<<<10240, 256, 0, stream>>>(prem, hyp, emb, EH, EL);
  // 2. enc xg = emb @ enc_wx^T + enc_bx
  k_gemm_bf<0><<<dim3(10, 64), 256, 0, stream>>>(EH, EL, 320, WencH, WencL, 320,
      enc_bx, XG, nullptr, nullptr, 0, HG, 10, 0);
  k_gates<<<(2*B_*T_*H_ + 255)/256, 256, 0, stream>>>(XG, enc_bh);
  // 3. enc tree scan
  for (int L = 0; L < LMAX; ++L)
    k_level<<<640, 1024, 0, stream>>>(XG, UTE, CNT, COFF, EIDX, EW, HASP, LVLCNT, WL, L, H1, CH, FH);
  k_tail<<<64, 320, 0, stream>>>(XG, UTE, CNT, COFF, EIDX, EW, HASP, DEPTH, MAXD, H1, CH, FH);
  // 4. attention (CH dead -> ATT)
  k_attn_mfma<<<dim3(2, B_, 2), 256, 0, stream>>>(H1, plen, hlen, ATT);
  // 5. enhance split into XG region (enc-xg dead), then proj GEMM -> PROJ bf16 hi/lo
  k_enh_split<<<29696, 256, 0, stream>>>(H1, ATT, ENH_H, ENH_L);
  k_gemm_bf<1><<<dim3(3, 64), 256, 0, stream>>>(ENH_H, ENH_L, 928, WPH, WPL, 928,
      proj_b, nullptr, EH, EL, 320, H_, 29, 1);
  // 6. comp xg = proj @ comp_wx^T + comp_bx (overwrites XG; ENH dead)
  k_gemm_bf<0><<<dim3(10, 64), 256, 0, stream>>>(EH, EL, 320, WcompH, WcompL, 320,
      comp_bx, XG, nullptr, nullptr, 0, HG, 10, 0);
  k_gates<<<(2*B_*T_*H_ + 255)/256, 256, 0, stream>>>(XG, comp_bh);
  // 7. comp tree scan
  for (int L = 0; L < LMAX; ++L)
    k_level<<<640, 1024, 0, stream>>>(XG, UTC, CNT, COFF, EIDX, EW, HASP, LVLCNT, WL, L, H1, CH, FH);
  k_tail<<<64, 320, 0, stream>>>(XG, UTC, CNT, COFF, EIDX, EW, HASP, DEPTH, MAXD, H1, CH, FH);
  // 8. pool + classifier
  k_pool<<<dim3(64, 8), 320, 0, stream>>>(H1, plen, hlen, PSUM, PMAX);
  k_classify<<<B_, 320, 0, stream>>>(PSUM, PMAX, plen, hlen, W1T, cls_b1, cls_w2, cls_b2, outp);
}

// Round 10
// 519.958 us; speedup vs baseline: 2.6736x; 1.1481x over previous
//
#include <hip/hip_runtime.h>
#include <math.h>

#define B_ 32
#define T_ 128
#define H_ 300
#define HG 1200   // 4*H
#define LMAX 10
#define WLCAP 8192
#define ECAP 2048
#define NEGV -10000000.0f

typedef __attribute__((ext_vector_type(8))) short bf16x8;
typedef __attribute__((ext_vector_type(4))) float f32x4;
typedef unsigned short ushort_t;

__device__ __forceinline__ float sigm(float x){ return 1.f/(1.f+expf(-x)); }

__device__ __forceinline__ unsigned short f2bf(float x){
  union { float f; unsigned int u; } c; c.f = x;
  unsigned int u = c.u;
  return (unsigned short)((u + 0x7fffu + ((u >> 16) & 1u)) >> 16);
}
__device__ __forceinline__ float bf2f(unsigned short h){
  union { unsigned int u; float f; } c; c.u = ((unsigned int)h) << 16;
  return c.f;
}

// ---------------- fused weight prep: fp32 transposes + bf16 hi/lo padded weights ----------------
__global__ __launch_bounds__(256) void k_prep_all(
    const float* __restrict__ enc_uh, const float* __restrict__ comp_uh,
    const float* __restrict__ enc_wx, const float* __restrict__ comp_wx,
    const float* __restrict__ pw, const float* __restrict__ cw1,
    float* __restrict__ te, float* __restrict__ tc, float* __restrict__ w1t,
    ushort_t* __restrict__ WencH, ushort_t* __restrict__ WencL,
    ushort_t* __restrict__ WcompH, ushort_t* __restrict__ WcompL,
    ushort_t* __restrict__ WPH, ushort_t* __restrict__ WPL)
{
  int i = blockIdx.x*256 + threadIdx.x;
  if (i < 90000) {                       // uh1 transposes: te/tc[m][k] = uh[1][k][m]
    int m = i / H_, k = i - m*H_;
    te[i] = enc_uh[H_*H_ + (size_t)k*H_ + m];
    tc[i] = comp_uh[H_*H_ + (size_t)k*H_ + m];
  } else if (i < 450000) {               // w1t (1200 x 300): w1t[m][k] = cw1[k][m]
    int i2 = i - 90000;
    int m = i2 / H_, k = i2 - m*H_;
    w1t[i2] = cw1[(size_t)k*HG + m];
  } else if (i < 834000) {               // Wenc hi/lo [1200][320], zero-padded
    int i2 = i - 450000;
    int n = i2 / 320, k = i2 - n*320;
    float v = (k < 300) ? enc_wx[(size_t)n*300 + k] : 0.f;
    ushort_t h = f2bf(v);
    WencH[i2] = h; WencL[i2] = f2bf(v - bf2f(h));
  } else if (i < 1218000) {              // Wcomp hi/lo [1200][320]
    int i2 = i - 834000;
    int n = i2 / 320, k = i2 - n*320;
    float v = (k < 300) ? comp_wx[(size_t)n*300 + k] : 0.f;
    ushort_t h = f2bf(v);
    WcompH[i2] = h; WcompL[i2] = f2bf(v - bf2f(h));
  } else if (i < 1496400) {              // folded proj W hi/lo [300][928]
    int i2 = i - 1218000;
    int n = i2 / 928, k = i2 - n*928;
    const float* r = pw + (size_t)n*HG;
    float v = 0.f;
    if (k < 300)      v = r[k] + r[600+k];
    else if (k < 600) v = r[k] - r[k+300];
    else if (k < 900) v = r[k+300];
    ushort_t h = f2bf(v);
    WPH[i2] = h; WPL[i2] = f2bf(v - bf2f(h));
  }
}

// ---------------- embedding gather + bf16 split: [8192][320] hi/lo ----------------
__global__ __launch_bounds__(256) void k_embed_split(const int* __restrict__ prem, const int* __restrict__ hyp,
    const float* __restrict__ emb, ushort_t* __restrict__ EH, ushort_t* __restrict__ EL)
{
  int i = blockIdx.x*256 + threadIdx.x;      // over 8192*320
  int bt = i / 320, k = i - bt*320;
  int side = bt >> 12, bt2 = bt & 4095;
  float v = 0.f;
  if (k < 300) {
    int tok = (side == 0 ? prem : hyp)[bt2];
    v = emb[(size_t)tok*H_ + k];
  }
  ushort_t h = f2bf(v);
  EH[i] = h; EL[i] = f2bf(v - bf2f(h));
}

// ---------------- enhance + bf16 split: A=[H1|ATT|H1*ATT] -> [8192][928] hi/lo ----------------
__global__ __launch_bounds__(256) void k_enh_split(const float* __restrict__ H1, const float* __restrict__ ATT,
    ushort_t* __restrict__ AH, ushort_t* __restrict__ AL)
{
  int i = blockIdx.x*256 + threadIdx.x;      // over 8192*928
  int r = i / 928, k = i - r*928;
  float v = 0.f;
  if (k < 300)      v = H1[(size_t)r*H_ + k];
  else if (k < 600) v = ATT[(size_t)r*H_ + k - 300];
  else if (k < 900) { int kk = k - 600; v = H1[(size_t)r*H_ + kk] * ATT[(size_t)r*H_ + kk]; }
  ushort_t h = f2bf(v);
  AH[i] = h; AL[i] = f2bf(v - bf2f(h));
}

// ---------------- graph analysis v2: LDS-staged graph, low-contention worklists ----------------
__global__ __launch_bounds__(256) void k_build(const float* __restrict__ lg, const float* __restrict__ rg,
    int* __restrict__ cnt_g, int* __restrict__ coff_g, int* __restrict__ eidx_g, float* __restrict__ ew_g,
    int* __restrict__ hasp_g, int* __restrict__ depth_g, int* __restrict__ maxd_g,
    int* __restrict__ lvlcnt_g, int* __restrict__ wl_g)
{
  int chain = blockIdx.x; int s = chain >> 5, b = chain & 31;
  const float* graph = (s ? rg : lg) + (size_t)b*T_*T_;
  int tid = threadIdx.x;
  __shared__ float gbuf[T_*T_];            // 64 KB: whole graph tile
  __shared__ int cnt[T_], coff[T_], depth[T_], hasp[T_];
  __shared__ short eidx[ECAP];
  __shared__ float ew[ECAP];
  __shared__ int lcnt[LMAX], lbase[LMAX], lpos[LMAX];
  __shared__ int etot_s;

  // stage graph coalesced: 4096 float4s / 256 threads = 16 each
  #pragma unroll
  for (int k = 0; k < 16; ++k)
    ((float4*)gbuf)[tid + k*256] = ((const float4*)graph)[tid + k*256];
  if (tid < T_) hasp[tid] = 0;
  if (tid < LMAX) { lcnt[tid] = 0; lpos[tid] = 0; }
  __syncthreads();
  // count children (from LDS)
  if (tid < T_) {
    int j = tid, c = 0;
    const float* gr = gbuf + j*T_;
    for (int t = 0; t < j; ++t) c += (gr[t] != 0.f) ? 1 : 0;
    cnt[j] = c;
  }
  __syncthreads();
  if (tid == 0) { int a = 0; for (int j = 0; j < T_; ++j) { coff[j] = a; a += cnt[j]; } etot_s = a; }
  __syncthreads();
  // fill edge lists + parent flags (from LDS)
  if (tid < T_) {
    int j = tid, p = coff[j];
    const float* gr = gbuf + j*T_;
    for (int t = 0; t < j; ++t) {
      float g = gr[t];
      if (g != 0.f && p < ECAP) { eidx[p] = (short)t; ew[p] = g; hasp[t] = 1; ++p; }
    }
  }
  __syncthreads();
  // depths (serial; all LDS)
  if (tid == 0) {
    int md = 0;
    for (int j = 0; j < T_; ++j) {
      int d = 0, e0 = coff[j], e1 = coff[j] + cnt[j];
      if (e1 > ECAP) e1 = ECAP;
      for (int k = e0; k < e1; ++k) { int dd = depth[eidx[k]] + 1; d = dd > d ? dd : d; }
      depth[j] = d; md = d > md ? d : md;
    }
    maxd_g[chain] = md;
  }
  __syncthreads();
  // per-level local counts (LDS atomics), then ONE global reservation per (chain,level)
  if (tid < T_) { int L = depth[tid]; if (L < LMAX) atomicAdd(&lcnt[L], 1); }
  __syncthreads();
  if (tid < LMAX && lcnt[tid] > 0) lbase[tid] = atomicAdd(&lvlcnt_g[tid], lcnt[tid]);
  __syncthreads();
  if (tid < T_) {
    int L = depth[tid];
    if (L < LMAX) {
      int p = atomicAdd(&lpos[L], 1);
      wl_g[L*WLCAP + lbase[L] + p] = (chain << 8) | tid;
    }
  }
  // commit per-chain arrays
  int base = chain * T_;
  if (tid < T_) {
    cnt_g[base+tid] = cnt[tid]; coff_g[base+tid] = coff[tid];
    hasp_g[base+tid] = hasp[tid]; depth_g[base+tid] = depth[tid];
  }
  int etot = etot_s; if (etot > ECAP) etot = ECAP;
  for (int i = tid; i < etot; i += 256) { eidx_g[chain*ECAP + i] = eidx[i]; ew_g[chain*ECAP + i] = ew[i]; }
}

// ---------------- per-level tree-LSTM (inline gates, round-4 proven) ----------------
__global__ __launch_bounds__(1024) void k_level(
    const float* __restrict__ xg, const float* __restrict__ bhv, const float* __restrict__ uh1T,
    const int* __restrict__ cnt_g, const int* __restrict__ coff_g,
    const int* __restrict__ eidx_g, const float* __restrict__ ew_g,
    const int* __restrict__ hasp_g, const int* __restrict__ lvlcnt_g, const int* __restrict__ wl_g,
    int L, float* __restrict__ hout, float* __restrict__ chist, float* __restrict__ fh)
{
  int count = lvlcnt_g[L];
  int nblk = (count + 3) >> 2;
  int tid = threadIdx.x;
  __shared__ float h_s[4][H_];
  __shared__ float psum[3][4][H_];
  __shared__ int nodes[4];
  __shared__ int anyp;
  for (int blk = blockIdx.x; blk < nblk; blk += gridDim.x) {
    int base = blk * 4;
    int nn = count - base; if (nn > 4) nn = 4;
    if (tid == 0) anyp = 0;
    __syncthreads();
    if (tid < 4) {
      int pk = (tid < nn) ? wl_g[L*WLCAP + base + tid] : -1;
      nodes[tid] = pk;
      if (pk >= 0 && hasp_g[(pk >> 8)*T_ + (pk & 255)]) atomicAdd(&anyp, 1);
    }
    __syncthreads();
    for (int w = tid; w < nn*H_; w += 1024) {
      int n = w / H_, e = w - n*H_;
      int pk = nodes[n]; int chain = pk >> 8, j = pk & 255;
      size_t cb = (size_t)chain*T_*H_, xb = (size_t)chain*T_*HG;
      const float* xp = xg + xb + (size_t)j*HG;
      float x0 = xp[e], x1 = xp[H_+e], x2 = xp[2*H_+e], x3 = xp[3*H_+e];
      float iu  = sigm(x0 + bhv[e]) * tanhf(x3 + bhv[3*H_+e]);
      float og  = sigm(x2 + bhv[2*H_+e]);
      float x1b = x1 + bhv[H_+e];
      float acc = iu;
      int c0 = coff_g[chain*T_+j], c1 = c0 + cnt_g[chain*T_+j];
      const int* ei = eidx_g + chain*ECAP;
      const float* ewp = ew_g + chain*ECAP;
      for (int k = c0; k < c1; ++k) {
        int t = ei[k];
        acc += ewp[k] * sigm(x1b + fh[cb + (size_t)t*H_ + e]) * chist[cb + (size_t)t*H_ + e];
      }
      chist[cb + (size_t)j*H_ + e] = acc;
      float hv = og * tanhf(acc);
      hout[cb + (size_t)j*H_ + e] = hv;
      h_s[n][e] = hv;
    }
    __syncthreads();
    if (anyp > 0) {
      if (tid < 3*H_) {
        int g = tid / H_, e = tid - g*H_;
        float a0=0.f, a1=0.f, a2=0.f, a3=0.f;
        const float* up = uh1T + e;
        int m0 = g*100, m1 = m0 + 100;
        #pragma unroll 4
        for (int m = m0; m < m1; ++m) {
          float u = up[(size_t)m*H_];
          a0 = fmaf(u, h_s[0][m], a0);
          a1 = fmaf(u, h_s[1][m], a1);
          a2 = fmaf(u, h_s[2][m], a2);
          a3 = fmaf(u, h_s[3][m], a3);
        }
        psum[g][0][e]=a0; psum[g][1][e]=a1; psum[g][2][e]=a2; psum[g][3][e]=a3;
      }
      __syncthreads();
      for (int w = tid; w < nn*H_; w += 1024) {
        int n = w / H_, e = w - n*H_;
        int pk = nodes[n]; int chain = pk >> 8, j = pk & 255;
        if (hasp_g[chain*T_+j]) {
          size_t cb = (size_t)chain*T_*H_;
          fh[cb + (size_t)j*H_ + e] = psum[0][n][e] + psum[1][n][e] + psum[2][n][e];
        }
      }
    }
    __syncthreads();
  }
}

// ---------------- serial tail for rare deep graphs (inline gates) ----------------
__global__ __launch_bounds__(320) void k_tail(const float* __restrict__ xg, const float* __restrict__ bhv,
    const float* __restrict__ uh1T, const int* __restrict__ cnt_g, const int* __restrict__ coff_g,
    const int* __restrict__ eidx_g, const float* __restrict__ ew_g, const int* __restrict__ hasp_g,
    const int* __restrict__ depth_g, const int* __restrict__ maxd_g,
    float* __restrict__ hout, float* __restrict__ chist, float* __restrict__ fh)
{
  int chain = blockIdx.x;
  if (maxd_g[chain] < LMAX) return;
  int tid = threadIdx.x;
  bool act = tid < H_;
  float bh0=0.f,bh1=0.f,bh2=0.f,bh3=0.f;
  if (act) { bh0=bhv[tid]; bh1=bhv[H_+tid]; bh2=bhv[2*H_+tid]; bh3=bhv[3*H_+tid]; }
  __shared__ float h_lds[H_];
  size_t cb = (size_t)chain*T_*H_, xb = (size_t)chain*T_*HG;
  const int* ei = eidx_g + chain*ECAP;
  const float* ewp = ew_g + chain*ECAP;
  for (int j = 0; j < T_; ++j) {
    if (depth_g[chain*T_+j] < LMAX) continue;
    if (act) {
      const float* xp = xg + xb + (size_t)j*HG;
      float x0 = xp[tid], x1 = xp[H_+tid], x2 = xp[2*H_+tid], x3 = xp[3*H_+tid];
      float acc = sigm(x0+bh0) * tanhf(x3+bh3);
      float og  = sigm(x2+bh2);
      float x1b = x1 + bh1;
      int c0 = coff_g[chain*T_+j], c1 = c0 + cnt_g[chain*T_+j];
      for (int k = c0; k < c1; ++k) {
        int t = ei[k];
        acc += ewp[k] * sigm(x1b + fh[cb + (size_t)t*H_ + tid]) * chist[cb + (size_t)t*H_ + tid];
      }
      chist[cb + (size_t)j*H_ + tid] = acc;
      float hv = og * tanhf(acc);
      hout[cb + (size_t)j*H_ + tid] = hv;
      h_lds[tid] = hv;
    }
    __syncthreads();
    if (hasp_g[chain*T_+j] && act) {
      float a = 0.f;
      const float* up = uh1T + tid;
      #pragma unroll 4
      for (int m = 0; m < H_; ++m) a = fmaf(up[(size_t)m*H_], h_lds[m], a);
      fh[cb + (size_t)j*H_ + tid] = a;
    }
    __syncthreads();
  }
}

// ---------------- split-bf16 MFMA GEMM v2 (round-9 proven) ----------------
template<int OUTBF>
__global__ __launch_bounds__(256) void k_gemm_bf(
    const ushort_t* __restrict__ Ah, const ushort_t* __restrict__ Al, int AS,
    const ushort_t* __restrict__ Wh, const ushort_t* __restrict__ Wl, int WS,
    const float* __restrict__ bias, float* __restrict__ C,
    ushort_t* __restrict__ Ch, ushort_t* __restrict__ Cl, int CS,
    int N, int NT, int act)
{
  __shared__ ushort_t sAh[128*32], sAl[128*32], sWh[128*32], sWl[128*32];  // 32 KB
  int tid = threadIdx.x;
  int bn = blockIdx.x * 128, bm = blockIdx.y * 128;
  int lane = tid & 63, wave = tid >> 6;
  int wr = (wave >> 1) * 64, wc = (wave & 1) * 64;
  int lrow = lane & 15, q = lane >> 4;

  int srow = tid >> 1, half = tid & 1;
  int ssw = (srow >> 1) & 3;
  int sg0 = ((2*half) ^ ssw) * 8, sg1 = ((2*half+1) ^ ssw) * 8;
  int sbase = srow * 32;
  const ushort_t* pAh = Ah + (size_t)(bm + srow)*AS + half*16;
  const ushort_t* pAl = Al + (size_t)(bm + srow)*AS + half*16;
  int wrow = bn + srow;
  int wsafe = (wrow < N) ? wrow : 0;
  const ushort_t* pWh = Wh + (size_t)wsafe*WS + half*16;
  const ushort_t* pWl = Wl + (size_t)wsafe*WS + half*16;

  bf16x8 rA0, rA1, rAl0, rAl1, rW0, rW1, rWl0, rWl1;
  auto issue = [&](int t){
    int kb = t * 32;
    rA0  = *(const bf16x8*)(pAh + kb); rA1  = *(const bf16x8*)(pAh + kb + 8);
    rAl0 = *(const bf16x8*)(pAl + kb); rAl1 = *(const bf16x8*)(pAl + kb + 8);
    rW0  = *(const bf16x8*)(pWh + kb); rW1  = *(const bf16x8*)(pWh + kb + 8);
    rWl0 = *(const bf16x8*)(pWl + kb); rWl1 = *(const bf16x8*)(pWl + kb + 8);
  };
  auto commit = [&](){
    *(bf16x8*)&sAh[sbase + sg0] = rA0; *(bf16x8*)&sAh[sbase + sg1] = rA1;
    *(bf16x8*)&sAl[sbase + sg0] = rAl0; *(bf16x8*)&sAl[sbase + sg1] = rAl1;
    *(bf16x8*)&sWh[sbase + sg0] = rW0; *(bf16x8*)&sWh[sbase + sg1] = rW1;
    *(bf16x8*)&sWl[sbase + sg0] = rWl0; *(bf16x8*)&sWl[sbase + sg1] = rWl1;
  };

  f32x4 acc[4][4];
  #pragma unroll
  for (int m = 0; m < 4; ++m)
    #pragma unroll
    for (int n = 0; n < 4; ++n) acc[m][n] = (f32x4){0.f,0.f,0.f,0.f};

  issue(0); commit();
  __syncthreads();
  for (int t = 0; t < NT; ++t) {
    bool more = (t+1 < NT);
    if (more) issue(t+1);
    bf16x8 ah[4], al[4], bh[4], bl[4];
    #pragma unroll
    for (int m = 0; m < 4; ++m) {
      int R = wr + m*16 + lrow;
      int o = R*32 + ((q ^ ((R>>1)&3)) * 8);
      ah[m] = *(const bf16x8*)&sAh[o];
      al[m] = *(const bf16x8*)&sAl[o];
    }
    #pragma unroll
    for (int n = 0; n < 4; ++n) {
      int R = wc + n*16 + lrow;
      int o = R*32 + ((q ^ ((R>>1)&3)) * 8);
      bh[n] = *(const bf16x8*)&sWh[o];
      bl[n] = *(const bf16x8*)&sWl[o];
    }
    #pragma unroll
    for (int m = 0; m < 4; ++m)
      #pragma unroll
      for (int n = 0; n < 4; ++n) {
        acc[m][n] = __builtin_amdgcn_mfma_f32_16x16x32_bf16(ah[m], bh[n], acc[m][n], 0,0,0);
        acc[m][n] = __builtin_amdgcn_mfma_f32_16x16x32_bf16(ah[m], bl[n], acc[m][n], 0,0,0);
        acc[m][n] = __builtin_amdgcn_mfma_f32_16x16x32_bf16(al[m], bh[n], acc[m][n], 0,0,0);
      }
    __syncthreads();
    if (more) commit();
    __syncthreads();
  }
  #pragma unroll
  for (int m = 0; m < 4; ++m) {
    int row0 = bm + wr + m*16 + (lane >> 4)*4;
    #pragma unroll
    for (int n = 0; n < 4; ++n) {
      int col = bn + wc + n*16 + lrow;
      if (OUTBF) {
        if (col < CS) {
          float bv = (col < N) ? bias[col] : 0.f;
          #pragma unroll
          for (int r = 0; r < 4; ++r) {
            float v = 0.f;
            if (col < N) { v = acc[m][n][r] + bv; if (act) v = fmaxf(v, 0.f); }
            ushort_t h = f2bf(v);
            Ch[(size_t)(row0 + r)*CS + col] = h;
            Cl[(size_t)(row0 + r)*CS + col] = f2bf(v - bf2f(h));
          }
        }
      } else {
        if (col < N) {
          float bv = bias[col];
          #pragma unroll
          for (int r = 0; r < 4; ++r) {
            float v = acc[m][n][r] + bv;
            if (act) v = fmaxf(v, 0.f);
            C[(size_t)(row0 + r)*N + col] = v;
          }
        }
      }
    }
  }
}

// ---------------- fused MFMA attention (round-8 proven) ----------------
__global__ __launch_bounds__(256) void k_attn_mfma(
    const float* __restrict__ Hm, const int* __restrict__ plen, const int* __restrict__ hlen,
    float* __restrict__ ATT)
{
  __shared__ float regA_f[12800];
  __shared__ ushort_t pbuf[2*64*136];
  ushort_t* regA = (ushort_t*)regA_f;

  int tid = threadIdx.x;
  int lane = tid & 63, wave = tid >> 6;
  int lrow = lane & 15, koff = (lane >> 4) * 8;
  int d = blockIdx.x, b = blockIdx.y, q0 = blockIdx.z * 64;
  const float* Q  = Hm + ((size_t)(d*B_ + b)*T_ + q0) * H_;
  const float* Kp = Hm + ((size_t)((1-d)*B_ + b)*T_) * H_;
  float* outp = ATT + ((size_t)(d*B_ + b)*T_ + q0) * H_;
  int klen = (d == 0) ? hlen[b] : plen[b];

  ushort_t* sQh = regA;
  ushort_t* sQl = regA + 2560;
  ushort_t* sKh = regA + 5120;
  ushort_t* sKl = regA + 10240;
  int qrow = tid >> 2, qk0 = (tid & 3) * 8;
  int krow = tid >> 1, kk0 = (tid & 1) * 16;
  const float* Qr = Q + (size_t)qrow*H_;
  const float* Kr = Kp + (size_t)krow*H_;

  float4 gq[2], gk4[4];
  auto issue1 = [&](int t){
    int kb = t*32;
    #pragma unroll
    for (int i = 0; i < 2; ++i) {
      int g = kb + qk0 + i*4;
      gq[i] = make_float4(0.f,0.f,0.f,0.f);
      if (g < H_) gq[i] = *(const float4*)(Qr + g);
    }
    #pragma unroll
    for (int i = 0; i < 4; ++i) {
      int g = kb + kk0 + i*4;
      gk4[i] = make_float4(0.f,0.f,0.f,0.f);
      if (g < H_) gk4[i] = *(const float4*)(Kr + g);
    }
  };
  auto commit1 = [&](){
    #pragma unroll
    for (int i = 0; i < 2; ++i) {
      float4 v = gq[i]; ushort4 h, l;
      h.x=f2bf(v.x); h.y=f2bf(v.y); h.z=f2bf(v.z); h.w=f2bf(v.w);
      l.x=f2bf(v.x-bf2f(h.x)); l.y=f2bf(v.y-bf2f(h.y)); l.z=f2bf(v.z-bf2f(h.z)); l.w=f2bf(v.w-bf2f(h.w));
      int o = qrow*40 + qk0 + i*4;
      *(ushort4*)&sQh[o] = h; *(ushort4*)&sQl[o] = l;
    }
    #pragma unroll
    for (int i = 0; i < 4; ++i) {
      float4 v = gk4[i]; ushort4 h, l;
      h.x=f2bf(v.x); h.y=f2bf(v.y); h.z=f2bf(v.z); h.w=f2bf(v.w);
      l.x=f2bf(v.x-bf2f(h.x)); l.y=f2bf(v.y-bf2f(h.y)); l.z=f2bf(v.z-bf2f(h.z)); l.w=f2bf(v.w-bf2f(h.w));
      int o = krow*40 + kk0 + i*4;
      *(ushort4*)&sKh[o] = h; *(ushort4*)&sKl[o] = l;
    }
  };

  f32x4 acc1[4][2];
  #pragma unroll
  for (int m = 0; m < 4; ++m)
    #pragma unroll
    for (int n = 0; n < 2; ++n) acc1[m][n] = (f32x4){0.f,0.f,0.f,0.f};
  int wc = wave * 32;

  issue1(0); commit1();
  __syncthreads();
  for (int t = 0; t < 10; ++t) {
    bool more = (t < 9);
    bf16x8 ah[4], al[4], bh[2], bl[2];
    #pragma unroll
    for (int m = 0; m < 4; ++m) {
      int o = (m*16 + lrow)*40 + koff;
      ah[m] = *(const bf16x8*)&sQh[o];
      al[m] = *(const bf16x8*)&sQl[o];
    }
    #pragma unroll
    for (int n = 0; n < 2; ++n) {
      int o = (wc + n*16 + lrow)*40 + koff;
      bh[n] = *(const bf16x8*)&sKh[o];
      bl[n] = *(const bf16x8*)&sKl[o];
    }
    if (more) issue1(t+1);
    __syncthreads();
    if (more) commit1();
    #pragma unroll
    for (int m = 0; m < 4; ++m)
      #pragma unroll
      for (int n = 0; n < 2; ++n) {
        acc1[m][n] = __builtin_amdgcn_mfma_f32_16x16x32_bf16(ah[m], bh[n], acc1[m][n], 0,0,0);
        acc1[m][n] = __builtin_amdgcn_mfma_f32_16x16x32_bf16(ah[m], bl[n], acc1[m][n], 0,0,0);
        acc1[m][n] = __builtin_amdgcn_mfma_f32_16x16x32_bf16(al[m], bh[n], acc1[m][n], 0,0,0);
      }
    __syncthreads();
  }
  float* sim = regA_f;
  #pragma unroll
  for (int m = 0; m < 4; ++m)
    #pragma unroll
    for (int n = 0; n < 2; ++n)
      #pragma unroll
      for (int r = 0; r < 4; ++r)
        sim[(m*16 + (lane>>4)*4 + r)*132 + wc + n*16 + lrow] = acc1[m][n][r];
  __syncthreads();

  {
    int row = tid >> 2, qtr = (tid & 3) * 32;
    const float* sr = sim + row*132;
    float mx = NEGV;
    for (int c = 0; c < 32; ++c) { int cg = qtr + c; float s = (cg < klen) ? sr[cg] : NEGV; mx = fmaxf(mx, s); }
    mx = fmaxf(mx, __shfl_xor(mx, 1));
    mx = fmaxf(mx, __shfl_xor(mx, 2));
    float sum = 0.f;
    for (int c = 0; c < 32; ++c) { int cg = qtr + c; if (cg < klen) sum += expf(sr[cg] - mx); }
    sum += __shfl_xor(sum, 1);
    sum += __shfl_xor(sum, 2);
    float rinv = 1.f / sum;
    for (int c = 0; c < 32; ++c) {
      int cg = qtr + c;
      float p = (cg < klen) ? expf(sr[cg] - mx) * rinv : 0.f;
      ushort_t h = f2bf(p);
      pbuf[row*136 + cg] = h;
      pbuf[64*136 + row*136 + cg] = f2bf(p - bf2f(h));
    }
  }
  __syncthreads();

  ushort_t* kth = regA;
  ushort_t* ktl = regA + 12800;
  int wr2 = (wave & 1) * 32;
  int wcf = (wave >> 1) * 160;
  f32x4 acc3[2][10];
  #pragma unroll
  for (int m = 0; m < 2; ++m)
    #pragma unroll
    for (int n = 0; n < 10; ++n) acc3[m][n] = (f32x4){0.f,0.f,0.f,0.f};
  int skey = tid >> 3, sf4 = tid & 7;

  for (int kc = 0; kc < 4; ++kc) {
    __syncthreads();
    const float* kr = Kp + (size_t)(kc*32 + skey)*H_;
    for (int f4 = sf4; f4 < 75; f4 += 8) {
      float4 v = *(const float4*)(kr + f4*4);
      float vv[4] = {v.x, v.y, v.z, v.w};
      #pragma unroll
      for (int i = 0; i < 4; ++i) {
        int feat = f4*4 + i;
        ushort_t h = f2bf(vv[i]);
        kth[feat*40 + skey] = h;
        ktl[feat*40 + skey] = f2bf(vv[i] - bf2f(h));
      }
    }
    __syncthreads();
    bf16x8 ph[2], pl[2], kh[10], kl[10];
    #pragma unroll
    for (int m = 0; m < 2; ++m) {
      int o = (wr2 + m*16 + lrow)*136 + kc*32 + koff;
      ph[m] = *(const bf16x8*)&pbuf[o];
      pl[m] = *(const bf16x8*)&pbuf[64*136 + o];
    }
    #pragma unroll
    for (int n = 0; n < 10; ++n) {
      int o = (wcf + n*16 + lrow)*40 + koff;
      kh[n] = *(const bf16x8*)&kth[o];
      kl[n] = *(const bf16x8*)&ktl[o];
    }
    #pragma unroll
    for (int m = 0; m < 2; ++m)
      #pragma unroll
      for (int n = 0; n < 10; ++n) {
        acc3[m][n] = __builtin_amdgcn_mfma_f32_16x16x32_bf16(ph[m], kh[n], acc3[m][n], 0,0,0);
        acc3[m][n] = __builtin_amdgcn_mfma_f32_16x16x32_bf16(ph[m], kl[n], acc3[m][n], 0,0,0);
        acc3[m][n] = __builtin_amdgcn_mfma_f32_16x16x32_bf16(pl[m], kh[n], acc3[m][n], 0,0,0);
      }
  }
  #pragma unroll
  for (int m = 0; m < 2; ++m) {
    int row0 = wr2 + m*16 + (lane >> 4)*4;
    #pragma unroll
    for (int n = 0; n < 10; ++n) {
      int col = wcf + n*16 + lrow;
      if (col < H_) {
        #pragma unroll
        for (int r = 0; r < 4; ++r)
          outp[(size_t)(row0 + r)*H_ + col] = acc3[m][n][r];
      }
    }
  }
}

// ---------------- pool stage 1 ----------------
__global__ __launch_bounds__(320) void k_pool(const float* __restrict__ H,
    const int* __restrict__ plen, const int* __restrict__ hlen,
    float* __restrict__ psum, float* __restrict__ pmax)
{
  int chain = blockIdx.x; int s = chain >> 5, b = chain & 31;
  int c = blockIdx.y; int t0 = c * 16;
  int len = (s == 0 ? plen[b] : hlen[b]);
  int tid = threadIdx.x;
  __shared__ float buf[16*H_];
  const float* hp = H + (size_t)chain*T_*H_ + (size_t)t0*H_;
  for (int i = tid; i < 16*H_; i += 320) buf[i] = hp[i];
  __syncthreads();
  if (tid < H_) {
    int tmax = len - t0; if (tmax > 16) tmax = 16;
    float sum = 0.f, mx = NEGV;
    for (int t = 0; t < tmax; ++t) { float x = buf[t*H_ + tid]; sum += x; mx = fmaxf(mx, x); }
    int o = (chain*8 + c)*H_ + tid;
    psum[o] = sum; pmax[o] = mx;
  }
}

// ---------------- pool stage 2 + classifier ----------------
__global__ __launch_bounds__(320) void k_classify(
    const float* __restrict__ psum, const float* __restrict__ pmax,
    const int* __restrict__ plen, const int* __restrict__ hlen,
    const float* __restrict__ w1t, const float* __restrict__ b1,
    const float* __restrict__ w2, const float* __restrict__ b2,
    float* __restrict__ out)
{
  int b = blockIdx.x;
  int tid = threadIdx.x;
  __shared__ float v[HG];
  __shared__ float hid[H_];
  for (int s = 0; s < 2; ++s) {
    int chain = s*B_ + b;
    int len = (s == 0 ? plen[b] : hlen[b]);
    if (tid < H_) {
      float sum = 0.f, mx = NEGV;
      #pragma unroll
      for (int c = 0; c < 8; ++c) {
        int o = (chain*8 + c)*H_ + tid;
        sum += psum[o]; mx = fmaxf(mx, pmax[o]);
      }
      v[s*600 + tid]       = sum / (float)len;
      v[s*600 + 300 + tid] = mx;
    }
  }
  __syncthreads();
  if (tid < H_) {
    float a0 = b1[tid], a1 = 0.f, a2 = 0.f, a3 = 0.f;
    for (int m = 0; m < HG; m += 4) {
      a0 = fmaf(v[m+0], w1t[(size_t)(m+0)*H_ + tid], a0);
      a1 = fmaf(v[m+1], w1t[(size_t)(m+1)*H_ + tid], a1);
      a2 = fmaf(v[m+2], w1t[(size_t)(m+2)*H_ + tid], a2);
      a3 = fmaf(v[m+3], w1t[(size_t)(m+3)*H_ + tid], a3);
    }
    hid[tid] = tanhf(a0 + a1 + a2 + a3);
  }
  __syncthreads();
  if (tid < 3) {
    float a = b2[tid];
    const float* wr = w2 + (size_t)tid*H_;
    for (int n = 0; n < H_; ++n) a = fmaf(hid[n], wr[n], a);
    out[b*3 + tid] = a;
  }
}

// ---------------- launch ----------------
extern "C" void kernel_launch(void* const* d_in, const int* in_sizes, int n_in,
                              void* d_out, int out_size, void* d_ws, size_t ws_size,
                              hipStream_t stream) {
  const int*   prem    = (const int*)d_in[0];
  const int*   plen    = (const int*)d_in[1];
  const int*   hyp     = (const int*)d_in[2];
  const int*   hlen    = (const int*)d_in[3];
  const float* lg      = (const float*)d_in[4];
  const float* rg      = (const float*)d_in[5];
  const float* emb     = (const float*)d_in[6];
  const float* enc_wx  = (const float*)d_in[7];
  const float* enc_bx  = (const float*)d_in[8];
  const float* enc_uh  = (const float*)d_in[9];
  const float* enc_bh  = (const float*)d_in[10];
  const float* comp_wx = (const float*)d_in[11];
  const float* comp_bx = (const float*)d_in[12];
  const float* comp_uh = (const float*)d_in[13];
  const float* comp_bh = (const float*)d_in[14];
  const float* proj_w  = (const float*)d_in[15];
  const float* proj_b  = (const float*)d_in[16];
  const float* cls_w1  = (const float*)d_in[17];
  const float* cls_b1  = (const float*)d_in[18];
  const float* cls_w2  = (const float*)d_in[19];
  const float* cls_b2  = (const float*)d_in[20];
  float* outp = (float*)d_out;

  // workspace layout (floats); ENH bf16 aliases XG; PROJ bf16 aliases EH/EL
  float* XG  = (float*)d_ws;                       // 9,830,400 f
  ushort_t* EH = (ushort_t*)(XG + 9830400);        // [8192][320] hi (also PROJ hi)
  ushort_t* EL = EH + 2621440;                     // [8192][320] lo (also PROJ lo)
  float* H1  = XG + 9830400 + 2621440;
  float* CH  = H1 + 2457600;                       // ATT alias
  float* FH  = CH + 2457600;
  float* UTE = FH + 2457600;
  float* UTC = UTE + 90000;
  float* W1T = UTC + 90000;
  ushort_t* WencH  = (ushort_t*)(W1T + 360000);
  ushort_t* WencL  = WencH + 384000;
  ushort_t* WcompH = WencL + 384000;
  ushort_t* WcompL = WcompH + 384000;
  ushort_t* WPH    = WcompL + 384000;
  ushort_t* WPL    = WPH + 278400;
  float* PSUM = W1T + 360000 + 1046400;
  float* PMAX = PSUM + 153600;
  float* EW   = PMAX + 153600;
  int* EIDX   = (int*)(EW + 64*ECAP);
  int* CNT    = EIDX + 64*ECAP;
  int* COFF   = CNT + 64*T_;
  int* DEPTH  = COFF + 64*T_;
  int* HASP   = DEPTH + 64*T_;
  int* MAXD   = HASP + 64*T_;
  int* LVLCNT = MAXD + 64;
  int* WL     = LVLCNT + LMAX;
  float* ATT  = CH;
  ushort_t* ENH_H = (ushort_t*)XG;                 // [8192][928] hi (after enc scan, XG dead)
  ushort_t* ENH_L = ENH_H + 7602176;

  hipMemsetAsync(LVLCNT, 0, LMAX*sizeof(int), stream);
  // 1. weight prep + graph analysis + embedding split
  k_prep_all<<<(1496400 + 255)/256, 256, 0, stream>>>(enc_uh, comp_uh, enc_wx, comp_wx, proj_w, cls_w1,
      UTE, UTC, W1T, WencH, WencL, WcompH, WcompL, WPH, WPL);
  k_build<<<64, 256, 0, stream>>>(lg, rg, CNT, COFF, EIDX, EW, HASP, DEPTH, MAXD, LVLCNT, WL);
  k_embed_split<<<10240, 256, 0, stream>>>(prem, hyp, emb, EH, EL);
  // 2. enc xg = emb @ enc_wx^T + enc_bx
  k_gemm_bf<0><<<dim3(10, 64), 256, 0, stream>>>(EH, EL, 320, WencH, WencL, 320,
      enc_bx, XG, nullptr, nullptr, 0, HG, 10, 0);
  // 3. enc tree scan (gates inline)
  for (int L = 0; L < LMAX; ++L)
    k_level<<<640, 1024, 0, stream>>>(XG, enc_bh, UTE, CNT, COFF, EIDX, EW, HASP, LVLCNT, WL, L, H1, CH, FH);
  k_tail<<<64, 320, 0, stream>>>(XG, enc_bh, UTE, CNT, COFF, EIDX, EW, HASP, DEPTH, MAXD, H1, CH, FH);
  // 4. attention (CH dead -> ATT)
  k_attn_mfma<<<dim3(2, B_, 2), 256, 0, stream>>>(H1, plen, hlen, ATT);
  // 5. enhance split (enc-xg dead), proj GEMM -> PROJ bf16 hi/lo
  k_enh_split<<<29696, 256, 0, stream>>>(H1, ATT, ENH_H, ENH_L);
  k_gemm_bf<1><<<dim3(3, 64), 256, 0, stream>>>(ENH_H, ENH_L, 928, WPH, WPL, 928,
      proj_b, nullptr, EH, EL, 320, H_, 29, 1);
  // 6. comp xg = proj @ comp_wx^T + comp_bx (overwrites XG)
  k_gemm_bf<0><<<dim3(10, 64), 256, 0, stream>>>(EH, EL, 320, WcompH, WcompL, 320,
      comp_bx, XG, nullptr, nullptr, 0, HG, 10, 0);
  // 7. comp tree scan
  for (int L = 0; L < LMAX; ++L)
    k_level<<<640, 1024, 0, stream>>>(XG, comp_bh, UTC, CNT, COFF, EIDX, EW, HASP, LVLCNT, WL, L, H1, CH, FH);
  k_tail<<<64, 320, 0, stream>>>(XG, comp_bh, UTC, CNT, COFF, EIDX, EW, HASP, DEPTH, MAXD, H1, CH, FH);
  // 8. pool + classifier
  k_pool<<<dim3(64, 8), 320, 0, stream>>>(H1, plen, hlen, PSUM, PMAX);
  k_classify<<<B_, 320, 0, stream>>>(PSUM, PMAX, plen, hlen, W1T, cls_b1, cls_w2, cls_b2, outp);
}